// Round 3
// baseline (1402.847 us; speedup 1.0000x reference)
//
#include <hip/hip_runtime.h>
#include <hip/hip_bf16.h>

typedef unsigned short u16;

#define LEAKY 0.2f

__device__ __forceinline__ float bu2f(u16 v) {
    return __uint_as_float(((unsigned)v) << 16);
}
__device__ __forceinline__ u16 f2bu(float f) {
    unsigned u = __float_as_uint(f);
    unsigned r = (u + 0x7FFFu + ((u >> 16) & 1u)) >> 16;
    return (u16)r;
}
__device__ __forceinline__ unsigned fmapu(float f) {
    unsigned u = __float_as_uint(f);
    return (u & 0x80000000u) ? ~u : (u | 0x80000000u);
}
__device__ __forceinline__ float funmapu(unsigned u) {
    return __uint_as_float((u & 0x80000000u) ? (u & 0x7FFFFFFFu) : ~u);
}

// ---------------- CSR build ----------------

__global__ void k_init(int* deg, unsigned* gmaxb, float* sumexp, int N) {
    int i = blockIdx.x * blockDim.x + threadIdx.x;
    if (i < N) deg[i] = 1;  // self loop
    if (i == 0) { *gmaxb = 0u; *sumexp = 0.f; }
}

__global__ void k_count(const int* __restrict__ dst, int* __restrict__ deg, int E) {
    int i = blockIdx.x * blockDim.x + threadIdx.x;
    if (i < E) atomicAdd(&deg[dst[i]], 1);
}

__global__ void k_scan(const int* __restrict__ deg, int* __restrict__ rowst, int N) {
    // single block, 1024 threads
    __shared__ int part[1024];
    int t = threadIdx.x;
    int chunk = (N + 1023) / 1024;
    int lo = t * chunk;
    int hi = min(lo + chunk, N);
    int s = 0;
    for (int i = lo; i < hi; ++i) s += deg[i];
    part[t] = s;
    __syncthreads();
    if (t == 0) {
        int run = 0;
        for (int i = 0; i < 1024; ++i) { int v = part[i]; part[i] = run; run += v; }
    }
    __syncthreads();
    int run = part[t];
    for (int i = lo; i < hi; ++i) { rowst[i] = run; run += deg[i]; }
    if (hi == N && lo < N) rowst[N] = run;
}

__global__ void k_selfloop(const int* __restrict__ rowst, int* __restrict__ cursor,
                           int* __restrict__ adj, int N) {
    int i = blockIdx.x * blockDim.x + threadIdx.x;
    if (i < N) {
        int p = rowst[i];
        adj[p] = i;          // self loop first
        cursor[i] = p + 1;
    }
}

__global__ void k_scatter(const int* __restrict__ src, const int* __restrict__ dst,
                          int* __restrict__ cursor, int* __restrict__ adj, int E) {
    int i = blockIdx.x * blockDim.x + threadIdx.x;
    if (i < E) {
        int pos = atomicAdd(&cursor[dst[i]], 1);
        adj[pos] = src[i];
    }
}

// ---------------- GEMM (N x 128) @ (128 x 128) + attention-coef epilogue ----------------

template <typename T>
__device__ __forceinline__ float ldv(const T* p, size_t i);
template <>
__device__ __forceinline__ float ldv<float>(const float* p, size_t i) { return p[i]; }
template <>
__device__ __forceinline__ float ldv<u16>(const u16* p, size_t i) { return bu2f(p[i]); }

template <int H, typename TIN>
__global__ __launch_bounds__(128) void k_gemm_att(
    const TIN* __restrict__ in, const float* __restrict__ W,
    const float* __restrict__ att_s, const float* __restrict__ att_d,
    u16* __restrict__ out, float* __restrict__ a_src, float* __restrict__ a_dst, int N) {
    __shared__ float Wl[128 * 128];
    __shared__ float xr[128];
    __shared__ float r2s[2], r2d[2];
    int c = threadIdx.x;
    for (int i = 0; i < 128; ++i) Wl[i * 128 + c] = W[i * 128 + c];
    float atts = att_s[c];
    float attd = att_d[c];
    int r0 = blockIdx.x * 32;
    int rend = min(r0 + 32, N);
    for (int r = r0; r < rend; ++r) {
        __syncthreads();
        xr[c] = ldv(in, (size_t)r * 128 + c);
        __syncthreads();
        float acc = 0.f;
#pragma unroll 8
        for (int k = 0; k < 128; ++k) acc += xr[k] * Wl[k * 128 + c];
        out[(size_t)r * 128 + c] = f2bu(acc);
        float ps = acc * atts;
        float pd = acc * attd;
#pragma unroll
        for (int o = 32; o > 0; o >>= 1) {
            ps += __shfl_down(ps, o);
            pd += __shfl_down(pd, o);
        }
        if (H == 2) {
            if ((c & 63) == 0) {
                int h = c >> 6;
                a_src[(size_t)r * 2 + h] = ps;
                a_dst[(size_t)r * 2 + h] = pd;
            }
        } else {
            if ((c & 63) == 0) { r2s[c >> 6] = ps; r2d[c >> 6] = pd; }
            __syncthreads();
            if (c == 0) {
                a_src[r] = r2s[0] + r2s[1];
                a_dst[r] = r2d[0] + r2d[1];
            }
        }
    }
}

// ---------------- per-node segment softmax + aggregation (online) ----------------

template <int H, typename TOUT>
__global__ __launch_bounds__(128) void k_agg(
    const int* __restrict__ rowst, const int* __restrict__ adj,
    const float* __restrict__ a_src, const float* __restrict__ a_dst,
    const u16* __restrict__ h_in, const float* __restrict__ bias,
    TOUT* __restrict__ out, int N) {
    int n = blockIdx.x;
    if (n >= N) return;
    const int Ch = 128 / H;
    int c = threadIdx.x;
    int h = c / Ch;
    __shared__ float sm_m[H], sm_s[H], sscale[H];
    __shared__ int srcs[64];
    __shared__ float ev[H][64], pv[H][64];
    if (c < H) { sm_m[c] = -1e30f; sm_s[c] = 0.f; }
    float acc = 0.f;
    int rs = rowst[n], re = rowst[n + 1];
    __syncthreads();
    for (int base = rs; base < re; base += 64) {
        int cnt = min(64, re - base);
        if (c < cnt) {
            int s = adj[base + c];
            srcs[c] = s;
#pragma unroll
            for (int hh = 0; hh < H; ++hh) {
                float xv = a_src[(size_t)s * H + hh] + a_dst[(size_t)n * H + hh];
                ev[hh][c] = (xv > 0.f) ? xv : LEAKY * xv;
            }
        }
        __syncthreads();
        if (c < H) {
            float mx = sm_m[c];
            for (int e = 0; e < cnt; ++e) mx = fmaxf(mx, ev[c][e]);
            float sc = __expf(sm_m[c] - mx);
            float ss = sm_s[c] * sc;
            for (int e = 0; e < cnt; ++e) {
                float pe = __expf(ev[c][e] - mx);
                pv[c][e] = pe;
                ss += pe;
            }
            sm_m[c] = mx; sm_s[c] = ss; sscale[c] = sc;
        }
        __syncthreads();
        acc *= sscale[h];
        for (int e = 0; e < cnt; ++e) {
            acc += pv[h][e] * bu2f(h_in[(size_t)srcs[e] * 128 + c]);
        }
        __syncthreads();
    }
    float val = acc / (sm_s[h] + 1e-16f) + bias[c];
    if constexpr (sizeof(TOUT) == 2) {
        out[(size_t)n * 128 + c] = (TOUT)f2bu(val);
    } else {
        out[(size_t)n * 128 + c] = (TOUT)val;
    }
}

// ---------------- score head ----------------

__global__ void k_cvec(const float* __restrict__ q, const float* __restrict__ Wq1,
                       const float* __restrict__ bq1, float* __restrict__ cvec) {
    int j = threadIdx.x;  // 128 threads
    float acc = bq1[j];
    for (int k = 0; k < 384; ++k) acc += q[k] * Wq1[(size_t)(128 + k) * 128 + j];
    cvec[j] = acc;
}

// Tiled score head: stage Wq1 (top 128x128 block) in LDS once per block,
// process 64 nodes per block, 2 rows in flight (256 threads).
__global__ __launch_bounds__(256) void k_score(
    const float* __restrict__ h2, const float* __restrict__ Wq1, const float* __restrict__ Wq2,
    const float* __restrict__ bq2, const float* __restrict__ cvec,
    float* __restrict__ scores, unsigned* __restrict__ gmaxb, int N) {
    __shared__ float Wl[128 * 128];   // 64 KB
    __shared__ float w2s[128];
    __shared__ float cv[128];
    __shared__ float xr[2][128];
    __shared__ float red[2][2];
    int t = threadIdx.x;
    int c = t & 127;
    int rp = t >> 7;   // 0 or 1
    for (int i = t; i < 128 * 128; i += 256) Wl[i] = Wq1[i];
    if (t < 128) { w2s[t] = Wq2[t]; cv[t] = cvec[t]; }
    float bq2v = bq2[0];
    int r0 = blockIdx.x * 64;
    int rend = min(r0 + 64, N);
    for (int rr = r0; rr < rend; rr += 2) {
        int r = rr + rp;
        __syncthreads();
        if (r < N) xr[rp][c] = h2[(size_t)r * 128 + c];
        __syncthreads();
        float acc = cv[c];
#pragma unroll 8
        for (int k = 0; k < 128; ++k) acc += xr[rp][k] * Wl[k * 128 + c];
        float tt = fmaxf(acc, 0.f) * w2s[c];
#pragma unroll
        for (int o = 32; o > 0; o >>= 1) tt += __shfl_down(tt, o);
        if ((c & 63) == 0) red[rp][c >> 6] = tt;
        __syncthreads();
        if (c == 0 && r < N) {
            float s = red[rp][0] + red[rp][1] + bq2v;
            scores[r] = s;
            atomicMax(gmaxb, fmapu(s));
        }
    }
}

__global__ void k_sumexp(float* __restrict__ scores, const unsigned* __restrict__ gmaxb,
                         float* __restrict__ sumexp, int N) {
    int i = blockIdx.x * blockDim.x + threadIdx.x;
    float gmax = funmapu(*gmaxb);
    float p = 0.f;
    if (i < N) {
        p = __expf(scores[i] - gmax);
        scores[i] = p;
    }
#pragma unroll
    for (int o = 32; o > 0; o >>= 1) p += __shfl_down(p, o);
    __shared__ float ws_[4];
    if ((threadIdx.x & 63) == 0) ws_[threadIdx.x >> 6] = p;
    __syncthreads();
    if (threadIdx.x == 0) atomicAdd(sumexp, ws_[0] + ws_[1] + ws_[2] + ws_[3]);
}

__global__ void k_final(const float* __restrict__ scores, const float* __restrict__ sumexp,
                        float* __restrict__ out_s, int N) {
    int i = blockIdx.x * blockDim.x + threadIdx.x;
    if (i < N) out_s[i] = scores[i] / *sumexp;
}

// ---------------- launch ----------------

extern "C" void kernel_launch(void* const* d_in, const int* in_sizes, int n_in,
                              void* d_out, int out_size, void* d_ws, size_t ws_size,
                              hipStream_t stream) {
    const float* x   = (const float*)d_in[0];
    const int*   ei  = (const int*)d_in[1];
    const float* q   = (const float*)d_in[3];
    const float* W1  = (const float*)d_in[4];
    const float* as1 = (const float*)d_in[5];
    const float* ad1 = (const float*)d_in[6];
    const float* b1  = (const float*)d_in[7];
    const float* W2  = (const float*)d_in[8];
    const float* as2 = (const float*)d_in[9];
    const float* ad2 = (const float*)d_in[10];
    const float* b2  = (const float*)d_in[11];
    const float* Wq1 = (const float*)d_in[12];
    const float* bq1 = (const float*)d_in[13];
    const float* Wq2 = (const float*)d_in[14];
    const float* bq2 = (const float*)d_in[15];

    const int N = in_sizes[0] / 128;
    const int E = in_sizes[1] / 2;
    const int ET = E + N;
    const int* esrc = ei;
    const int* edst = ei + E;

    char* p = (char*)d_ws;
    auto alloc = [&](size_t bytes) -> char* {
        char* r = p;
        p += (bytes + 255) & ~(size_t)255;
        return r;
    };
    u16*   hbufA  = (u16*)alloc((size_t)N * 128 * sizeof(u16));  // gemm outputs (bf16)
    u16*   hbufB  = (u16*)alloc((size_t)N * 128 * sizeof(u16));  // layer-1 result (bf16)
    float* asrc1  = (float*)alloc((size_t)N * 2 * sizeof(float));
    float* adst1  = (float*)alloc((size_t)N * 2 * sizeof(float));
    float* asrc2  = (float*)alloc((size_t)N * sizeof(float));
    float* adst2  = (float*)alloc((size_t)N * sizeof(float));
    int*   deg    = (int*)alloc((size_t)N * sizeof(int));
    int*   rowst  = (int*)alloc((size_t)(N + 1) * sizeof(int));
    int*   cursor = (int*)alloc((size_t)N * sizeof(int));
    int*   adjl   = (int*)alloc((size_t)ET * sizeof(int));
    float* scores = (float*)alloc((size_t)N * sizeof(float));
    float* cvec   = (float*)alloc(128 * sizeof(float));
    unsigned* gmaxb = (unsigned*)alloc(256);
    float* sumexp   = (float*)alloc(256);

    float* out_h = (float*)d_out;             // [N*128]
    float* out_s = out_h + (size_t)N * 128;   // [N]

    const int tb = 256;
    k_init<<<(N + tb - 1) / tb, tb, 0, stream>>>(deg, gmaxb, sumexp, N);
    k_count<<<(E + tb - 1) / tb, tb, 0, stream>>>(edst, deg, E);
    k_scan<<<1, 1024, 0, stream>>>(deg, rowst, N);
    k_selfloop<<<(N + tb - 1) / tb, tb, 0, stream>>>(rowst, cursor, adjl, N);
    k_scatter<<<(E + tb - 1) / tb, tb, 0, stream>>>(esrc, edst, cursor, adjl, E);

    // layer 1: heads=2  (x f32 -> h1 bf16)
    k_gemm_att<2, float><<<(N + 31) / 32, 128, 0, stream>>>(x, W1, as1, ad1, hbufA, asrc1, adst1, N);
    k_agg<2, u16><<<N, 128, 0, stream>>>(rowst, adjl, asrc1, adst1, hbufA, b1, hbufB, N);

    // layer 2: heads=1  (h1 bf16 -> h2 f32 into d_out)
    k_gemm_att<1, u16><<<(N + 31) / 32, 128, 0, stream>>>(hbufB, W2, as2, ad2, hbufA, asrc2, adst2, N);
    k_agg<1, float><<<N, 128, 0, stream>>>(rowst, adjl, asrc2, adst2, hbufA, b2, out_h, N);

    // score head
    k_cvec<<<1, 128, 0, stream>>>(q, Wq1, bq1, cvec);
    k_score<<<(N + 63) / 64, 256, 0, stream>>>(out_h, Wq1, Wq2, bq2, cvec, scores, gmaxb, N);
    k_sumexp<<<(N + tb - 1) / tb, tb, 0, stream>>>(scores, gmaxb, sumexp, N);
    k_final<<<(N + tb - 1) / tb, tb, 0, stream>>>(scores, sumexp, out_s, N);
}

// Round 4
// 910.716 us; speedup vs baseline: 1.5404x; 1.5404x over previous
//
#include <hip/hip_runtime.h>
#include <hip/hip_bf16.h>

typedef unsigned short u16;

#define LEAKY 0.2f

__device__ __forceinline__ float bu2f(u16 v) {
    return __uint_as_float(((unsigned)v) << 16);
}
__device__ __forceinline__ u16 f2bu(float f) {
    unsigned u = __float_as_uint(f);
    unsigned r = (u + 0x7FFFu + ((u >> 16) & 1u)) >> 16;
    return (u16)r;
}
__device__ __forceinline__ unsigned fmapu(float f) {
    unsigned u = __float_as_uint(f);
    return (u & 0x80000000u) ? ~u : (u | 0x80000000u);
}
__device__ __forceinline__ float funmapu(unsigned u) {
    return __uint_as_float((u & 0x80000000u) ? (u & 0x7FFFFFFFu) : ~u);
}

// ---------------- CSR build ----------------

__global__ void k_init(int* deg, unsigned* gmaxb, float* sumexp, int N) {
    int i = blockIdx.x * blockDim.x + threadIdx.x;
    if (i < N) deg[i] = 1;  // self loop
    if (i == 0) { *gmaxb = 0u; *sumexp = 0.f; }
}

__global__ void k_count(const int* __restrict__ dst, int* __restrict__ deg, int E) {
    int i = blockIdx.x * blockDim.x + threadIdx.x;
    if (i < E) atomicAdd(&deg[dst[i]], 1);
}

__global__ void k_scan(const int* __restrict__ deg, int* __restrict__ rowst, int N) {
    // single block, 1024 threads
    __shared__ int part[1024];
    int t = threadIdx.x;
    int chunk = (N + 1023) / 1024;
    int lo = t * chunk;
    int hi = min(lo + chunk, N);
    int s = 0;
    for (int i = lo; i < hi; ++i) s += deg[i];
    part[t] = s;
    __syncthreads();
    if (t == 0) {
        int run = 0;
        for (int i = 0; i < 1024; ++i) { int v = part[i]; part[i] = run; run += v; }
    }
    __syncthreads();
    int run = part[t];
    for (int i = lo; i < hi; ++i) { rowst[i] = run; run += deg[i]; }
    if (hi == N && lo < N) rowst[N] = run;
}

__global__ void k_selfloop(const int* __restrict__ rowst, int* __restrict__ cursor,
                           int* __restrict__ adj, int N) {
    int i = blockIdx.x * blockDim.x + threadIdx.x;
    if (i < N) {
        int p = rowst[i];
        adj[p] = i;          // self loop first
        cursor[i] = p + 1;
    }
}

__global__ void k_scatter(const int* __restrict__ src, const int* __restrict__ dst,
                          int* __restrict__ cursor, int* __restrict__ adj, int E) {
    int i = blockIdx.x * blockDim.x + threadIdx.x;
    if (i < E) {
        int pos = atomicAdd(&cursor[dst[i]], 1);
        adj[pos] = src[i];
    }
}

// ---------------- GEMM (N x 128) @ (128 x 128) + attention-coef epilogue ----------------

template <typename T>
__device__ __forceinline__ float ldv(const T* p, size_t i);
template <>
__device__ __forceinline__ float ldv<float>(const float* p, size_t i) { return p[i]; }
template <>
__device__ __forceinline__ float ldv<u16>(const u16* p, size_t i) { return bu2f(p[i]); }

template <int H, typename TIN>
__global__ __launch_bounds__(128) void k_gemm_att(
    const TIN* __restrict__ in, const float* __restrict__ W,
    const float* __restrict__ att_s, const float* __restrict__ att_d,
    u16* __restrict__ out, float* __restrict__ a_src, float* __restrict__ a_dst, int N) {
    __shared__ float Wl[128 * 128];
    __shared__ float xr[128];
    __shared__ float r2s[2], r2d[2];
    int c = threadIdx.x;
    for (int i = 0; i < 128; ++i) Wl[i * 128 + c] = W[i * 128 + c];
    float atts = att_s[c];
    float attd = att_d[c];
    int r0 = blockIdx.x * 32;
    int rend = min(r0 + 32, N);
    for (int r = r0; r < rend; ++r) {
        __syncthreads();
        xr[c] = ldv(in, (size_t)r * 128 + c);
        __syncthreads();
        float acc = 0.f;
#pragma unroll 8
        for (int k = 0; k < 128; ++k) acc += xr[k] * Wl[k * 128 + c];
        out[(size_t)r * 128 + c] = f2bu(acc);
        float ps = acc * atts;
        float pd = acc * attd;
#pragma unroll
        for (int o = 32; o > 0; o >>= 1) {
            ps += __shfl_down(ps, o);
            pd += __shfl_down(pd, o);
        }
        if (H == 2) {
            if ((c & 63) == 0) {
                int h = c >> 6;
                a_src[(size_t)r * 2 + h] = ps;
                a_dst[(size_t)r * 2 + h] = pd;
            }
        } else {
            if ((c & 63) == 0) { r2s[c >> 6] = ps; r2d[c >> 6] = pd; }
            __syncthreads();
            if (c == 0) {
                a_src[r] = r2s[0] + r2s[1];
                a_dst[r] = r2d[0] + r2d[1];
            }
        }
    }
}

// ---------------- per-node segment softmax + aggregation (online) ----------------

template <int H, typename TOUT>
__global__ __launch_bounds__(128) void k_agg(
    const int* __restrict__ rowst, const int* __restrict__ adj,
    const float* __restrict__ a_src, const float* __restrict__ a_dst,
    const u16* __restrict__ h_in, const float* __restrict__ bias,
    TOUT* __restrict__ out, int N) {
    int n = blockIdx.x;
    if (n >= N) return;
    const int Ch = 128 / H;
    int c = threadIdx.x;
    int h = c / Ch;
    __shared__ float sm_m[H], sm_s[H], sscale[H];
    __shared__ int srcs[64];
    __shared__ float ev[H][64], pv[H][64];
    if (c < H) { sm_m[c] = -1e30f; sm_s[c] = 0.f; }
    float acc = 0.f;
    int rs = rowst[n], re = rowst[n + 1];
    __syncthreads();
    for (int base = rs; base < re; base += 64) {
        int cnt = min(64, re - base);
        if (c < cnt) {
            int s = adj[base + c];
            srcs[c] = s;
#pragma unroll
            for (int hh = 0; hh < H; ++hh) {
                float xv = a_src[(size_t)s * H + hh] + a_dst[(size_t)n * H + hh];
                ev[hh][c] = (xv > 0.f) ? xv : LEAKY * xv;
            }
        }
        __syncthreads();
        if (c < H) {
            float mx = sm_m[c];
            for (int e = 0; e < cnt; ++e) mx = fmaxf(mx, ev[c][e]);
            float sc = __expf(sm_m[c] - mx);
            float ss = sm_s[c] * sc;
            for (int e = 0; e < cnt; ++e) {
                float pe = __expf(ev[c][e] - mx);
                pv[c][e] = pe;
                ss += pe;
            }
            sm_m[c] = mx; sm_s[c] = ss; sscale[c] = sc;
        }
        __syncthreads();
        acc *= sscale[h];
        for (int e = 0; e < cnt; ++e) {
            acc += pv[h][e] * bu2f(h_in[(size_t)srcs[e] * 128 + c]);
        }
        __syncthreads();
    }
    float val = acc / (sm_s[h] + 1e-16f) + bias[c];
    if constexpr (sizeof(TOUT) == 2) {
        out[(size_t)n * 128 + c] = (TOUT)f2bu(val);
    } else {
        out[(size_t)n * 128 + c] = (TOUT)val;
    }
}

// ---------------- score head ----------------

__global__ void k_cvec(const float* __restrict__ q, const float* __restrict__ Wq1,
                       const float* __restrict__ bq1, float* __restrict__ cvec) {
    int j = threadIdx.x;  // 128 threads
    float acc = bq1[j];
    for (int k = 0; k < 384; ++k) acc += q[k] * Wq1[(size_t)(128 + k) * 128 + j];
    cvec[j] = acc;
}

// Tiled score head: Wq1 staged in LDS; 64 rows/block; 8-row register blocking;
// ONE atomicMax per block (block-local max reduction) to avoid same-address
// atomic serialization (50000 atomics -> 782).
__global__ __launch_bounds__(256) void k_score(
    const float* __restrict__ h2, const float* __restrict__ Wq1, const float* __restrict__ Wq2,
    const float* __restrict__ bq2, const float* __restrict__ cvec,
    float* __restrict__ scores, unsigned* __restrict__ gmaxb, int N) {
    __shared__ float Wl[128 * 128];   // 64 KB
    __shared__ float w2s[128];
    __shared__ float cv[128];
    __shared__ float xr[2][8][128];
    __shared__ float red[2][8][2];
    __shared__ float bmax[2];
    int t = threadIdx.x;
    int c = t & 127;
    int rp = t >> 7;   // 0 or 1
    for (int i = t; i < 128 * 128; i += 256) Wl[i] = Wq1[i];
    if (t < 128) { w2s[t] = Wq2[t]; cv[t] = cvec[t]; }
    float bq2v = bq2[0];
    float lmax = -1e30f;   // meaningful on c==0 lanes only
    int r0 = blockIdx.x * 64;
    for (int it = 0; it < 4; ++it) {
        int rbase = r0 + it * 16 + rp * 8;
        __syncthreads();
#pragma unroll
        for (int j = 0; j < 8; ++j) {
            int r = rbase + j;
            xr[rp][j][c] = (r < N) ? h2[(size_t)r * 128 + c] : 0.f;
        }
        __syncthreads();
        float acc[8];
#pragma unroll
        for (int j = 0; j < 8; ++j) acc[j] = cv[c];
#pragma unroll 4
        for (int k = 0; k < 128; ++k) {
            float w = Wl[k * 128 + c];
#pragma unroll
            for (int j = 0; j < 8; ++j) acc[j] += xr[rp][j][k] * w;
        }
#pragma unroll
        for (int j = 0; j < 8; ++j) {
            float tt = fmaxf(acc[j], 0.f) * w2s[c];
#pragma unroll
            for (int o = 32; o > 0; o >>= 1) tt += __shfl_down(tt, o);
            if ((c & 63) == 0) red[rp][j][c >> 6] = tt;
        }
        __syncthreads();
        if (c == 0) {
#pragma unroll
            for (int j = 0; j < 8; ++j) {
                int r = rbase + j;
                if (r < N) {
                    float s = red[rp][j][0] + red[rp][j][1] + bq2v;
                    scores[r] = s;
                    lmax = fmaxf(lmax, s);
                }
            }
        }
    }
    if (c == 0) bmax[rp] = lmax;
    __syncthreads();
    if (t == 0) atomicMax(gmaxb, fmapu(fmaxf(bmax[0], bmax[1])));
}

__global__ void k_sumexp(float* __restrict__ scores, const unsigned* __restrict__ gmaxb,
                         float* __restrict__ sumexp, int N) {
    int i = blockIdx.x * blockDim.x + threadIdx.x;
    float gmax = funmapu(*gmaxb);
    float p = 0.f;
    if (i < N) {
        p = __expf(scores[i] - gmax);
        scores[i] = p;
    }
#pragma unroll
    for (int o = 32; o > 0; o >>= 1) p += __shfl_down(p, o);
    __shared__ float ws_[4];
    if ((threadIdx.x & 63) == 0) ws_[threadIdx.x >> 6] = p;
    __syncthreads();
    if (threadIdx.x == 0) atomicAdd(sumexp, ws_[0] + ws_[1] + ws_[2] + ws_[3]);
}

__global__ void k_final(const float* __restrict__ scores, const float* __restrict__ sumexp,
                        float* __restrict__ out_s, int N) {
    int i = blockIdx.x * blockDim.x + threadIdx.x;
    if (i < N) out_s[i] = scores[i] / *sumexp;
}

// ---------------- launch ----------------

extern "C" void kernel_launch(void* const* d_in, const int* in_sizes, int n_in,
                              void* d_out, int out_size, void* d_ws, size_t ws_size,
                              hipStream_t stream) {
    const float* x   = (const float*)d_in[0];
    const int*   ei  = (const int*)d_in[1];
    const float* q   = (const float*)d_in[3];
    const float* W1  = (const float*)d_in[4];
    const float* as1 = (const float*)d_in[5];
    const float* ad1 = (const float*)d_in[6];
    const float* b1  = (const float*)d_in[7];
    const float* W2  = (const float*)d_in[8];
    const float* as2 = (const float*)d_in[9];
    const float* ad2 = (const float*)d_in[10];
    const float* b2  = (const float*)d_in[11];
    const float* Wq1 = (const float*)d_in[12];
    const float* bq1 = (const float*)d_in[13];
    const float* Wq2 = (const float*)d_in[14];
    const float* bq2 = (const float*)d_in[15];

    const int N = in_sizes[0] / 128;
    const int E = in_sizes[1] / 2;
    const int ET = E + N;
    const int* esrc = ei;
    const int* edst = ei + E;

    char* p = (char*)d_ws;
    auto alloc = [&](size_t bytes) -> char* {
        char* r = p;
        p += (bytes + 255) & ~(size_t)255;
        return r;
    };
    u16*   hbufA  = (u16*)alloc((size_t)N * 128 * sizeof(u16));  // gemm outputs (bf16)
    u16*   hbufB  = (u16*)alloc((size_t)N * 128 * sizeof(u16));  // layer-1 result (bf16)
    float* asrc1  = (float*)alloc((size_t)N * 2 * sizeof(float));
    float* adst1  = (float*)alloc((size_t)N * 2 * sizeof(float));
    float* asrc2  = (float*)alloc((size_t)N * sizeof(float));
    float* adst2  = (float*)alloc((size_t)N * sizeof(float));
    int*   deg    = (int*)alloc((size_t)N * sizeof(int));
    int*   rowst  = (int*)alloc((size_t)(N + 1) * sizeof(int));
    int*   cursor = (int*)alloc((size_t)N * sizeof(int));
    int*   adjl   = (int*)alloc((size_t)ET * sizeof(int));
    float* scores = (float*)alloc((size_t)N * sizeof(float));
    float* cvec   = (float*)alloc(128 * sizeof(float));
    unsigned* gmaxb = (unsigned*)alloc(256);
    float* sumexp   = (float*)alloc(256);

    float* out_h = (float*)d_out;             // [N*128]
    float* out_s = out_h + (size_t)N * 128;   // [N]

    const int tb = 256;
    k_init<<<(N + tb - 1) / tb, tb, 0, stream>>>(deg, gmaxb, sumexp, N);
    k_count<<<(E + tb - 1) / tb, tb, 0, stream>>>(edst, deg, E);
    k_scan<<<1, 1024, 0, stream>>>(deg, rowst, N);
    k_selfloop<<<(N + tb - 1) / tb, tb, 0, stream>>>(rowst, cursor, adjl, N);
    k_scatter<<<(E + tb - 1) / tb, tb, 0, stream>>>(esrc, edst, cursor, adjl, E);

    // layer 1: heads=2  (x f32 -> h1 bf16)
    k_gemm_att<2, float><<<(N + 31) / 32, 128, 0, stream>>>(x, W1, as1, ad1, hbufA, asrc1, adst1, N);
    k_agg<2, u16><<<N, 128, 0, stream>>>(rowst, adjl, asrc1, adst1, hbufA, b1, hbufB, N);

    // layer 2: heads=1  (h1 bf16 -> h2 f32 into d_out)
    k_gemm_att<1, u16><<<(N + 31) / 32, 128, 0, stream>>>(hbufB, W2, as2, ad2, hbufA, asrc2, adst2, N);
    k_agg<1, float><<<N, 128, 0, stream>>>(rowst, adjl, asrc2, adst2, hbufA, b2, out_h, N);

    // score head
    k_cvec<<<1, 128, 0, stream>>>(q, Wq1, bq1, cvec);
    k_score<<<(N + 63) / 64, 256, 0, stream>>>(out_h, Wq1, Wq2, bq2, cvec, scores, gmaxb, N);
    k_sumexp<<<(N + tb - 1) / tb, tb, 0, stream>>>(scores, gmaxb, sumexp, N);
    k_final<<<(N + tb - 1) / tb, tb, 0, stream>>>(scores, sumexp, out_s, N);
}

// Round 5
// 591.223 us; speedup vs baseline: 2.3728x; 1.5404x over previous
//
#include <hip/hip_runtime.h>
#include <hip/hip_bf16.h>

typedef unsigned short u16;

#define LEAKY 0.2f

__device__ __forceinline__ float bu2f(u16 v) {
    return __uint_as_float(((unsigned)v) << 16);
}
__device__ __forceinline__ u16 f2bu(float f) {
    unsigned u = __float_as_uint(f);
    unsigned r = (u + 0x7FFFu + ((u >> 16) & 1u)) >> 16;
    return (u16)r;
}
__device__ __forceinline__ unsigned fmapu(float f) {
    unsigned u = __float_as_uint(f);
    return (u & 0x80000000u) ? ~u : (u | 0x80000000u);
}
__device__ __forceinline__ float funmapu(unsigned u) {
    return __uint_as_float((u & 0x80000000u) ? (u & 0x7FFFFFFFu) : ~u);
}

// ---------------- CSR build ----------------

__global__ void k_init(int* deg, unsigned* gmaxb, float* sumexp, int N) {
    int i = blockIdx.x * blockDim.x + threadIdx.x;
    if (i < N) deg[i] = 1;  // self loop
    if (i == 0) { *gmaxb = 0u; *sumexp = 0.f; }
}

__global__ void k_count(const int* __restrict__ dst, int* __restrict__ deg, int E) {
    int i = blockIdx.x * blockDim.x + threadIdx.x;
    if (i < E) atomicAdd(&deg[dst[i]], 1);
}

__global__ void k_scan(const int* __restrict__ deg, int* __restrict__ rowst, int N) {
    __shared__ int part[1024];
    int t = threadIdx.x;
    int chunk = (N + 1023) / 1024;
    int lo = t * chunk;
    int hi = min(lo + chunk, N);
    int s = 0;
    for (int i = lo; i < hi; ++i) s += deg[i];
    part[t] = s;
    __syncthreads();
    if (t == 0) {
        int run = 0;
        for (int i = 0; i < 1024; ++i) { int v = part[i]; part[i] = run; run += v; }
    }
    __syncthreads();
    int run = part[t];
    for (int i = lo; i < hi; ++i) { rowst[i] = run; run += deg[i]; }
    if (hi == N && lo < N) rowst[N] = run;
}

__global__ void k_selfloop(const int* __restrict__ rowst, int* __restrict__ cursor,
                           int* __restrict__ adj, int N) {
    int i = blockIdx.x * blockDim.x + threadIdx.x;
    if (i < N) {
        int p = rowst[i];
        adj[p] = i;          // self loop first
        cursor[i] = p + 1;
    }
}

__global__ void k_scatter(const int* __restrict__ src, const int* __restrict__ dst,
                          int* __restrict__ cursor, int* __restrict__ adj, int E) {
    int i = blockIdx.x * blockDim.x + threadIdx.x;
    if (i < E) {
        int pos = atomicAdd(&cursor[dst[i]], 1);
        adj[pos] = src[i];
    }
}

// ---------------- GEMM (N x 128) @ (128 x 128) + attention-coef epilogue ----------------
// k_score-style: 256 threads, 64 rows/block, 8-row register blocking.

template <typename T>
__device__ __forceinline__ float ldv(const T* p, size_t i);
template <>
__device__ __forceinline__ float ldv<float>(const float* p, size_t i) { return p[i]; }
template <>
__device__ __forceinline__ float ldv<u16>(const u16* p, size_t i) { return bu2f(p[i]); }

template <int H, typename TIN>
__global__ __launch_bounds__(256) void k_gemm_att(
    const TIN* __restrict__ in, const float* __restrict__ W,
    const float* __restrict__ att_s, const float* __restrict__ att_d,
    u16* __restrict__ out, float* __restrict__ a_src, float* __restrict__ a_dst, int N) {
    __shared__ float Wl[128 * 128];        // 64 KB
    __shared__ float xr[2][8][128];
    __shared__ float red_s[2][8][2], red_d[2][8][2];
    int t = threadIdx.x;
    int c = t & 127;
    int rp = t >> 7;   // 0 or 1
    for (int i = t; i < 128 * 128; i += 256) Wl[i] = W[i];
    float atts = att_s[c];
    float attd = att_d[c];
    int r0 = blockIdx.x * 64;
    for (int it = 0; it < 4; ++it) {
        int rbase = r0 + it * 16 + rp * 8;
        __syncthreads();
#pragma unroll
        for (int j = 0; j < 8; ++j) {
            int r = rbase + j;
            xr[rp][j][c] = (r < N) ? ldv(in, (size_t)r * 128 + c) : 0.f;
        }
        __syncthreads();
        float acc[8];
#pragma unroll
        for (int j = 0; j < 8; ++j) acc[j] = 0.f;
#pragma unroll 4
        for (int k = 0; k < 128; ++k) {
            float w = Wl[k * 128 + c];
#pragma unroll
            for (int j = 0; j < 8; ++j) acc[j] += xr[rp][j][k] * w;
        }
#pragma unroll
        for (int j = 0; j < 8; ++j) {
            int r = rbase + j;
            if (r < N) out[(size_t)r * 128 + c] = f2bu(acc[j]);
        }
#pragma unroll
        for (int j = 0; j < 8; ++j) {
            float ps = acc[j] * atts;
            float pd = acc[j] * attd;
#pragma unroll
            for (int o = 32; o > 0; o >>= 1) {
                ps += __shfl_down(ps, o);
                pd += __shfl_down(pd, o);
            }
            if (H == 2) {
                int r = rbase + j;
                if ((c & 63) == 0 && r < N) {
                    a_src[(size_t)r * 2 + (c >> 6)] = ps;
                    a_dst[(size_t)r * 2 + (c >> 6)] = pd;
                }
            } else {
                if ((c & 63) == 0) {
                    red_s[rp][j][c >> 6] = ps;
                    red_d[rp][j][c >> 6] = pd;
                }
            }
        }
        if (H == 1) {
            __syncthreads();
            if (t < 16) {
                int rpp = t >> 3, j = t & 7;
                int r = r0 + it * 16 + rpp * 8 + j;
                if (r < N) {
                    a_src[r] = red_s[rpp][j][0] + red_s[rpp][j][1];
                    a_dst[r] = red_d[rpp][j][0] + red_d[rpp][j][1];
                }
            }
        }
    }
}

// ---------------- per-node segment softmax + aggregation (online, wave-parallel) ----------------

template <int H, typename TOUT>
__global__ __launch_bounds__(128) void k_agg(
    const int* __restrict__ rowst, const int* __restrict__ adj,
    const float* __restrict__ a_src, const float* __restrict__ a_dst,
    const u16* __restrict__ h_in, const float* __restrict__ bias,
    TOUT* __restrict__ out, int N) {
    int n = blockIdx.x;
    if (n >= N) return;
    const int Ch = 128 / H;
    int c = threadIdx.x;
    int w = c >> 6;      // wave id
    int l = c & 63;      // lane
    int h = c / Ch;      // head this thread accumulates for
    int hh = (H == 2) ? w : 0;  // head this wave softmaxes for
    __shared__ float sm_m[H], sm_s[H], sscale[H], asd[H];
    __shared__ int srcs[64];
    __shared__ float pv[H][64];
    if (c < H) {
        sm_m[c] = -1e30f; sm_s[c] = 0.f;
        asd[c] = a_dst[(size_t)n * H + c];
    }
    float acc = 0.f;
    int rs = rowst[n], re = rowst[n + 1];
    __syncthreads();
    for (int base = rs; base < re; base += 64) {
        int cnt = min(64, re - base);
        if (c < cnt) srcs[c] = adj[base + c];
        __syncthreads();
        // wave-parallel online softmax: wave w handles head hh
        bool active = (H == 2) || (w == 0);
        bool ok = active && (l < cnt);
        float xv = -1e30f;
        if (ok) {
            float v = a_src[(size_t)srcs[l] * H + hh] + asd[hh];
            xv = (v > 0.f) ? v : LEAKY * v;
        }
        float lm = xv;
#pragma unroll
        for (int o = 32; o > 0; o >>= 1) lm = fmaxf(lm, __shfl_xor(lm, o));
        float mx = fmaxf(sm_m[hh], lm);
        float pe = ok ? __expf(xv - mx) : 0.f;
        float sum = pe;
#pragma unroll
        for (int o = 32; o > 0; o >>= 1) sum += __shfl_xor(sum, o);
        if (active) {
            pv[hh][l] = pe;
            if (l == 0) {
                float sc = __expf(sm_m[hh] - mx);
                sscale[hh] = sc;
                sm_s[hh] = sm_s[hh] * sc + sum;
                sm_m[hh] = mx;
            }
        }
        __syncthreads();
        acc *= sscale[h];
        for (int e = 0; e < cnt; ++e) {
            acc += pv[h][e] * bu2f(h_in[(size_t)srcs[e] * 128 + c]);
        }
        __syncthreads();
    }
    float val = acc / (sm_s[h] + 1e-16f) + bias[c];
    if constexpr (sizeof(TOUT) == 2) {
        out[(size_t)n * 128 + c] = (TOUT)f2bu(val);
    } else {
        out[(size_t)n * 128 + c] = (TOUT)val;
    }
}

// ---------------- score head ----------------

__global__ void k_cvec(const float* __restrict__ q, const float* __restrict__ Wq1,
                       const float* __restrict__ bq1, float* __restrict__ cvec) {
    int j = threadIdx.x;  // 128 threads
    float acc = bq1[j];
    for (int k = 0; k < 384; ++k) acc += q[k] * Wq1[(size_t)(128 + k) * 128 + j];
    cvec[j] = acc;
}

__global__ __launch_bounds__(256) void k_score(
    const float* __restrict__ h2, const float* __restrict__ Wq1, const float* __restrict__ Wq2,
    const float* __restrict__ bq2, const float* __restrict__ cvec,
    float* __restrict__ scores, unsigned* __restrict__ gmaxb, int N) {
    __shared__ float Wl[128 * 128];   // 64 KB
    __shared__ float w2s[128];
    __shared__ float cv[128];
    __shared__ float xr[2][8][128];
    __shared__ float red[2][8][2];
    __shared__ float bmax[2];
    int t = threadIdx.x;
    int c = t & 127;
    int rp = t >> 7;   // 0 or 1
    for (int i = t; i < 128 * 128; i += 256) Wl[i] = Wq1[i];
    if (t < 128) { w2s[t] = Wq2[t]; cv[t] = cvec[t]; }
    float bq2v = bq2[0];
    float lmax = -1e30f;   // meaningful on c==0 lanes only
    int r0 = blockIdx.x * 64;
    for (int it = 0; it < 4; ++it) {
        int rbase = r0 + it * 16 + rp * 8;
        __syncthreads();
#pragma unroll
        for (int j = 0; j < 8; ++j) {
            int r = rbase + j;
            xr[rp][j][c] = (r < N) ? h2[(size_t)r * 128 + c] : 0.f;
        }
        __syncthreads();
        float acc[8];
#pragma unroll
        for (int j = 0; j < 8; ++j) acc[j] = cv[c];
#pragma unroll 4
        for (int k = 0; k < 128; ++k) {
            float w = Wl[k * 128 + c];
#pragma unroll
            for (int j = 0; j < 8; ++j) acc[j] += xr[rp][j][k] * w;
        }
#pragma unroll
        for (int j = 0; j < 8; ++j) {
            float tt = fmaxf(acc[j], 0.f) * w2s[c];
#pragma unroll
            for (int o = 32; o > 0; o >>= 1) tt += __shfl_down(tt, o);
            if ((c & 63) == 0) red[rp][j][c >> 6] = tt;
        }
        __syncthreads();
        if (c == 0) {
#pragma unroll
            for (int j = 0; j < 8; ++j) {
                int r = rbase + j;
                if (r < N) {
                    float s = red[rp][j][0] + red[rp][j][1] + bq2v;
                    scores[r] = s;
                    lmax = fmaxf(lmax, s);
                }
            }
        }
    }
    if (c == 0) bmax[rp] = lmax;
    __syncthreads();
    if (t == 0) atomicMax(gmaxb, fmapu(fmaxf(bmax[0], bmax[1])));
}

__global__ void k_sumexp(float* __restrict__ scores, const unsigned* __restrict__ gmaxb,
                         float* __restrict__ sumexp, int N) {
    int i = blockIdx.x * blockDim.x + threadIdx.x;
    float gmax = funmapu(*gmaxb);
    float p = 0.f;
    if (i < N) {
        p = __expf(scores[i] - gmax);
        scores[i] = p;
    }
#pragma unroll
    for (int o = 32; o > 0; o >>= 1) p += __shfl_down(p, o);
    __shared__ float ws_[4];
    if ((threadIdx.x & 63) == 0) ws_[threadIdx.x >> 6] = p;
    __syncthreads();
    if (threadIdx.x == 0) atomicAdd(sumexp, ws_[0] + ws_[1] + ws_[2] + ws_[3]);
}

__global__ void k_final(const float* __restrict__ scores, const float* __restrict__ sumexp,
                        float* __restrict__ out_s, int N) {
    int i = blockIdx.x * blockDim.x + threadIdx.x;
    if (i < N) out_s[i] = scores[i] / *sumexp;
}

// ---------------- launch ----------------

extern "C" void kernel_launch(void* const* d_in, const int* in_sizes, int n_in,
                              void* d_out, int out_size, void* d_ws, size_t ws_size,
                              hipStream_t stream) {
    const float* x   = (const float*)d_in[0];
    const int*   ei  = (const int*)d_in[1];
    const float* q   = (const float*)d_in[3];
    const float* W1  = (const float*)d_in[4];
    const float* as1 = (const float*)d_in[5];
    const float* ad1 = (const float*)d_in[6];
    const float* b1  = (const float*)d_in[7];
    const float* W2  = (const float*)d_in[8];
    const float* as2 = (const float*)d_in[9];
    const float* ad2 = (const float*)d_in[10];
    const float* b2  = (const float*)d_in[11];
    const float* Wq1 = (const float*)d_in[12];
    const float* bq1 = (const float*)d_in[13];
    const float* Wq2 = (const float*)d_in[14];
    const float* bq2 = (const float*)d_in[15];

    const int N = in_sizes[0] / 128;
    const int E = in_sizes[1] / 2;
    const int ET = E + N;
    const int* esrc = ei;
    const int* edst = ei + E;

    char* p = (char*)d_ws;
    auto alloc = [&](size_t bytes) -> char* {
        char* r = p;
        p += (bytes + 255) & ~(size_t)255;
        return r;
    };
    u16*   hbufA  = (u16*)alloc((size_t)N * 128 * sizeof(u16));  // gemm outputs (bf16)
    u16*   hbufB  = (u16*)alloc((size_t)N * 128 * sizeof(u16));  // layer-1 result (bf16)
    float* asrc1  = (float*)alloc((size_t)N * 2 * sizeof(float));
    float* adst1  = (float*)alloc((size_t)N * 2 * sizeof(float));
    float* asrc2  = (float*)alloc((size_t)N * sizeof(float));
    float* adst2  = (float*)alloc((size_t)N * sizeof(float));
    int*   deg    = (int*)alloc((size_t)N * sizeof(int));
    int*   rowst  = (int*)alloc((size_t)(N + 1) * sizeof(int));
    int*   cursor = (int*)alloc((size_t)N * sizeof(int));
    int*   adjl   = (int*)alloc((size_t)ET * sizeof(int));
    float* scores = (float*)alloc((size_t)N * sizeof(float));
    float* cvec   = (float*)alloc(128 * sizeof(float));
    unsigned* gmaxb = (unsigned*)alloc(256);
    float* sumexp   = (float*)alloc(256);

    float* out_h = (float*)d_out;             // [N*128]
    float* out_s = out_h + (size_t)N * 128;   // [N]

    const int tb = 256;
    k_init<<<(N + tb - 1) / tb, tb, 0, stream>>>(deg, gmaxb, sumexp, N);
    k_count<<<(E + tb - 1) / tb, tb, 0, stream>>>(edst, deg, E);
    k_scan<<<1, 1024, 0, stream>>>(deg, rowst, N);
    k_selfloop<<<(N + tb - 1) / tb, tb, 0, stream>>>(rowst, cursor, adjl, N);
    k_scatter<<<(E + tb - 1) / tb, tb, 0, stream>>>(esrc, edst, cursor, adjl, E);

    // layer 1: heads=2  (x f32 -> h1 bf16)
    k_gemm_att<2, float><<<(N + 63) / 64, 256, 0, stream>>>(x, W1, as1, ad1, hbufA, asrc1, adst1, N);
    k_agg<2, u16><<<N, 128, 0, stream>>>(rowst, adjl, asrc1, adst1, hbufA, b1, hbufB, N);

    // layer 2: heads=1  (h1 bf16 -> h2 f32 into d_out)
    k_gemm_att<1, u16><<<(N + 63) / 64, 256, 0, stream>>>(hbufB, W2, as2, ad2, hbufA, asrc2, adst2, N);
    k_agg<1, float><<<N, 128, 0, stream>>>(rowst, adjl, asrc2, adst2, hbufA, b2, out_h, N);

    // score head
    k_cvec<<<1, 128, 0, stream>>>(q, Wq1, bq1, cvec);
    k_score<<<(N + 63) / 64, 256, 0, stream>>>(out_h, Wq1, Wq2, bq2, cvec, scores, gmaxb, N);
    k_sumexp<<<(N + tb - 1) / tb, tb, 0, stream>>>(scores, gmaxb, sumexp, N);
    k_final<<<(N + tb - 1) / tb, tb, 0, stream>>>(scores, sumexp, out_s, N);
}

// Round 6
// 442.005 us; speedup vs baseline: 3.1738x; 1.3376x over previous
//
#include <hip/hip_runtime.h>
#include <hip/hip_bf16.h>

typedef unsigned short u16;
typedef __attribute__((ext_vector_type(8))) short bf16x8;
typedef __attribute__((ext_vector_type(4))) float f32x4;

#define LEAKY 0.2f

__device__ __forceinline__ float bu2f(u16 v) {
    return __uint_as_float(((unsigned)v) << 16);
}
__device__ __forceinline__ u16 f2bu(float f) {
    unsigned u = __float_as_uint(f);
    unsigned r = (u + 0x7FFFu + ((u >> 16) & 1u)) >> 16;
    return (u16)r;
}
__device__ __forceinline__ unsigned fmapu(float f) {
    unsigned u = __float_as_uint(f);
    return (u & 0x80000000u) ? ~u : (u | 0x80000000u);
}
__device__ __forceinline__ float funmapu(unsigned u) {
    return __uint_as_float((u & 0x80000000u) ? (u & 0x7FFFFFFFu) : ~u);
}

// ---------------- CSR build ----------------

__global__ void k_init(int* deg, unsigned* gmaxb, float* sumexp, int N) {
    int i = blockIdx.x * blockDim.x + threadIdx.x;
    if (i < N) deg[i] = 1;  // self loop
    if (i == 0) { *gmaxb = 0u; *sumexp = 0.f; }
}

__global__ void k_count(const int* __restrict__ dst, int* __restrict__ deg, int E) {
    int i = blockIdx.x * blockDim.x + threadIdx.x;
    if (i < E) atomicAdd(&deg[dst[i]], 1);
}

__global__ void k_scan(const int* __restrict__ deg, int* __restrict__ rowst, int N) {
    __shared__ int part[1024];
    int t = threadIdx.x;
    int chunk = (N + 1023) / 1024;
    int lo = t * chunk;
    int hi = min(lo + chunk, N);
    int s = 0;
    for (int i = lo; i < hi; ++i) s += deg[i];
    part[t] = s;
    __syncthreads();
    if (t == 0) {
        int run = 0;
        for (int i = 0; i < 1024; ++i) { int v = part[i]; part[i] = run; run += v; }
    }
    __syncthreads();
    int run = part[t];
    for (int i = lo; i < hi; ++i) { rowst[i] = run; run += deg[i]; }
    if (hi == N && lo < N) rowst[N] = run;
}

__global__ void k_selfloop(const int* __restrict__ rowst, int* __restrict__ cursor,
                           int* __restrict__ adj, int N) {
    int i = blockIdx.x * blockDim.x + threadIdx.x;
    if (i < N) {
        int p = rowst[i];
        adj[p] = i;          // self loop first
        cursor[i] = p + 1;
    }
}

__global__ void k_scatter(const int* __restrict__ src, const int* __restrict__ dst,
                          int* __restrict__ cursor, int* __restrict__ adj, int E) {
    int i = blockIdx.x * blockDim.x + threadIdx.x;
    if (i < E) {
        int pos = atomicAdd(&cursor[dst[i]], 1);
        adj[pos] = src[i];
    }
}

// ---------------- MFMA GEMM (N x 128) @ (128 x 128) + attention-coef epilogue ----------------
// B (W) held entirely in registers (32 bf16x8 frags); A-frags loaded straight from
// global (16 B/lane, layout-matched); no LDS, no syncthreads in the K-loop.
// mfma_f32_16x16x32_bf16: A[m= l&15][k=(l>>4)*8+j]; B[k=(l>>4)*8+j][n= l&15];
// C/D: col = l&15, row = (l>>4)*4 + reg   (m89-verified mapping).

template <int H, typename TIN>
__global__ __launch_bounds__(256, 2) void k_gemm_mfma(
    const TIN* __restrict__ in, const float* __restrict__ W,
    const float* __restrict__ att_s, const float* __restrict__ att_d,
    u16* __restrict__ out, float* __restrict__ a_src, float* __restrict__ a_dst,
    int N, int ngrp) {
    int t = threadIdx.x;
    int l = t & 63;
    int wv = t >> 6;        // wave 0..3
    int l16 = l & 15;
    int lk = l >> 4;        // 0..3

    // preload B fragments: b[ks][n] covers k in [ks*32, ks*32+32), n in [n*16, n*16+16)
    bf16x8 b[4][8];
#pragma unroll
    for (int ks = 0; ks < 4; ++ks) {
#pragma unroll
        for (int n = 0; n < 8; ++n) {
            int kbase = ks * 32 + lk * 8;
            int col = n * 16 + l16;
            bf16x8 bb;
#pragma unroll
            for (int j = 0; j < 8; ++j) bb[j] = (short)f2bu(W[(size_t)(kbase + j) * 128 + col]);
            b[ks][n] = bb;
        }
    }
    float atts[8], attd[8];
#pragma unroll
    for (int n = 0; n < 8; ++n) {
        atts[n] = att_s[n * 16 + l16];
        attd[n] = att_d[n * 16 + l16];
    }

    for (int g = blockIdx.x; g < ngrp; g += gridDim.x) {
        int rowbase = g * 64 + wv * 16;
        f32x4 acc[8];
#pragma unroll
        for (int n = 0; n < 8; ++n) acc[n] = (f32x4){0.f, 0.f, 0.f, 0.f};
        int ra = rowbase + l16;   // A-row this lane feeds
#pragma unroll
        for (int ks = 0; ks < 4; ++ks) {
            bf16x8 a;
            if (ra < N) {
                if constexpr (sizeof(TIN) == 4) {
                    const float4* pf = (const float4*)((const float*)in + (size_t)ra * 128 + ks * 32 + lk * 8);
                    float4 p0 = pf[0], p1 = pf[1];
                    a[0] = (short)f2bu(p0.x); a[1] = (short)f2bu(p0.y);
                    a[2] = (short)f2bu(p0.z); a[3] = (short)f2bu(p0.w);
                    a[4] = (short)f2bu(p1.x); a[5] = (short)f2bu(p1.y);
                    a[6] = (short)f2bu(p1.z); a[7] = (short)f2bu(p1.w);
                } else {
                    a = *(const bf16x8*)((const u16*)in + (size_t)ra * 128 + ks * 32 + lk * 8);
                }
            } else {
                a = (bf16x8){0, 0, 0, 0, 0, 0, 0, 0};
            }
#pragma unroll
            for (int n = 0; n < 8; ++n)
                acc[n] = __builtin_amdgcn_mfma_f32_16x16x32_bf16(a, b[ks][n], acc[n], 0, 0, 0);
        }
        // store h
#pragma unroll
        for (int n = 0; n < 8; ++n) {
#pragma unroll
            for (int i = 0; i < 4; ++i) {
                int r = rowbase + lk * 4 + i;
                if (r < N) out[(size_t)r * 128 + n * 16 + l16] = f2bu(acc[n][i]);
            }
        }
        // attention-coef row sums
#pragma unroll
        for (int i = 0; i < 4; ++i) {
            int r = rowbase + lk * 4 + i;
            if (H == 2) {
                float s0 = 0.f, s1 = 0.f, d0 = 0.f, d1 = 0.f;
#pragma unroll
                for (int n = 0; n < 4; ++n) { s0 += acc[n][i] * atts[n]; d0 += acc[n][i] * attd[n]; }
#pragma unroll
                for (int n = 4; n < 8; ++n) { s1 += acc[n][i] * atts[n]; d1 += acc[n][i] * attd[n]; }
#pragma unroll
                for (int o = 1; o < 16; o <<= 1) {
                    s0 += __shfl_xor(s0, o); d0 += __shfl_xor(d0, o);
                    s1 += __shfl_xor(s1, o); d1 += __shfl_xor(d1, o);
                }
                if (l16 == 0 && r < N) {
                    a_src[(size_t)r * 2 + 0] = s0; a_src[(size_t)r * 2 + 1] = s1;
                    a_dst[(size_t)r * 2 + 0] = d0; a_dst[(size_t)r * 2 + 1] = d1;
                }
            } else {
                float s0 = 0.f, d0 = 0.f;
#pragma unroll
                for (int n = 0; n < 8; ++n) { s0 += acc[n][i] * atts[n]; d0 += acc[n][i] * attd[n]; }
#pragma unroll
                for (int o = 1; o < 16; o <<= 1) {
                    s0 += __shfl_xor(s0, o); d0 += __shfl_xor(d0, o);
                }
                if (l16 == 0 && r < N) { a_src[r] = s0; a_dst[r] = d0; }
            }
        }
    }
}

// ---------------- per-node segment softmax + aggregation (online, wave-parallel) ----------------

template <int H, typename TOUT>
__global__ __launch_bounds__(128) void k_agg(
    const int* __restrict__ rowst, const int* __restrict__ adj,
    const float* __restrict__ a_src, const float* __restrict__ a_dst,
    const u16* __restrict__ h_in, const float* __restrict__ bias,
    TOUT* __restrict__ out, int N) {
    int n = blockIdx.x;
    if (n >= N) return;
    const int Ch = 128 / H;
    int c = threadIdx.x;
    int w = c >> 6;
    int l = c & 63;
    int h = c / Ch;
    int hh = (H == 2) ? w : 0;
    __shared__ float sm_m[H], sm_s[H], sscale[H], asd[H];
    __shared__ int srcs[64];
    __shared__ float pv[H][64];
    if (c < H) {
        sm_m[c] = -1e30f; sm_s[c] = 0.f;
        asd[c] = a_dst[(size_t)n * H + c];
    }
    float acc = 0.f;
    int rs = rowst[n], re = rowst[n + 1];
    __syncthreads();
    for (int base = rs; base < re; base += 64) {
        int cnt = min(64, re - base);
        if (c < cnt) srcs[c] = adj[base + c];
        __syncthreads();
        bool active = (H == 2) || (w == 0);
        bool ok = active && (l < cnt);
        float xv = -1e30f;
        if (ok) {
            float v = a_src[(size_t)srcs[l] * H + hh] + asd[hh];
            xv = (v > 0.f) ? v : LEAKY * v;
        }
        float lm = xv;
#pragma unroll
        for (int o = 32; o > 0; o >>= 1) lm = fmaxf(lm, __shfl_xor(lm, o));
        float mx = fmaxf(sm_m[hh], lm);
        float pe = ok ? __expf(xv - mx) : 0.f;
        float sum = pe;
#pragma unroll
        for (int o = 32; o > 0; o >>= 1) sum += __shfl_xor(sum, o);
        if (active) {
            pv[hh][l] = pe;
            if (l == 0) {
                float sc = __expf(sm_m[hh] - mx);
                sscale[hh] = sc;
                sm_s[hh] = sm_s[hh] * sc + sum;
                sm_m[hh] = mx;
            }
        }
        __syncthreads();
        acc *= sscale[h];
        for (int e = 0; e < cnt; ++e) {
            acc += pv[h][e] * bu2f(h_in[(size_t)srcs[e] * 128 + c]);
        }
        __syncthreads();
    }
    float val = acc / (sm_s[h] + 1e-16f) + bias[c];
    if constexpr (sizeof(TOUT) == 2) {
        out[(size_t)n * 128 + c] = (TOUT)f2bu(val);
    } else {
        out[(size_t)n * 128 + c] = (TOUT)val;
    }
}

// ---------------- score head ----------------

__global__ void k_cvec(const float* __restrict__ q, const float* __restrict__ Wq1,
                       const float* __restrict__ bq1, float* __restrict__ cvec) {
    int j = threadIdx.x;  // 128 threads
    float acc = bq1[j];
    for (int k = 0; k < 384; ++k) acc += q[k] * Wq1[(size_t)(128 + k) * 128 + j];
    cvec[j] = acc;
}

__global__ __launch_bounds__(256) void k_score(
    const float* __restrict__ h2, const float* __restrict__ Wq1, const float* __restrict__ Wq2,
    const float* __restrict__ bq2, const float* __restrict__ cvec,
    float* __restrict__ scores, unsigned* __restrict__ gmaxb, int N) {
    __shared__ float Wl[128 * 128];   // 64 KB
    __shared__ float w2s[128];
    __shared__ float cv[128];
    __shared__ float xr[2][8][128];
    __shared__ float red[2][8][2];
    __shared__ float bmax[2];
    int t = threadIdx.x;
    int c = t & 127;
    int rp = t >> 7;
    for (int i = t; i < 128 * 128; i += 256) Wl[i] = Wq1[i];
    if (t < 128) { w2s[t] = Wq2[t]; cv[t] = cvec[t]; }
    float bq2v = bq2[0];
    float lmax = -1e30f;
    int r0 = blockIdx.x * 64;
    for (int it = 0; it < 4; ++it) {
        int rbase = r0 + it * 16 + rp * 8;
        __syncthreads();
#pragma unroll
        for (int j = 0; j < 8; ++j) {
            int r = rbase + j;
            xr[rp][j][c] = (r < N) ? h2[(size_t)r * 128 + c] : 0.f;
        }
        __syncthreads();
        float acc[8];
#pragma unroll
        for (int j = 0; j < 8; ++j) acc[j] = cv[c];
#pragma unroll 4
        for (int k = 0; k < 128; ++k) {
            float w = Wl[k * 128 + c];
#pragma unroll
            for (int j = 0; j < 8; ++j) acc[j] += xr[rp][j][k] * w;
        }
#pragma unroll
        for (int j = 0; j < 8; ++j) {
            float tt = fmaxf(acc[j], 0.f) * w2s[c];
#pragma unroll
            for (int o = 32; o > 0; o >>= 1) tt += __shfl_down(tt, o);
            if ((c & 63) == 0) red[rp][j][c >> 6] = tt;
        }
        __syncthreads();
        if (c == 0) {
#pragma unroll
            for (int j = 0; j < 8; ++j) {
                int r = rbase + j;
                if (r < N) {
                    float s = red[rp][j][0] + red[rp][j][1] + bq2v;
                    scores[r] = s;
                    lmax = fmaxf(lmax, s);
                }
            }
        }
    }
    if (c == 0) bmax[rp] = lmax;
    __syncthreads();
    if (t == 0) atomicMax(gmaxb, fmapu(fmaxf(bmax[0], bmax[1])));
}

__global__ void k_sumexp(float* __restrict__ scores, const unsigned* __restrict__ gmaxb,
                         float* __restrict__ sumexp, int N) {
    int i = blockIdx.x * blockDim.x + threadIdx.x;
    float gmax = funmapu(*gmaxb);
    float p = 0.f;
    if (i < N) {
        p = __expf(scores[i] - gmax);
        scores[i] = p;
    }
#pragma unroll
    for (int o = 32; o > 0; o >>= 1) p += __shfl_down(p, o);
    __shared__ float ws_[4];
    if ((threadIdx.x & 63) == 0) ws_[threadIdx.x >> 6] = p;
    __syncthreads();
    if (threadIdx.x == 0) atomicAdd(sumexp, ws_[0] + ws_[1] + ws_[2] + ws_[3]);
}

__global__ void k_final(const float* __restrict__ scores, const float* __restrict__ sumexp,
                        float* __restrict__ out_s, int N) {
    int i = blockIdx.x * blockDim.x + threadIdx.x;
    if (i < N) out_s[i] = scores[i] / *sumexp;
}

// ---------------- launch ----------------

extern "C" void kernel_launch(void* const* d_in, const int* in_sizes, int n_in,
                              void* d_out, int out_size, void* d_ws, size_t ws_size,
                              hipStream_t stream) {
    const float* x   = (const float*)d_in[0];
    const int*   ei  = (const int*)d_in[1];
    const float* q   = (const float*)d_in[3];
    const float* W1  = (const float*)d_in[4];
    const float* as1 = (const float*)d_in[5];
    const float* ad1 = (const float*)d_in[6];
    const float* b1  = (const float*)d_in[7];
    const float* W2  = (const float*)d_in[8];
    const float* as2 = (const float*)d_in[9];
    const float* ad2 = (const float*)d_in[10];
    const float* b2  = (const float*)d_in[11];
    const float* Wq1 = (const float*)d_in[12];
    const float* bq1 = (const float*)d_in[13];
    const float* Wq2 = (const float*)d_in[14];
    const float* bq2 = (const float*)d_in[15];

    const int N = in_sizes[0] / 128;
    const int E = in_sizes[1] / 2;
    const int ET = E + N;
    const int* esrc = ei;
    const int* edst = ei + E;

    char* p = (char*)d_ws;
    auto alloc = [&](size_t bytes) -> char* {
        char* r = p;
        p += (bytes + 255) & ~(size_t)255;
        return r;
    };
    u16*   hbufA  = (u16*)alloc((size_t)N * 128 * sizeof(u16));  // gemm outputs (bf16)
    u16*   hbufB  = (u16*)alloc((size_t)N * 128 * sizeof(u16));  // layer-1 result (bf16)
    float* asrc1  = (float*)alloc((size_t)N * 2 * sizeof(float));
    float* adst1  = (float*)alloc((size_t)N * 2 * sizeof(float));
    float* asrc2  = (float*)alloc((size_t)N * sizeof(float));
    float* adst2  = (float*)alloc((size_t)N * sizeof(float));
    int*   deg    = (int*)alloc((size_t)N * sizeof(int));
    int*   rowst  = (int*)alloc((size_t)(N + 1) * sizeof(int));
    int*   cursor = (int*)alloc((size_t)N * sizeof(int));
    int*   adjl   = (int*)alloc((size_t)ET * sizeof(int));
    float* scores = (float*)alloc((size_t)N * sizeof(float));
    float* cvec   = (float*)alloc(128 * sizeof(float));
    unsigned* gmaxb = (unsigned*)alloc(256);
    float* sumexp   = (float*)alloc(256);

    float* out_h = (float*)d_out;             // [N*128]
    float* out_s = out_h + (size_t)N * 128;   // [N]

    const int tb = 256;
    k_init<<<(N + tb - 1) / tb, tb, 0, stream>>>(deg, gmaxb, sumexp, N);
    k_count<<<(E + tb - 1) / tb, tb, 0, stream>>>(edst, deg, E);
    k_scan<<<1, 1024, 0, stream>>>(deg, rowst, N);
    k_selfloop<<<(N + tb - 1) / tb, tb, 0, stream>>>(rowst, cursor, adjl, N);
    k_scatter<<<(E + tb - 1) / tb, tb, 0, stream>>>(esrc, edst, cursor, adjl, E);

    const int ngrp = (N + 63) / 64;
    const int gb = (ngrp < 512) ? ngrp : 512;

    // layer 1: heads=2  (x f32 -> h1 bf16)
    k_gemm_mfma<2, float><<<gb, 256, 0, stream>>>(x, W1, as1, ad1, hbufA, asrc1, adst1, N, ngrp);
    k_agg<2, u16><<<N, 128, 0, stream>>>(rowst, adjl, asrc1, adst1, hbufA, b1, hbufB, N);

    // layer 2: heads=1  (h1 bf16 -> h2 f32 into d_out)
    k_gemm_mfma<1, u16><<<gb, 256, 0, stream>>>(hbufB, W2, as2, ad2, hbufA, asrc2, adst2, N, ngrp);
    k_agg<1, float><<<N, 128, 0, stream>>>(rowst, adjl, asrc2, adst2, hbufA, b2, out_h, N);

    // score head
    k_cvec<<<1, 128, 0, stream>>>(q, Wq1, bq1, cvec);
    k_score<<<(N + 63) / 64, 256, 0, stream>>>(out_h, Wq1, Wq2, bq2, cvec, scores, gmaxb, N);
    k_sumexp<<<(N + tb - 1) / tb, tb, 0, stream>>>(scores, gmaxb, sumexp, N);
    k_final<<<(N + tb - 1) / tb, tb, 0, stream>>>(scores, sumexp, out_s, N);
}

// Round 7
// 363.997 us; speedup vs baseline: 3.8540x; 1.2143x over previous
//
#include <hip/hip_runtime.h>
#include <hip/hip_bf16.h>

typedef unsigned short u16;
typedef __attribute__((ext_vector_type(8))) short bf16x8;
typedef __attribute__((ext_vector_type(4))) float f32x4;

#define LEAKY 0.2f

__device__ __forceinline__ float bu2f(u16 v) {
    return __uint_as_float(((unsigned)v) << 16);
}
__device__ __forceinline__ u16 f2bu(float f) {
    unsigned u = __float_as_uint(f);
    unsigned r = (u + 0x7FFFu + ((u >> 16) & 1u)) >> 16;
    return (u16)r;
}
__device__ __forceinline__ unsigned fmapu(float f) {
    unsigned u = __float_as_uint(f);
    return (u & 0x80000000u) ? ~u : (u | 0x80000000u);
}
__device__ __forceinline__ float funmapu(unsigned u) {
    return __uint_as_float((u & 0x80000000u) ? (u & 0x7FFFFFFFu) : ~u);
}

// ---------------- CSR build ----------------

__global__ void k_init(int* deg, unsigned* gmaxb, float* sumexp, int N) {
    int i = blockIdx.x * blockDim.x + threadIdx.x;
    if (i < N) deg[i] = 1;  // self loop
    if (i == 0) { *gmaxb = 0u; *sumexp = 0.f; }
}

__global__ void k_count(const int* __restrict__ dst, int* __restrict__ deg, int E) {
    int i = blockIdx.x * blockDim.x + threadIdx.x;
    if (i < E) atomicAdd(&deg[dst[i]], 1);
}

__global__ void k_scan(const int* __restrict__ deg, int* __restrict__ rowst, int N) {
    __shared__ int part[1024];
    int t = threadIdx.x;
    int chunk = (N + 1023) / 1024;
    int lo = t * chunk;
    int hi = min(lo + chunk, N);
    int s = 0;
    for (int i = lo; i < hi; ++i) s += deg[i];
    part[t] = s;
    __syncthreads();
    if (t == 0) {
        int run = 0;
        for (int i = 0; i < 1024; ++i) { int v = part[i]; part[i] = run; run += v; }
    }
    __syncthreads();
    int run = part[t];
    for (int i = lo; i < hi; ++i) { rowst[i] = run; run += deg[i]; }
    if (hi == N && lo < N) rowst[N] = run;
}

__global__ void k_selfloop(const int* __restrict__ rowst, int* __restrict__ cursor,
                           int* __restrict__ adj, int N) {
    int i = blockIdx.x * blockDim.x + threadIdx.x;
    if (i < N) {
        int p = rowst[i];
        adj[p] = i;          // self loop first
        cursor[i] = p + 1;
    }
}

__global__ void k_scatter(const int* __restrict__ src, const int* __restrict__ dst,
                          int* __restrict__ cursor, int* __restrict__ adj, int E) {
    int i = blockIdx.x * blockDim.x + threadIdx.x;
    if (i < E) {
        int pos = atomicAdd(&cursor[dst[i]], 1);
        adj[pos] = src[i];
    }
}

// ---------------- MFMA GEMM (N x 128) @ (128 x 128) + attention-coef epilogue ----------------
// B (W) held entirely in registers (32 bf16x8 frags); A-frags loaded straight from
// global; no LDS, no syncthreads in the K-loop.
// mfma_f32_16x16x32_bf16: C/D: col = l&15, row = (l>>4)*4 + reg  (m89-verified).

template <int H, typename TIN>
__global__ __launch_bounds__(256, 2) void k_gemm_mfma(
    const TIN* __restrict__ in, const float* __restrict__ W,
    const float* __restrict__ att_s, const float* __restrict__ att_d,
    u16* __restrict__ out, float* __restrict__ a_src, float* __restrict__ a_dst,
    int N, int ngrp) {
    int t = threadIdx.x;
    int l = t & 63;
    int wv = t >> 6;        // wave 0..3
    int l16 = l & 15;
    int lk = l >> 4;        // 0..3

    bf16x8 b[4][8];
#pragma unroll
    for (int ks = 0; ks < 4; ++ks) {
#pragma unroll
        for (int n = 0; n < 8; ++n) {
            int kbase = ks * 32 + lk * 8;
            int col = n * 16 + l16;
            bf16x8 bb;
#pragma unroll
            for (int j = 0; j < 8; ++j) bb[j] = (short)f2bu(W[(size_t)(kbase + j) * 128 + col]);
            b[ks][n] = bb;
        }
    }
    float atts[8], attd[8];
#pragma unroll
    for (int n = 0; n < 8; ++n) {
        atts[n] = att_s[n * 16 + l16];
        attd[n] = att_d[n * 16 + l16];
    }

    for (int g = blockIdx.x; g < ngrp; g += gridDim.x) {
        int rowbase = g * 64 + wv * 16;
        f32x4 acc[8];
#pragma unroll
        for (int n = 0; n < 8; ++n) acc[n] = (f32x4){0.f, 0.f, 0.f, 0.f};
        int ra = rowbase + l16;   // A-row this lane feeds
#pragma unroll
        for (int ks = 0; ks < 4; ++ks) {
            bf16x8 a;
            if (ra < N) {
                if constexpr (sizeof(TIN) == 4) {
                    const float4* pf = (const float4*)((const float*)in + (size_t)ra * 128 + ks * 32 + lk * 8);
                    float4 p0 = pf[0], p1 = pf[1];
                    a[0] = (short)f2bu(p0.x); a[1] = (short)f2bu(p0.y);
                    a[2] = (short)f2bu(p0.z); a[3] = (short)f2bu(p0.w);
                    a[4] = (short)f2bu(p1.x); a[5] = (short)f2bu(p1.y);
                    a[6] = (short)f2bu(p1.z); a[7] = (short)f2bu(p1.w);
                } else {
                    a = *(const bf16x8*)((const u16*)in + (size_t)ra * 128 + ks * 32 + lk * 8);
                }
            } else {
                a = (bf16x8){0, 0, 0, 0, 0, 0, 0, 0};
            }
#pragma unroll
            for (int n = 0; n < 8; ++n)
                acc[n] = __builtin_amdgcn_mfma_f32_16x16x32_bf16(a, b[ks][n], acc[n], 0, 0, 0);
        }
        // store h
#pragma unroll
        for (int n = 0; n < 8; ++n) {
#pragma unroll
            for (int i = 0; i < 4; ++i) {
                int r = rowbase + lk * 4 + i;
                if (r < N) out[(size_t)r * 128 + n * 16 + l16] = f2bu(acc[n][i]);
            }
        }
        // attention-coef row sums
#pragma unroll
        for (int i = 0; i < 4; ++i) {
            int r = rowbase + lk * 4 + i;
            if (H == 2) {
                float s0 = 0.f, s1 = 0.f, d0 = 0.f, d1 = 0.f;
#pragma unroll
                for (int n = 0; n < 4; ++n) { s0 += acc[n][i] * atts[n]; d0 += acc[n][i] * attd[n]; }
#pragma unroll
                for (int n = 4; n < 8; ++n) { s1 += acc[n][i] * atts[n]; d1 += acc[n][i] * attd[n]; }
#pragma unroll
                for (int o = 1; o < 16; o <<= 1) {
                    s0 += __shfl_xor(s0, o); d0 += __shfl_xor(d0, o);
                    s1 += __shfl_xor(s1, o); d1 += __shfl_xor(d1, o);
                }
                if (l16 == 0 && r < N) {
                    a_src[(size_t)r * 2 + 0] = s0; a_src[(size_t)r * 2 + 1] = s1;
                    a_dst[(size_t)r * 2 + 0] = d0; a_dst[(size_t)r * 2 + 1] = d1;
                }
            } else {
                float s0 = 0.f, d0 = 0.f;
#pragma unroll
                for (int n = 0; n < 8; ++n) { s0 += acc[n][i] * atts[n]; d0 += acc[n][i] * attd[n]; }
#pragma unroll
                for (int o = 1; o < 16; o <<= 1) {
                    s0 += __shfl_xor(s0, o); d0 += __shfl_xor(d0, o);
                }
                if (l16 == 0 && r < N) { a_src[r] = s0; a_dst[r] = d0; }
            }
        }
    }
}

// ---------------- per-node segment softmax + aggregation (online, wave-parallel) ----------------

template <int H, typename TOUT>
__global__ __launch_bounds__(128) void k_agg(
    const int* __restrict__ rowst, const int* __restrict__ adj,
    const float* __restrict__ a_src, const float* __restrict__ a_dst,
    const u16* __restrict__ h_in, const float* __restrict__ bias,
    TOUT* __restrict__ out, int N) {
    int n = blockIdx.x;
    if (n >= N) return;
    const int Ch = 128 / H;
    int c = threadIdx.x;
    int w = c >> 6;
    int l = c & 63;
    int h = c / Ch;
    int hh = (H == 2) ? w : 0;
    __shared__ float sm_m[H], sm_s[H], sscale[H], asd[H];
    __shared__ int srcs[64];
    __shared__ float pv[H][64];
    if (c < H) {
        sm_m[c] = -1e30f; sm_s[c] = 0.f;
        asd[c] = a_dst[(size_t)n * H + c];
    }
    float acc = 0.f;
    int rs = rowst[n], re = rowst[n + 1];
    __syncthreads();
    for (int base = rs; base < re; base += 64) {
        int cnt = min(64, re - base);
        if (c < cnt) srcs[c] = adj[base + c];
        __syncthreads();
        bool active = (H == 2) || (w == 0);
        bool ok = active && (l < cnt);
        float xv = -1e30f;
        if (ok) {
            float v = a_src[(size_t)srcs[l] * H + hh] + asd[hh];
            xv = (v > 0.f) ? v : LEAKY * v;
        }
        float lm = xv;
#pragma unroll
        for (int o = 32; o > 0; o >>= 1) lm = fmaxf(lm, __shfl_xor(lm, o));
        float mx = fmaxf(sm_m[hh], lm);
        float pe = ok ? __expf(xv - mx) : 0.f;
        float sum = pe;
#pragma unroll
        for (int o = 32; o > 0; o >>= 1) sum += __shfl_xor(sum, o);
        if (active) {
            pv[hh][l] = pe;
            if (l == 0) {
                float sc = __expf(sm_m[hh] - mx);
                sscale[hh] = sc;
                sm_s[hh] = sm_s[hh] * sc + sum;
                sm_m[hh] = mx;
            }
        }
        __syncthreads();
        acc *= sscale[h];
        for (int e = 0; e < cnt; ++e) {
            acc += pv[h][e] * bu2f(h_in[(size_t)srcs[e] * 128 + c]);
        }
        __syncthreads();
    }
    float val = acc / (sm_s[h] + 1e-16f) + bias[c];
    if constexpr (sizeof(TOUT) == 2) {
        out[(size_t)n * 128 + c] = (TOUT)f2bu(val);
    } else {
        out[(size_t)n * 128 + c] = (TOUT)val;
    }
}

// ---------------- score head ----------------

__global__ void k_cvec(const float* __restrict__ q, const float* __restrict__ Wq1,
                       const float* __restrict__ bq1, float* __restrict__ cvec) {
    int j = threadIdx.x;  // 128 threads
    float acc = bq1[j];
    for (int k = 0; k < 384; ++k) acc += q[k] * Wq1[(size_t)(128 + k) * 128 + j];
    cvec[j] = acc;
}

// MFMA score head: Wq1[0:128][0:128] in registers; epilogue = +cvec, ReLU, *Wq2,
// 16-lane row-sum, block-local max, ONE atomicMax per block.
__global__ __launch_bounds__(256, 2) void k_score_mfma(
    const float* __restrict__ h2, const float* __restrict__ Wq1, const float* __restrict__ Wq2,
    const float* __restrict__ bq2, const float* __restrict__ cvec,
    float* __restrict__ scores, unsigned* __restrict__ gmaxb, int N, int ngrp) {
    int t = threadIdx.x;
    int l = t & 63;
    int wv = t >> 6;
    int l16 = l & 15;
    int lk = l >> 4;

    bf16x8 b[4][8];
#pragma unroll
    for (int ks = 0; ks < 4; ++ks) {
#pragma unroll
        for (int n = 0; n < 8; ++n) {
            int kbase = ks * 32 + lk * 8;
            int col = n * 16 + l16;
            bf16x8 bb;
#pragma unroll
            for (int j = 0; j < 8; ++j) bb[j] = (short)f2bu(Wq1[(size_t)(kbase + j) * 128 + col]);
            b[ks][n] = bb;
        }
    }
    float cva[8], w2a[8];
#pragma unroll
    for (int n = 0; n < 8; ++n) {
        cva[n] = cvec[n * 16 + l16];
        w2a[n] = Wq2[n * 16 + l16];
    }
    float bq2v = bq2[0];
    float lmax = -1e30f;

    for (int g = blockIdx.x; g < ngrp; g += gridDim.x) {
        int rowbase = g * 64 + wv * 16;
        f32x4 acc[8];
#pragma unroll
        for (int n = 0; n < 8; ++n) acc[n] = (f32x4){0.f, 0.f, 0.f, 0.f};
        int ra = rowbase + l16;
#pragma unroll
        for (int ks = 0; ks < 4; ++ks) {
            bf16x8 a;
            if (ra < N) {
                const float4* pf = (const float4*)(h2 + (size_t)ra * 128 + ks * 32 + lk * 8);
                float4 p0 = pf[0], p1 = pf[1];
                a[0] = (short)f2bu(p0.x); a[1] = (short)f2bu(p0.y);
                a[2] = (short)f2bu(p0.z); a[3] = (short)f2bu(p0.w);
                a[4] = (short)f2bu(p1.x); a[5] = (short)f2bu(p1.y);
                a[6] = (short)f2bu(p1.z); a[7] = (short)f2bu(p1.w);
            } else {
                a = (bf16x8){0, 0, 0, 0, 0, 0, 0, 0};
            }
#pragma unroll
            for (int n = 0; n < 8; ++n)
                acc[n] = __builtin_amdgcn_mfma_f32_16x16x32_bf16(a, b[ks][n], acc[n], 0, 0, 0);
        }
#pragma unroll
        for (int i = 0; i < 4; ++i) {
            int r = rowbase + lk * 4 + i;
            float s = 0.f;
#pragma unroll
            for (int n = 0; n < 8; ++n) s += fmaxf(acc[n][i] + cva[n], 0.f) * w2a[n];
#pragma unroll
            for (int o = 1; o < 16; o <<= 1) s += __shfl_xor(s, o);
            if (l16 == 0 && r < N) {
                float sc = s + bq2v;
                scores[r] = sc;
                lmax = fmaxf(lmax, sc);
            }
        }
    }
#pragma unroll
    for (int o = 1; o < 64; o <<= 1) lmax = fmaxf(lmax, __shfl_xor(lmax, o));
    __shared__ float bmax[4];
    if (l == 0) bmax[wv] = lmax;
    __syncthreads();
    if (t == 0)
        atomicMax(gmaxb, fmapu(fmaxf(fmaxf(bmax[0], bmax[1]), fmaxf(bmax[2], bmax[3]))));
}

__global__ void k_sumexp(float* __restrict__ scores, const unsigned* __restrict__ gmaxb,
                         float* __restrict__ sumexp, int N) {
    int i = blockIdx.x * blockDim.x + threadIdx.x;
    float gmax = funmapu(*gmaxb);
    float p = 0.f;
    if (i < N) {
        p = __expf(scores[i] - gmax);
        scores[i] = p;
    }
#pragma unroll
    for (int o = 32; o > 0; o >>= 1) p += __shfl_down(p, o);
    __shared__ float ws_[4];
    if ((threadIdx.x & 63) == 0) ws_[threadIdx.x >> 6] = p;
    __syncthreads();
    if (threadIdx.x == 0) atomicAdd(sumexp, ws_[0] + ws_[1] + ws_[2] + ws_[3]);
}

__global__ void k_final(const float* __restrict__ scores, const float* __restrict__ sumexp,
                        float* __restrict__ out_s, int N) {
    int i = blockIdx.x * blockDim.x + threadIdx.x;
    if (i < N) out_s[i] = scores[i] / *sumexp;
}

// ---------------- launch ----------------

extern "C" void kernel_launch(void* const* d_in, const int* in_sizes, int n_in,
                              void* d_out, int out_size, void* d_ws, size_t ws_size,
                              hipStream_t stream) {
    const float* x   = (const float*)d_in[0];
    const int*   ei  = (const int*)d_in[1];
    const float* q   = (const float*)d_in[3];
    const float* W1  = (const float*)d_in[4];
    const float* as1 = (const float*)d_in[5];
    const float* ad1 = (const float*)d_in[6];
    const float* b1  = (const float*)d_in[7];
    const float* W2  = (const float*)d_in[8];
    const float* as2 = (const float*)d_in[9];
    const float* ad2 = (const float*)d_in[10];
    const float* b2  = (const float*)d_in[11];
    const float* Wq1 = (const float*)d_in[12];
    const float* bq1 = (const float*)d_in[13];
    const float* Wq2 = (const float*)d_in[14];
    const float* bq2 = (const float*)d_in[15];

    const int N = in_sizes[0] / 128;
    const int E = in_sizes[1] / 2;
    const int ET = E + N;
    const int* esrc = ei;
    const int* edst = ei + E;

    char* p = (char*)d_ws;
    auto alloc = [&](size_t bytes) -> char* {
        char* r = p;
        p += (bytes + 255) & ~(size_t)255;
        return r;
    };
    u16*   hbufA  = (u16*)alloc((size_t)N * 128 * sizeof(u16));  // gemm outputs (bf16)
    u16*   hbufB  = (u16*)alloc((size_t)N * 128 * sizeof(u16));  // layer-1 result (bf16)
    float* asrc1  = (float*)alloc((size_t)N * 2 * sizeof(float));
    float* adst1  = (float*)alloc((size_t)N * 2 * sizeof(float));
    float* asrc2  = (float*)alloc((size_t)N * sizeof(float));
    float* adst2  = (float*)alloc((size_t)N * sizeof(float));
    int*   deg    = (int*)alloc((size_t)N * sizeof(int));
    int*   rowst  = (int*)alloc((size_t)(N + 1) * sizeof(int));
    int*   cursor = (int*)alloc((size_t)N * sizeof(int));
    int*   adjl   = (int*)alloc((size_t)ET * sizeof(int));
    float* scores = (float*)alloc((size_t)N * sizeof(float));
    float* cvec   = (float*)alloc(128 * sizeof(float));
    unsigned* gmaxb = (unsigned*)alloc(256);
    float* sumexp   = (float*)alloc(256);

    float* out_h = (float*)d_out;             // [N*128]
    float* out_s = out_h + (size_t)N * 128;   // [N]

    const int tb = 256;
    k_init<<<(N + tb - 1) / tb, tb, 0, stream>>>(deg, gmaxb, sumexp, N);
    k_count<<<(E + tb - 1) / tb, tb, 0, stream>>>(edst, deg, E);
    k_scan<<<1, 1024, 0, stream>>>(deg, rowst, N);
    k_selfloop<<<(N + tb - 1) / tb, tb, 0, stream>>>(rowst, cursor, adjl, N);
    k_scatter<<<(E + tb - 1) / tb, tb, 0, stream>>>(esrc, edst, cursor, adjl, E);

    const int ngrp = (N + 63) / 64;
    const int gb = (ngrp < 512) ? ngrp : 512;

    // layer 1: heads=2  (x f32 -> h1 bf16)
    k_gemm_mfma<2, float><<<gb, 256, 0, stream>>>(x, W1, as1, ad1, hbufA, asrc1, adst1, N, ngrp);
    k_agg<2, u16><<<N, 128, 0, stream>>>(rowst, adjl, asrc1, adst1, hbufA, b1, hbufB, N);

    // layer 2: heads=1  (h1 bf16 -> h2 f32 into d_out)
    k_gemm_mfma<1, u16><<<gb, 256, 0, stream>>>(hbufB, W2, as2, ad2, hbufA, asrc2, adst2, N, ngrp);
    k_agg<1, float><<<N, 128, 0, stream>>>(rowst, adjl, asrc2, adst2, hbufA, b2, out_h, N);

    // score head
    k_cvec<<<1, 128, 0, stream>>>(q, Wq1, bq1, cvec);
    k_score_mfma<<<gb, 256, 0, stream>>>(out_h, Wq1, Wq2, bq2, cvec, scores, gmaxb, N, ngrp);
    k_sumexp<<<(N + tb - 1) / tb, tb, 0, stream>>>(scores, gmaxb, sumexp, N);
    k_final<<<(N + tb - 1) / tb, tb, 0, stream>>>(scores, sumexp, out_s, N);
}

// Round 8
// 293.448 us; speedup vs baseline: 4.7806x; 1.2404x over previous
//
#include <hip/hip_runtime.h>
#include <hip/hip_bf16.h>

typedef unsigned short u16;
typedef __attribute__((ext_vector_type(8))) short bf16x8;
typedef __attribute__((ext_vector_type(4))) float f32x4;

#define LEAKY 0.2f

__device__ __forceinline__ float bu2f(u16 v) {
    return __uint_as_float(((unsigned)v) << 16);
}
__device__ __forceinline__ u16 f2bu(float f) {
    unsigned u = __float_as_uint(f);
    unsigned r = (u + 0x7FFFu + ((u >> 16) & 1u)) >> 16;
    return (u16)r;
}
__device__ __forceinline__ unsigned fmapu(float f) {
    unsigned u = __float_as_uint(f);
    return (u & 0x80000000u) ? ~u : (u | 0x80000000u);
}
__device__ __forceinline__ float funmapu(unsigned u) {
    return __uint_as_float((u & 0x80000000u) ? (u & 0x7FFFFFFFu) : ~u);
}

// ---------------- CSR build ----------------

__global__ void k_init(int* deg, unsigned* gmaxb, float* sumexp, int N) {
    int i = blockIdx.x * blockDim.x + threadIdx.x;
    if (i < N) deg[i] = 1;  // self loop
    if (i == 0) { *gmaxb = 0u; *sumexp = 0.f; }
}

__global__ void k_count(const int* __restrict__ dst, int* __restrict__ deg, int E) {
    int i = blockIdx.x * blockDim.x + threadIdx.x;
    if (i < E) atomicAdd(&deg[dst[i]], 1);
}

// ---- hierarchical exclusive scan of deg -> rowst (rowst[N] = total) ----
// scan1: per-1024-block sums; scan2: exclusive scan of block sums (1 wave);
// scan3: local scan + block offset -> rowst.

__global__ __launch_bounds__(256) void k_scan1(const int* __restrict__ deg,
                                               int* __restrict__ bsum, int N) {
    int b = blockIdx.x;
    int t = threadIdx.x;
    int base = b * 1024;
    int s = 0;
    for (int i = t; i < 1024; i += 256) {
        int idx = base + i;
        if (idx < N) s += deg[idx];
    }
#pragma unroll
    for (int o = 32; o > 0; o >>= 1) s += __shfl_down(s, o);
    __shared__ int ws[4];
    if ((t & 63) == 0) ws[t >> 6] = s;
    __syncthreads();
    if (t == 0) bsum[b] = ws[0] + ws[1] + ws[2] + ws[3];
}

__global__ void k_scan2(int* __restrict__ bsum, int nb) {
    int t = threadIdx.x;   // 64 threads
    if (nb <= 64) {
        int orig = (t < nb) ? bsum[t] : 0;
        int v = orig;
#pragma unroll
        for (int o = 1; o < 64; o <<= 1) {
            int u = __shfl_up(v, o);
            if (t >= o) v += u;
        }
        if (t < nb) bsum[t] = v - orig;  // exclusive
    } else {
        if (t == 0) {
            int run = 0;
            for (int i = 0; i < nb; ++i) { int v = bsum[i]; bsum[i] = run; run += v; }
        }
    }
}

__global__ __launch_bounds__(256) void k_scan3(const int* __restrict__ deg,
                                               const int* __restrict__ bsum,
                                               int* __restrict__ rowst, int N) {
    int b = blockIdx.x;
    int t = threadIdx.x;
    int l = t & 63;
    int wv = t >> 6;
    int idx0 = b * 1024 + t * 4;
    int d[4];
#pragma unroll
    for (int j = 0; j < 4; ++j) d[j] = (idx0 + j < N) ? deg[idx0 + j] : 0;
    int s = d[0] + d[1] + d[2] + d[3];
    int orig = s;
    int v = s;
#pragma unroll
    for (int o = 1; o < 64; o <<= 1) {
        int u = __shfl_up(v, o);
        if (l >= o) v += u;
    }
    __shared__ int wsum[4];
    if (l == 63) wsum[wv] = v;
    __syncthreads();
    int woff = 0;
    for (int w = 0; w < wv; ++w) woff += wsum[w];
    int run = v - orig + woff + bsum[b];
#pragma unroll
    for (int j = 0; j < 4; ++j) {
        if (idx0 + j < N) rowst[idx0 + j] = run;
        run += d[j];
    }
    if (idx0 <= N - 1 && N - 1 < idx0 + 4) rowst[N] = run;
}

__global__ void k_selfloop(const int* __restrict__ rowst, int* __restrict__ cursor,
                           int* __restrict__ adj, int N) {
    int i = blockIdx.x * blockDim.x + threadIdx.x;
    if (i < N) {
        int p = rowst[i];
        adj[p] = i;          // self loop first
        cursor[i] = p + 1;
    }
}

__global__ void k_scatter(const int* __restrict__ src, const int* __restrict__ dst,
                          int* __restrict__ cursor, int* __restrict__ adj, int E) {
    int i = blockIdx.x * blockDim.x + threadIdx.x;
    if (i < E) {
        int pos = atomicAdd(&cursor[dst[i]], 1);
        adj[pos] = src[i];
    }
}

// ---------------- MFMA GEMM (N x 128) @ (128 x 128) + attention-coef epilogue ----------------

template <int H, typename TIN>
__global__ __launch_bounds__(256, 2) void k_gemm_mfma(
    const TIN* __restrict__ in, const float* __restrict__ W,
    const float* __restrict__ att_s, const float* __restrict__ att_d,
    u16* __restrict__ out, float* __restrict__ a_src, float* __restrict__ a_dst,
    int N, int ngrp) {
    int t = threadIdx.x;
    int l = t & 63;
    int wv = t >> 6;        // wave 0..3
    int l16 = l & 15;
    int lk = l >> 4;        // 0..3

    bf16x8 b[4][8];
#pragma unroll
    for (int ks = 0; ks < 4; ++ks) {
#pragma unroll
        for (int n = 0; n < 8; ++n) {
            int kbase = ks * 32 + lk * 8;
            int col = n * 16 + l16;
            bf16x8 bb;
#pragma unroll
            for (int j = 0; j < 8; ++j) bb[j] = (short)f2bu(W[(size_t)(kbase + j) * 128 + col]);
            b[ks][n] = bb;
        }
    }
    float atts[8], attd[8];
#pragma unroll
    for (int n = 0; n < 8; ++n) {
        atts[n] = att_s[n * 16 + l16];
        attd[n] = att_d[n * 16 + l16];
    }

    for (int g = blockIdx.x; g < ngrp; g += gridDim.x) {
        int rowbase = g * 64 + wv * 16;
        f32x4 acc[8];
#pragma unroll
        for (int n = 0; n < 8; ++n) acc[n] = (f32x4){0.f, 0.f, 0.f, 0.f};
        int ra = rowbase + l16;   // A-row this lane feeds
#pragma unroll
        for (int ks = 0; ks < 4; ++ks) {
            bf16x8 a;
            if (ra < N) {
                if constexpr (sizeof(TIN) == 4) {
                    const float4* pf = (const float4*)((const float*)in + (size_t)ra * 128 + ks * 32 + lk * 8);
                    float4 p0 = pf[0], p1 = pf[1];
                    a[0] = (short)f2bu(p0.x); a[1] = (short)f2bu(p0.y);
                    a[2] = (short)f2bu(p0.z); a[3] = (short)f2bu(p0.w);
                    a[4] = (short)f2bu(p1.x); a[5] = (short)f2bu(p1.y);
                    a[6] = (short)f2bu(p1.z); a[7] = (short)f2bu(p1.w);
                } else {
                    a = *(const bf16x8*)((const u16*)in + (size_t)ra * 128 + ks * 32 + lk * 8);
                }
            } else {
                a = (bf16x8){0, 0, 0, 0, 0, 0, 0, 0};
            }
#pragma unroll
            for (int n = 0; n < 8; ++n)
                acc[n] = __builtin_amdgcn_mfma_f32_16x16x32_bf16(a, b[ks][n], acc[n], 0, 0, 0);
        }
        // store h
#pragma unroll
        for (int n = 0; n < 8; ++n) {
#pragma unroll
            for (int i = 0; i < 4; ++i) {
                int r = rowbase + lk * 4 + i;
                if (r < N) out[(size_t)r * 128 + n * 16 + l16] = f2bu(acc[n][i]);
            }
        }
        // attention-coef row sums
#pragma unroll
        for (int i = 0; i < 4; ++i) {
            int r = rowbase + lk * 4 + i;
            if (H == 2) {
                float s0 = 0.f, s1 = 0.f, d0 = 0.f, d1 = 0.f;
#pragma unroll
                for (int n = 0; n < 4; ++n) { s0 += acc[n][i] * atts[n]; d0 += acc[n][i] * attd[n]; }
#pragma unroll
                for (int n = 4; n < 8; ++n) { s1 += acc[n][i] * atts[n]; d1 += acc[n][i] * attd[n]; }
#pragma unroll
                for (int o = 1; o < 16; o <<= 1) {
                    s0 += __shfl_xor(s0, o); d0 += __shfl_xor(d0, o);
                    s1 += __shfl_xor(s1, o); d1 += __shfl_xor(d1, o);
                }
                if (l16 == 0 && r < N) {
                    a_src[(size_t)r * 2 + 0] = s0; a_src[(size_t)r * 2 + 1] = s1;
                    a_dst[(size_t)r * 2 + 0] = d0; a_dst[(size_t)r * 2 + 1] = d1;
                }
            } else {
                float s0 = 0.f, d0 = 0.f;
#pragma unroll
                for (int n = 0; n < 8; ++n) { s0 += acc[n][i] * atts[n]; d0 += acc[n][i] * attd[n]; }
#pragma unroll
                for (int o = 1; o < 16; o <<= 1) {
                    s0 += __shfl_xor(s0, o); d0 += __shfl_xor(d0, o);
                }
                if (l16 == 0 && r < N) { a_src[r] = s0; a_dst[r] = d0; }
            }
        }
    }
}

// ---------------- per-node segment softmax + aggregation (online, wave-parallel) ----------------

template <int H, typename TOUT>
__global__ __launch_bounds__(128) void k_agg(
    const int* __restrict__ rowst, const int* __restrict__ adj,
    const float* __restrict__ a_src, const float* __restrict__ a_dst,
    const u16* __restrict__ h_in, const float* __restrict__ bias,
    TOUT* __restrict__ out, int N) {
    int n = blockIdx.x;
    if (n >= N) return;
    const int Ch = 128 / H;
    int c = threadIdx.x;
    int w = c >> 6;
    int l = c & 63;
    int h = c / Ch;
    int hh = (H == 2) ? w : 0;
    __shared__ float sm_m[H], sm_s[H], sscale[H], asd[H];
    __shared__ int srcs[64];
    __shared__ float pv[H][64];
    if (c < H) {
        sm_m[c] = -1e30f; sm_s[c] = 0.f;
        asd[c] = a_dst[(size_t)n * H + c];
    }
    float acc = 0.f;
    int rs = rowst[n], re = rowst[n + 1];
    __syncthreads();
    for (int base = rs; base < re; base += 64) {
        int cnt = min(64, re - base);
        if (c < cnt) srcs[c] = adj[base + c];
        __syncthreads();
        bool active = (H == 2) || (w == 0);
        bool ok = active && (l < cnt);
        float xv = -1e30f;
        if (ok) {
            float v = a_src[(size_t)srcs[l] * H + hh] + asd[hh];
            xv = (v > 0.f) ? v : LEAKY * v;
        }
        float lm = xv;
#pragma unroll
        for (int o = 32; o > 0; o >>= 1) lm = fmaxf(lm, __shfl_xor(lm, o));
        float mx = fmaxf(sm_m[hh], lm);
        float pe = ok ? __expf(xv - mx) : 0.f;
        float sum = pe;
#pragma unroll
        for (int o = 32; o > 0; o >>= 1) sum += __shfl_xor(sum, o);
        if (active) {
            pv[hh][l] = pe;
            if (l == 0) {
                float sc = __expf(sm_m[hh] - mx);
                sscale[hh] = sc;
                sm_s[hh] = sm_s[hh] * sc + sum;
                sm_m[hh] = mx;
            }
        }
        __syncthreads();
        acc *= sscale[h];
        for (int e = 0; e < cnt; ++e) {
            acc += pv[h][e] * bu2f(h_in[(size_t)srcs[e] * 128 + c]);
        }
        __syncthreads();
    }
    float val = acc / (sm_s[h] + 1e-16f) + bias[c];
    if constexpr (sizeof(TOUT) == 2) {
        out[(size_t)n * 128 + c] = (TOUT)f2bu(val);
    } else {
        out[(size_t)n * 128 + c] = (TOUT)val;
    }
}

// ---------------- score head ----------------

__global__ void k_cvec(const float* __restrict__ q, const float* __restrict__ Wq1,
                       const float* __restrict__ bq1, float* __restrict__ cvec) {
    int j = threadIdx.x;  // 128 threads
    float acc = bq1[j];
    for (int k = 0; k < 384; ++k) acc += q[k] * Wq1[(size_t)(128 + k) * 128 + j];
    cvec[j] = acc;
}

__global__ __launch_bounds__(256, 2) void k_score_mfma(
    const float* __restrict__ h2, const float* __restrict__ Wq1, const float* __restrict__ Wq2,
    const float* __restrict__ bq2, const float* __restrict__ cvec,
    float* __restrict__ scores, unsigned* __restrict__ gmaxb, int N, int ngrp) {
    int t = threadIdx.x;
    int l = t & 63;
    int wv = t >> 6;
    int l16 = l & 15;
    int lk = l >> 4;

    bf16x8 b[4][8];
#pragma unroll
    for (int ks = 0; ks < 4; ++ks) {
#pragma unroll
        for (int n = 0; n < 8; ++n) {
            int kbase = ks * 32 + lk * 8;
            int col = n * 16 + l16;
            bf16x8 bb;
#pragma unroll
            for (int j = 0; j < 8; ++j) bb[j] = (short)f2bu(Wq1[(size_t)(kbase + j) * 128 + col]);
            b[ks][n] = bb;
        }
    }
    float cva[8], w2a[8];
#pragma unroll
    for (int n = 0; n < 8; ++n) {
        cva[n] = cvec[n * 16 + l16];
        w2a[n] = Wq2[n * 16 + l16];
    }
    float bq2v = bq2[0];
    float lmax = -1e30f;

    for (int g = blockIdx.x; g < ngrp; g += gridDim.x) {
        int rowbase = g * 64 + wv * 16;
        f32x4 acc[8];
#pragma unroll
        for (int n = 0; n < 8; ++n) acc[n] = (f32x4){0.f, 0.f, 0.f, 0.f};
        int ra = rowbase + l16;
#pragma unroll
        for (int ks = 0; ks < 4; ++ks) {
            bf16x8 a;
            if (ra < N) {
                const float4* pf = (const float4*)(h2 + (size_t)ra * 128 + ks * 32 + lk * 8);
                float4 p0 = pf[0], p1 = pf[1];
                a[0] = (short)f2bu(p0.x); a[1] = (short)f2bu(p0.y);
                a[2] = (short)f2bu(p0.z); a[3] = (short)f2bu(p0.w);
                a[4] = (short)f2bu(p1.x); a[5] = (short)f2bu(p1.y);
                a[6] = (short)f2bu(p1.z); a[7] = (short)f2bu(p1.w);
            } else {
                a = (bf16x8){0, 0, 0, 0, 0, 0, 0, 0};
            }
#pragma unroll
            for (int n = 0; n < 8; ++n)
                acc[n] = __builtin_amdgcn_mfma_f32_16x16x32_bf16(a, b[ks][n], acc[n], 0, 0, 0);
        }
#pragma unroll
        for (int i = 0; i < 4; ++i) {
            int r = rowbase + lk * 4 + i;
            float s = 0.f;
#pragma unroll
            for (int n = 0; n < 8; ++n) s += fmaxf(acc[n][i] + cva[n], 0.f) * w2a[n];
#pragma unroll
            for (int o = 1; o < 16; o <<= 1) s += __shfl_xor(s, o);
            if (l16 == 0 && r < N) {
                float sc = s + bq2v;
                scores[r] = sc;
                lmax = fmaxf(lmax, sc);
            }
        }
    }
#pragma unroll
    for (int o = 1; o < 64; o <<= 1) lmax = fmaxf(lmax, __shfl_xor(lmax, o));
    __shared__ float bmax[4];
    if (l == 0) bmax[wv] = lmax;
    __syncthreads();
    if (t == 0)
        atomicMax(gmaxb, fmapu(fmaxf(fmaxf(bmax[0], bmax[1]), fmaxf(bmax[2], bmax[3]))));
}

__global__ void k_sumexp(float* __restrict__ scores, const unsigned* __restrict__ gmaxb,
                         float* __restrict__ sumexp, int N) {
    int i = blockIdx.x * blockDim.x + threadIdx.x;
    float gmax = funmapu(*gmaxb);
    float p = 0.f;
    if (i < N) {
        p = __expf(scores[i] - gmax);
        scores[i] = p;
    }
#pragma unroll
    for (int o = 32; o > 0; o >>= 1) p += __shfl_down(p, o);
    __shared__ float ws_[4];
    if ((threadIdx.x & 63) == 0) ws_[threadIdx.x >> 6] = p;
    __syncthreads();
    if (threadIdx.x == 0) atomicAdd(sumexp, ws_[0] + ws_[1] + ws_[2] + ws_[3]);
}

__global__ void k_final(const float* __restrict__ scores, const float* __restrict__ sumexp,
                        float* __restrict__ out_s, int N) {
    int i = blockIdx.x * blockDim.x + threadIdx.x;
    if (i < N) out_s[i] = scores[i] / *sumexp;
}

// ---------------- launch ----------------

extern "C" void kernel_launch(void* const* d_in, const int* in_sizes, int n_in,
                              void* d_out, int out_size, void* d_ws, size_t ws_size,
                              hipStream_t stream) {
    const float* x   = (const float*)d_in[0];
    const int*   ei  = (const int*)d_in[1];
    const float* q   = (const float*)d_in[3];
    const float* W1  = (const float*)d_in[4];
    const float* as1 = (const float*)d_in[5];
    const float* ad1 = (const float*)d_in[6];
    const float* b1  = (const float*)d_in[7];
    const float* W2  = (const float*)d_in[8];
    const float* as2 = (const float*)d_in[9];
    const float* ad2 = (const float*)d_in[10];
    const float* b2  = (const float*)d_in[11];
    const float* Wq1 = (const float*)d_in[12];
    const float* bq1 = (const float*)d_in[13];
    const float* Wq2 = (const float*)d_in[14];
    const float* bq2 = (const float*)d_in[15];

    const int N = in_sizes[0] / 128;
    const int E = in_sizes[1] / 2;
    const int ET = E + N;
    const int* esrc = ei;
    const int* edst = ei + E;

    char* p = (char*)d_ws;
    auto alloc = [&](size_t bytes) -> char* {
        char* r = p;
        p += (bytes + 255) & ~(size_t)255;
        return r;
    };
    u16*   hbufA  = (u16*)alloc((size_t)N * 128 * sizeof(u16));  // gemm outputs (bf16)
    u16*   hbufB  = (u16*)alloc((size_t)N * 128 * sizeof(u16));  // layer-1 result (bf16)
    float* asrc1  = (float*)alloc((size_t)N * 2 * sizeof(float));
    float* adst1  = (float*)alloc((size_t)N * 2 * sizeof(float));
    float* asrc2  = (float*)alloc((size_t)N * sizeof(float));
    float* adst2  = (float*)alloc((size_t)N * sizeof(float));
    int*   deg    = (int*)alloc((size_t)N * sizeof(int));
    int*   rowst  = (int*)alloc((size_t)(N + 1) * sizeof(int));
    int*   cursor = (int*)alloc((size_t)N * sizeof(int));
    int*   adjl   = (int*)alloc((size_t)ET * sizeof(int));
    float* scores = (float*)alloc((size_t)N * sizeof(float));
    float* cvec   = (float*)alloc(128 * sizeof(float));
    int*   bsum   = (int*)alloc(((size_t)(N + 1023) / 1024 + 64) * sizeof(int));
    unsigned* gmaxb = (unsigned*)alloc(256);
    float* sumexp   = (float*)alloc(256);

    float* out_h = (float*)d_out;             // [N*128]
    float* out_s = out_h + (size_t)N * 128;   // [N]

    const int tb = 256;
    const int nb = (N + 1023) / 1024;
    k_init<<<(N + tb - 1) / tb, tb, 0, stream>>>(deg, gmaxb, sumexp, N);
    k_count<<<(E + tb - 1) / tb, tb, 0, stream>>>(edst, deg, E);
    k_scan1<<<nb, 256, 0, stream>>>(deg, bsum, N);
    k_scan2<<<1, 64, 0, stream>>>(bsum, nb);
    k_scan3<<<nb, 256, 0, stream>>>(deg, bsum, rowst, N);
    k_selfloop<<<(N + tb - 1) / tb, tb, 0, stream>>>(rowst, cursor, adjl, N);
    k_scatter<<<(E + tb - 1) / tb, tb, 0, stream>>>(esrc, edst, cursor, adjl, E);

    const int ngrp = (N + 63) / 64;
    const int gb = (ngrp < 512) ? ngrp : 512;

    // layer 1: heads=2  (x f32 -> h1 bf16)
    k_gemm_mfma<2, float><<<gb, 256, 0, stream>>>(x, W1, as1, ad1, hbufA, asrc1, adst1, N, ngrp);
    k_agg<2, u16><<<N, 128, 0, stream>>>(rowst, adjl, asrc1, adst1, hbufA, b1, hbufB, N);

    // layer 2: heads=1  (h1 bf16 -> h2 f32 into d_out)
    k_gemm_mfma<1, u16><<<gb, 256, 0, stream>>>(hbufB, W2, as2, ad2, hbufA, asrc2, adst2, N, ngrp);
    k_agg<1, float><<<N, 128, 0, stream>>>(rowst, adjl, asrc2, adst2, hbufA, b2, out_h, N);

    // score head
    k_cvec<<<1, 128, 0, stream>>>(q, Wq1, bq1, cvec);
    k_score_mfma<<<gb, 256, 0, stream>>>(out_h, Wq1, Wq2, bq2, cvec, scores, gmaxb, N, ngrp);
    k_sumexp<<<(N + tb - 1) / tb, tb, 0, stream>>>(scores, gmaxb, sumexp, N);
    k_final<<<(N + tb - 1) / tb, tb, 0, stream>>>(scores, sumexp, out_s, N);
}

// Round 9
// 288.405 us; speedup vs baseline: 4.8642x; 1.0175x over previous
//
#include <hip/hip_runtime.h>
#include <hip/hip_bf16.h>

typedef unsigned short u16;
typedef __attribute__((ext_vector_type(8))) short bf16x8;
typedef __attribute__((ext_vector_type(4))) float f32x4;

#define LEAKY 0.2f

__device__ __forceinline__ float bu2f(u16 v) {
    return __uint_as_float(((unsigned)v) << 16);
}
__device__ __forceinline__ u16 f2bu(float f) {
    unsigned u = __float_as_uint(f);
    unsigned r = (u + 0x7FFFu + ((u >> 16) & 1u)) >> 16;
    return (u16)r;
}
__device__ __forceinline__ unsigned fmapu(float f) {
    unsigned u = __float_as_uint(f);
    return (u & 0x80000000u) ? ~u : (u | 0x80000000u);
}
__device__ __forceinline__ float funmapu(unsigned u) {
    return __uint_as_float((u & 0x80000000u) ? (u & 0x7FFFFFFFu) : ~u);
}

// ---------------- CSR build ----------------

__global__ void k_init(int* deg, unsigned* gmaxb, float* sumexp, int N) {
    int i = blockIdx.x * blockDim.x + threadIdx.x;
    if (i < N) deg[i] = 1;  // self loop
    if (i == 0) { *gmaxb = 0u; *sumexp = 0.f; }
}

__global__ void k_count(const int* __restrict__ dst, int* __restrict__ deg, int E) {
    int i = blockIdx.x * blockDim.x + threadIdx.x;
    if (i < E) atomicAdd(&deg[dst[i]], 1);
}

// ---- hierarchical exclusive scan of deg -> rowst (rowst[N] = total) ----

__global__ __launch_bounds__(256) void k_scan1(const int* __restrict__ deg,
                                               int* __restrict__ bsum, int N) {
    int b = blockIdx.x;
    int t = threadIdx.x;
    int base = b * 1024;
    int s = 0;
    for (int i = t; i < 1024; i += 256) {
        int idx = base + i;
        if (idx < N) s += deg[idx];
    }
#pragma unroll
    for (int o = 32; o > 0; o >>= 1) s += __shfl_down(s, o);
    __shared__ int ws[4];
    if ((t & 63) == 0) ws[t >> 6] = s;
    __syncthreads();
    if (t == 0) bsum[b] = ws[0] + ws[1] + ws[2] + ws[3];
}

__global__ void k_scan2(int* __restrict__ bsum, int nb) {
    int t = threadIdx.x;   // 64 threads
    if (nb <= 64) {
        int orig = (t < nb) ? bsum[t] : 0;
        int v = orig;
#pragma unroll
        for (int o = 1; o < 64; o <<= 1) {
            int u = __shfl_up(v, o);
            if (t >= o) v += u;
        }
        if (t < nb) bsum[t] = v - orig;  // exclusive
    } else {
        if (t == 0) {
            int run = 0;
            for (int i = 0; i < nb; ++i) { int v = bsum[i]; bsum[i] = run; run += v; }
        }
    }
}

__global__ __launch_bounds__(256) void k_scan3(const int* __restrict__ deg,
                                               const int* __restrict__ bsum,
                                               int* __restrict__ rowst, int N) {
    int b = blockIdx.x;
    int t = threadIdx.x;
    int l = t & 63;
    int wv = t >> 6;
    int idx0 = b * 1024 + t * 4;
    int d[4];
#pragma unroll
    for (int j = 0; j < 4; ++j) d[j] = (idx0 + j < N) ? deg[idx0 + j] : 0;
    int s = d[0] + d[1] + d[2] + d[3];
    int orig = s;
    int v = s;
#pragma unroll
    for (int o = 1; o < 64; o <<= 1) {
        int u = __shfl_up(v, o);
        if (l >= o) v += u;
    }
    __shared__ int wsum[4];
    if (l == 63) wsum[wv] = v;
    __syncthreads();
    int woff = 0;
    for (int w = 0; w < wv; ++w) woff += wsum[w];
    int run = v - orig + woff + bsum[b];
#pragma unroll
    for (int j = 0; j < 4; ++j) {
        if (idx0 + j < N) rowst[idx0 + j] = run;
        run += d[j];
    }
    if (idx0 <= N - 1 && N - 1 < idx0 + 4) rowst[N] = run;
}

__global__ void k_selfloop(const int* __restrict__ rowst, int* __restrict__ cursor,
                           int* __restrict__ adj, int N) {
    int i = blockIdx.x * blockDim.x + threadIdx.x;
    if (i < N) {
        int p = rowst[i];
        adj[p] = i;          // self loop first
        cursor[i] = p + 1;
    }
}

__global__ void k_scatter(const int* __restrict__ src, const int* __restrict__ dst,
                          int* __restrict__ cursor, int* __restrict__ adj, int E) {
    int i = blockIdx.x * blockDim.x + threadIdx.x;
    if (i < E) {
        int pos = atomicAdd(&cursor[dst[i]], 1);
        adj[pos] = src[i];
    }
}

// ---------------- MFMA GEMM (N x 128) @ (128 x 128) + attention-coef epilogue ----------------

template <int H, typename TIN>
__global__ __launch_bounds__(256, 2) void k_gemm_mfma(
    const TIN* __restrict__ in, const float* __restrict__ W,
    const float* __restrict__ att_s, const float* __restrict__ att_d,
    u16* __restrict__ out, float* __restrict__ a_src, float* __restrict__ a_dst,
    int N, int ngrp) {
    int t = threadIdx.x;
    int l = t & 63;
    int wv = t >> 6;        // wave 0..3
    int l16 = l & 15;
    int lk = l >> 4;        // 0..3

    bf16x8 b[4][8];
#pragma unroll
    for (int ks = 0; ks < 4; ++ks) {
#pragma unroll
        for (int n = 0; n < 8; ++n) {
            int kbase = ks * 32 + lk * 8;
            int col = n * 16 + l16;
            bf16x8 bb;
#pragma unroll
            for (int j = 0; j < 8; ++j) bb[j] = (short)f2bu(W[(size_t)(kbase + j) * 128 + col]);
            b[ks][n] = bb;
        }
    }
    float atts[8], attd[8];
#pragma unroll
    for (int n = 0; n < 8; ++n) {
        atts[n] = att_s[n * 16 + l16];
        attd[n] = att_d[n * 16 + l16];
    }

    for (int g = blockIdx.x; g < ngrp; g += gridDim.x) {
        int rowbase = g * 64 + wv * 16;
        f32x4 acc[8];
#pragma unroll
        for (int n = 0; n < 8; ++n) acc[n] = (f32x4){0.f, 0.f, 0.f, 0.f};
        int ra = rowbase + l16;   // A-row this lane feeds
#pragma unroll
        for (int ks = 0; ks < 4; ++ks) {
            bf16x8 a;
            if (ra < N) {
                if constexpr (sizeof(TIN) == 4) {
                    const float4* pf = (const float4*)((const float*)in + (size_t)ra * 128 + ks * 32 + lk * 8);
                    float4 p0 = pf[0], p1 = pf[1];
                    a[0] = (short)f2bu(p0.x); a[1] = (short)f2bu(p0.y);
                    a[2] = (short)f2bu(p0.z); a[3] = (short)f2bu(p0.w);
                    a[4] = (short)f2bu(p1.x); a[5] = (short)f2bu(p1.y);
                    a[6] = (short)f2bu(p1.z); a[7] = (short)f2bu(p1.w);
                } else {
                    a = *(const bf16x8*)((const u16*)in + (size_t)ra * 128 + ks * 32 + lk * 8);
                }
            } else {
                a = (bf16x8){0, 0, 0, 0, 0, 0, 0, 0};
            }
#pragma unroll
            for (int n = 0; n < 8; ++n)
                acc[n] = __builtin_amdgcn_mfma_f32_16x16x32_bf16(a, b[ks][n], acc[n], 0, 0, 0);
        }
        // store h
#pragma unroll
        for (int n = 0; n < 8; ++n) {
#pragma unroll
            for (int i = 0; i < 4; ++i) {
                int r = rowbase + lk * 4 + i;
                if (r < N) out[(size_t)r * 128 + n * 16 + l16] = f2bu(acc[n][i]);
            }
        }
        // attention-coef row sums
#pragma unroll
        for (int i = 0; i < 4; ++i) {
            int r = rowbase + lk * 4 + i;
            if (H == 2) {
                float s0 = 0.f, s1 = 0.f, d0 = 0.f, d1 = 0.f;
#pragma unroll
                for (int n = 0; n < 4; ++n) { s0 += acc[n][i] * atts[n]; d0 += acc[n][i] * attd[n]; }
#pragma unroll
                for (int n = 4; n < 8; ++n) { s1 += acc[n][i] * atts[n]; d1 += acc[n][i] * attd[n]; }
#pragma unroll
                for (int o = 1; o < 16; o <<= 1) {
                    s0 += __shfl_xor(s0, o); d0 += __shfl_xor(d0, o);
                    s1 += __shfl_xor(s1, o); d1 += __shfl_xor(d1, o);
                }
                if (l16 == 0 && r < N) {
                    a_src[(size_t)r * 2 + 0] = s0; a_src[(size_t)r * 2 + 1] = s1;
                    a_dst[(size_t)r * 2 + 0] = d0; a_dst[(size_t)r * 2 + 1] = d1;
                }
            } else {
                float s0 = 0.f, d0 = 0.f;
#pragma unroll
                for (int n = 0; n < 8; ++n) { s0 += acc[n][i] * atts[n]; d0 += acc[n][i] * attd[n]; }
#pragma unroll
                for (int o = 1; o < 16; o <<= 1) {
                    s0 += __shfl_xor(s0, o); d0 += __shfl_xor(d0, o);
                }
                if (l16 == 0 && r < N) { a_src[r] = s0; a_dst[r] = d0; }
            }
        }
    }
}

// ---------------- per-node segment softmax + aggregation ----------------
// Phase A: wave-parallel online softmax (wave per head).
// Phase B: 4 edge-groups x 32 lanes, ushort4 (8B) gathers, 4 edges in flight;
//          per-group partial acc combined via LDS at the end.

template <int H, typename TOUT>
__global__ __launch_bounds__(128) void k_agg(
    const int* __restrict__ rowst, const int* __restrict__ adj,
    const float* __restrict__ a_src, const float* __restrict__ a_dst,
    const u16* __restrict__ h_in, const float* __restrict__ bias,
    TOUT* __restrict__ out, int N) {
    int n = blockIdx.x;
    if (n >= N) return;
    const int Ch = 128 / H;
    int c = threadIdx.x;
    int w = c >> 6;
    int l = c & 63;
    int h = c / Ch;             // head of channel c (final combine)
    int hh = (H == 2) ? w : 0;  // head this wave softmaxes for
    int g = c >> 5;             // edge-group 0..3
    int li = c & 31;            // lane in group; channels li*4..li*4+3
    int h4 = (H == 2) ? (li >> 4) : 0;  // head of this thread's 4 channels
    __shared__ float sm_m[H], sm_s[H], sscale[H], asd[H];
    __shared__ int srcs[64];
    __shared__ float pv[H][64];
    __shared__ float accbuf[4][128];
    if (c < H) {
        sm_m[c] = -1e30f; sm_s[c] = 0.f;
        asd[c] = a_dst[(size_t)n * H + c];
    }
    if (c < 64) srcs[c] = 0;
    float a0 = 0.f, a1 = 0.f, a2 = 0.f, a3 = 0.f;
    int rs = rowst[n], re = rowst[n + 1];
    __syncthreads();
    for (int base = rs; base < re; base += 64) {
        int cnt = min(64, re - base);
        if (c < cnt) srcs[c] = adj[base + c];
        __syncthreads();
        // ---- phase A: online softmax ----
        bool active = (H == 2) || (w == 0);
        bool ok = active && (l < cnt);
        float xv = -1e30f;
        if (ok) {
            float v = a_src[(size_t)srcs[l] * H + hh] + asd[hh];
            xv = (v > 0.f) ? v : LEAKY * v;
        }
        float lm = xv;
#pragma unroll
        for (int o = 32; o > 0; o >>= 1) lm = fmaxf(lm, __shfl_xor(lm, o));
        float mx = fmaxf(sm_m[hh], lm);
        float pe = ok ? __expf(xv - mx) : 0.f;
        float sum = pe;
#pragma unroll
        for (int o = 32; o > 0; o >>= 1) sum += __shfl_xor(sum, o);
        if (active) {
            pv[hh][l] = pe;
            if (l == 0) {
                float sc = __expf(sm_m[hh] - mx);
                sscale[hh] = sc;
                sm_s[hh] = sm_s[hh] * sc + sum;
                sm_m[hh] = mx;
            }
        }
        __syncthreads();
        // ---- phase B: vectorized gather, 4 edges in flight ----
        float sc4 = sscale[h4];
        a0 *= sc4; a1 *= sc4; a2 *= sc4; a3 *= sc4;
        for (int e4 = 0; e4 < cnt; e4 += 4) {
            int e = e4 + g;                 // <= 63 always
            float pe_ = pv[h4][e];          // 0 for e >= cnt
            int s = srcs[e];                // valid node id even when stale
            ushort4 v = *(const ushort4*)(h_in + (size_t)s * 128 + li * 4);
            a0 += pe_ * bu2f(v.x);
            a1 += pe_ * bu2f(v.y);
            a2 += pe_ * bu2f(v.z);
            a3 += pe_ * bu2f(v.w);
        }
        __syncthreads();
    }
    accbuf[g][li * 4 + 0] = a0;
    accbuf[g][li * 4 + 1] = a1;
    accbuf[g][li * 4 + 2] = a2;
    accbuf[g][li * 4 + 3] = a3;
    __syncthreads();
    float val = (accbuf[0][c] + accbuf[1][c] + accbuf[2][c] + accbuf[3][c])
                / (sm_s[h] + 1e-16f) + bias[c];
    if constexpr (sizeof(TOUT) == 2) {
        out[(size_t)n * 128 + c] = (TOUT)f2bu(val);
    } else {
        out[(size_t)n * 128 + c] = (TOUT)val;
    }
}

// ---------------- score head ----------------

__global__ void k_cvec(const float* __restrict__ q, const float* __restrict__ Wq1,
                       const float* __restrict__ bq1, float* __restrict__ cvec) {
    int j = threadIdx.x;  // 128 threads
    float acc = bq1[j];
    for (int k = 0; k < 384; ++k) acc += q[k] * Wq1[(size_t)(128 + k) * 128 + j];
    cvec[j] = acc;
}

__global__ __launch_bounds__(256, 2) void k_score_mfma(
    const float* __restrict__ h2, const float* __restrict__ Wq1, const float* __restrict__ Wq2,
    const float* __restrict__ bq2, const float* __restrict__ cvec,
    float* __restrict__ scores, unsigned* __restrict__ gmaxb, int N, int ngrp) {
    int t = threadIdx.x;
    int l = t & 63;
    int wv = t >> 6;
    int l16 = l & 15;
    int lk = l >> 4;

    bf16x8 b[4][8];
#pragma unroll
    for (int ks = 0; ks < 4; ++ks) {
#pragma unroll
        for (int n = 0; n < 8; ++n) {
            int kbase = ks * 32 + lk * 8;
            int col = n * 16 + l16;
            bf16x8 bb;
#pragma unroll
            for (int j = 0; j < 8; ++j) bb[j] = (short)f2bu(Wq1[(size_t)(kbase + j) * 128 + col]);
            b[ks][n] = bb;
        }
    }
    float cva[8], w2a[8];
#pragma unroll
    for (int n = 0; n < 8; ++n) {
        cva[n] = cvec[n * 16 + l16];
        w2a[n] = Wq2[n * 16 + l16];
    }
    float bq2v = bq2[0];
    float lmax = -1e30f;

    for (int g = blockIdx.x; g < ngrp; g += gridDim.x) {
        int rowbase = g * 64 + wv * 16;
        f32x4 acc[8];
#pragma unroll
        for (int n = 0; n < 8; ++n) acc[n] = (f32x4){0.f, 0.f, 0.f, 0.f};
        int ra = rowbase + l16;
#pragma unroll
        for (int ks = 0; ks < 4; ++ks) {
            bf16x8 a;
            if (ra < N) {
                const float4* pf = (const float4*)(h2 + (size_t)ra * 128 + ks * 32 + lk * 8);
                float4 p0 = pf[0], p1 = pf[1];
                a[0] = (short)f2bu(p0.x); a[1] = (short)f2bu(p0.y);
                a[2] = (short)f2bu(p0.z); a[3] = (short)f2bu(p0.w);
                a[4] = (short)f2bu(p1.x); a[5] = (short)f2bu(p1.y);
                a[6] = (short)f2bu(p1.z); a[7] = (short)f2bu(p1.w);
            } else {
                a = (bf16x8){0, 0, 0, 0, 0, 0, 0, 0};
            }
#pragma unroll
            for (int n = 0; n < 8; ++n)
                acc[n] = __builtin_amdgcn_mfma_f32_16x16x32_bf16(a, b[ks][n], acc[n], 0, 0, 0);
        }
#pragma unroll
        for (int i = 0; i < 4; ++i) {
            int r = rowbase + lk * 4 + i;
            float s = 0.f;
#pragma unroll
            for (int n = 0; n < 8; ++n) s += fmaxf(acc[n][i] + cva[n], 0.f) * w2a[n];
#pragma unroll
            for (int o = 1; o < 16; o <<= 1) s += __shfl_xor(s, o);
            if (l16 == 0 && r < N) {
                float sc = s + bq2v;
                scores[r] = sc;
                lmax = fmaxf(lmax, sc);
            }
        }
    }
#pragma unroll
    for (int o = 1; o < 64; o <<= 1) lmax = fmaxf(lmax, __shfl_xor(lmax, o));
    __shared__ float bmax[4];
    if (l == 0) bmax[wv] = lmax;
    __syncthreads();
    if (t == 0)
        atomicMax(gmaxb, fmapu(fmaxf(fmaxf(bmax[0], bmax[1]), fmaxf(bmax[2], bmax[3]))));
}

__global__ void k_sumexp(float* __restrict__ scores, const unsigned* __restrict__ gmaxb,
                         float* __restrict__ sumexp, int N) {
    int i = blockIdx.x * blockDim.x + threadIdx.x;
    float gmax = funmapu(*gmaxb);
    float p = 0.f;
    if (i < N) {
        p = __expf(scores[i] - gmax);
        scores[i] = p;
    }
#pragma unroll
    for (int o = 32; o > 0; o >>= 1) p += __shfl_down(p, o);
    __shared__ float ws_[4];
    if ((threadIdx.x & 63) == 0) ws_[threadIdx.x >> 6] = p;
    __syncthreads();
    if (threadIdx.x == 0) atomicAdd(sumexp, ws_[0] + ws_[1] + ws_[2] + ws_[3]);
}

__global__ void k_final(const float* __restrict__ scores, const float* __restrict__ sumexp,
                        float* __restrict__ out_s, int N) {
    int i = blockIdx.x * blockDim.x + threadIdx.x;
    if (i < N) out_s[i] = scores[i] / *sumexp;
}

// ---------------- launch ----------------

extern "C" void kernel_launch(void* const* d_in, const int* in_sizes, int n_in,
                              void* d_out, int out_size, void* d_ws, size_t ws_size,
                              hipStream_t stream) {
    const float* x   = (const float*)d_in[0];
    const int*   ei  = (const int*)d_in[1];
    const float* q   = (const float*)d_in[3];
    const float* W1  = (const float*)d_in[4];
    const float* as1 = (const float*)d_in[5];
    const float* ad1 = (const float*)d_in[6];
    const float* b1  = (const float*)d_in[7];
    const float* W2  = (const float*)d_in[8];
    const float* as2 = (const float*)d_in[9];
    const float* ad2 = (const float*)d_in[10];
    const float* b2  = (const float*)d_in[11];
    const float* Wq1 = (const float*)d_in[12];
    const float* bq1 = (const float*)d_in[13];
    const float* Wq2 = (const float*)d_in[14];
    const float* bq2 = (const float*)d_in[15];

    const int N = in_sizes[0] / 128;
    const int E = in_sizes[1] / 2;
    const int ET = E + N;
    const int* esrc = ei;
    const int* edst = ei + E;

    char* p = (char*)d_ws;
    auto alloc = [&](size_t bytes) -> char* {
        char* r = p;
        p += (bytes + 255) & ~(size_t)255;
        return r;
    };
    u16*   hbufA  = (u16*)alloc((size_t)N * 128 * sizeof(u16));  // gemm outputs (bf16)
    u16*   hbufB  = (u16*)alloc((size_t)N * 128 * sizeof(u16));  // layer-1 result (bf16)
    float* asrc1  = (float*)alloc((size_t)N * 2 * sizeof(float));
    float* adst1  = (float*)alloc((size_t)N * 2 * sizeof(float));
    float* asrc2  = (float*)alloc((size_t)N * sizeof(float));
    float* adst2  = (float*)alloc((size_t)N * sizeof(float));
    int*   deg    = (int*)alloc((size_t)N * sizeof(int));
    int*   rowst  = (int*)alloc((size_t)(N + 1) * sizeof(int));
    int*   cursor = (int*)alloc((size_t)N * sizeof(int));
    int*   adjl   = (int*)alloc((size_t)ET * sizeof(int));
    float* scores = (float*)alloc((size_t)N * sizeof(float));
    float* cvec   = (float*)alloc(128 * sizeof(float));
    int*   bsum   = (int*)alloc(((size_t)(N + 1023) / 1024 + 64) * sizeof(int));
    unsigned* gmaxb = (unsigned*)alloc(256);
    float* sumexp   = (float*)alloc(256);

    float* out_h = (float*)d_out;             // [N*128]
    float* out_s = out_h + (size_t)N * 128;   // [N]

    const int tb = 256;
    const int nb = (N + 1023) / 1024;
    k_init<<<(N + tb - 1) / tb, tb, 0, stream>>>(deg, gmaxb, sumexp, N);
    k_count<<<(E + tb - 1) / tb, tb, 0, stream>>>(edst, deg, E);
    k_scan1<<<nb, 256, 0, stream>>>(deg, bsum, N);
    k_scan2<<<1, 64, 0, stream>>>(bsum, nb);
    k_scan3<<<nb, 256, 0, stream>>>(deg, bsum, rowst, N);
    k_selfloop<<<(N + tb - 1) / tb, tb, 0, stream>>>(rowst, cursor, adjl, N);
    k_scatter<<<(E + tb - 1) / tb, tb, 0, stream>>>(esrc, edst, cursor, adjl, E);

    const int ngrp = (N + 63) / 64;
    const int gb = (ngrp < 512) ? ngrp : 512;

    // layer 1: heads=2  (x f32 -> h1 bf16)
    k_gemm_mfma<2, float><<<gb, 256, 0, stream>>>(x, W1, as1, ad1, hbufA, asrc1, adst1, N, ngrp);
    k_agg<2, u16><<<N, 128, 0, stream>>>(rowst, adjl, asrc1, adst1, hbufA, b1, hbufB, N);

    // layer 2: heads=1  (h1 bf16 -> h2 f32 into d_out)
    k_gemm_mfma<1, u16><<<gb, 256, 0, stream>>>(hbufB, W2, as2, ad2, hbufA, asrc2, adst2, N, ngrp);
    k_agg<1, float><<<N, 128, 0, stream>>>(rowst, adjl, asrc2, adst2, hbufA, b2, out_h, N);

    // score head
    k_cvec<<<1, 128, 0, stream>>>(q, Wq1, bq1, cvec);
    k_score_mfma<<<gb, 256, 0, stream>>>(out_h, Wq1, Wq2, bq2, cvec, scores, gmaxb, N, ngrp);
    k_sumexp<<<(N + tb - 1) / tb, tb, 0, stream>>>(scores, gmaxb, sumexp, N);
    k_final<<<(N + tb - 1) / tb, tb, 0, stream>>>(scores, sumexp, out_s, N);
}

// Round 10
// 272.652 us; speedup vs baseline: 5.1452x; 1.0578x over previous
//
#include <hip/hip_runtime.h>
#include <hip/hip_bf16.h>

typedef unsigned short u16;
typedef __attribute__((ext_vector_type(8))) short bf16x8;
typedef __attribute__((ext_vector_type(4))) float f32x4;

#define LEAKY 0.2f

__device__ __forceinline__ float bu2f(u16 v) {
    return __uint_as_float(((unsigned)v) << 16);
}
__device__ __forceinline__ u16 f2bu(float f) {
    unsigned u = __float_as_uint(f);
    unsigned r = (u + 0x7FFFu + ((u >> 16) & 1u)) >> 16;
    return (u16)r;
}
__device__ __forceinline__ unsigned fmapu(float f) {
    unsigned u = __float_as_uint(f);
    return (u & 0x80000000u) ? ~u : (u | 0x80000000u);
}
__device__ __forceinline__ float funmapu(unsigned u) {
    return __uint_as_float((u & 0x80000000u) ? (u & 0x7FFFFFFFu) : ~u);
}

// ---------------- CSR build ----------------

__global__ void k_init(int* deg, unsigned* gmaxb, float* sumexp, int N) {
    int i = blockIdx.x * blockDim.x + threadIdx.x;
    if (i < N) deg[i] = 1;  // self loop
    if (i == 0) { *gmaxb = 0u; *sumexp = 0.f; }
}

__global__ void k_count(const int* __restrict__ dst, int* __restrict__ deg, int E) {
    int i = blockIdx.x * blockDim.x + threadIdx.x;
    if (i < E) atomicAdd(&deg[dst[i]], 1);
}

// ---- hierarchical exclusive scan of deg -> rowst (rowst[N] = total) ----

__global__ __launch_bounds__(256) void k_scan1(const int* __restrict__ deg,
                                               int* __restrict__ bsum, int N) {
    int b = blockIdx.x;
    int t = threadIdx.x;
    int base = b * 1024;
    int s = 0;
    for (int i = t; i < 1024; i += 256) {
        int idx = base + i;
        if (idx < N) s += deg[idx];
    }
#pragma unroll
    for (int o = 32; o > 0; o >>= 1) s += __shfl_down(s, o);
    __shared__ int ws[4];
    if ((t & 63) == 0) ws[t >> 6] = s;
    __syncthreads();
    if (t == 0) bsum[b] = ws[0] + ws[1] + ws[2] + ws[3];
}

__global__ void k_scan2(int* __restrict__ bsum, int nb) {
    int t = threadIdx.x;   // 64 threads
    if (nb <= 64) {
        int orig = (t < nb) ? bsum[t] : 0;
        int v = orig;
#pragma unroll
        for (int o = 1; o < 64; o <<= 1) {
            int u = __shfl_up(v, o);
            if (t >= o) v += u;
        }
        if (t < nb) bsum[t] = v - orig;  // exclusive
    } else {
        if (t == 0) {
            int run = 0;
            for (int i = 0; i < nb; ++i) { int v = bsum[i]; bsum[i] = run; run += v; }
        }
    }
}

__global__ __launch_bounds__(256) void k_scan3(const int* __restrict__ deg,
                                               const int* __restrict__ bsum,
                                               int* __restrict__ rowst, int N) {
    int b = blockIdx.x;
    int t = threadIdx.x;
    int l = t & 63;
    int wv = t >> 6;
    int idx0 = b * 1024 + t * 4;
    int d[4];
#pragma unroll
    for (int j = 0; j < 4; ++j) d[j] = (idx0 + j < N) ? deg[idx0 + j] : 0;
    int s = d[0] + d[1] + d[2] + d[3];
    int orig = s;
    int v = s;
#pragma unroll
    for (int o = 1; o < 64; o <<= 1) {
        int u = __shfl_up(v, o);
        if (l >= o) v += u;
    }
    __shared__ int wsum[4];
    if (l == 63) wsum[wv] = v;
    __syncthreads();
    int woff = 0;
    for (int w = 0; w < wv; ++w) woff += wsum[w];
    int run = v - orig + woff + bsum[b];
#pragma unroll
    for (int j = 0; j < 4; ++j) {
        if (idx0 + j < N) rowst[idx0 + j] = run;
        run += d[j];
    }
    if (idx0 <= N - 1 && N - 1 < idx0 + 4) rowst[N] = run;
}

__global__ void k_selfloop(const int* __restrict__ rowst, int* __restrict__ cursor,
                           int* __restrict__ adj, int N) {
    int i = blockIdx.x * blockDim.x + threadIdx.x;
    if (i < N) {
        int p = rowst[i];
        adj[p] = i;          // self loop first
        cursor[i] = p + 1;
    }
}

__global__ void k_scatter(const int* __restrict__ src, const int* __restrict__ dst,
                          int* __restrict__ cursor, int* __restrict__ adj, int E) {
    int i = blockIdx.x * blockDim.x + threadIdx.x;
    if (i < E) {
        int pos = atomicAdd(&cursor[dst[i]], 1);
        adj[pos] = src[i];
    }
}

// ---------------- MFMA GEMM (N x 128) @ (128 x 128) + attention-coef epilogue ----------------

template <int H, typename TIN>
__global__ __launch_bounds__(256, 2) void k_gemm_mfma(
    const TIN* __restrict__ in, const float* __restrict__ W,
    const float* __restrict__ att_s, const float* __restrict__ att_d,
    u16* __restrict__ out, float* __restrict__ a_src, float* __restrict__ a_dst,
    int N, int ngrp) {
    int t = threadIdx.x;
    int l = t & 63;
    int wv = t >> 6;        // wave 0..3
    int l16 = l & 15;
    int lk = l >> 4;        // 0..3

    bf16x8 b[4][8];
#pragma unroll
    for (int ks = 0; ks < 4; ++ks) {
#pragma unroll
        for (int n = 0; n < 8; ++n) {
            int kbase = ks * 32 + lk * 8;
            int col = n * 16 + l16;
            bf16x8 bb;
#pragma unroll
            for (int j = 0; j < 8; ++j) bb[j] = (short)f2bu(W[(size_t)(kbase + j) * 128 + col]);
            b[ks][n] = bb;
        }
    }
    float atts[8], attd[8];
#pragma unroll
    for (int n = 0; n < 8; ++n) {
        atts[n] = att_s[n * 16 + l16];
        attd[n] = att_d[n * 16 + l16];
    }

    for (int g = blockIdx.x; g < ngrp; g += gridDim.x) {
        int rowbase = g * 64 + wv * 16;
        f32x4 acc[8];
#pragma unroll
        for (int n = 0; n < 8; ++n) acc[n] = (f32x4){0.f, 0.f, 0.f, 0.f};
        int ra = rowbase + l16;   // A-row this lane feeds
#pragma unroll
        for (int ks = 0; ks < 4; ++ks) {
            bf16x8 a;
            if (ra < N) {
                if constexpr (sizeof(TIN) == 4) {
                    const float4* pf = (const float4*)((const float*)in + (size_t)ra * 128 + ks * 32 + lk * 8);
                    float4 p0 = pf[0], p1 = pf[1];
                    a[0] = (short)f2bu(p0.x); a[1] = (short)f2bu(p0.y);
                    a[2] = (short)f2bu(p0.z); a[3] = (short)f2bu(p0.w);
                    a[4] = (short)f2bu(p1.x); a[5] = (short)f2bu(p1.y);
                    a[6] = (short)f2bu(p1.z); a[7] = (short)f2bu(p1.w);
                } else {
                    a = *(const bf16x8*)((const u16*)in + (size_t)ra * 128 + ks * 32 + lk * 8);
                }
            } else {
                a = (bf16x8){0, 0, 0, 0, 0, 0, 0, 0};
            }
#pragma unroll
            for (int n = 0; n < 8; ++n)
                acc[n] = __builtin_amdgcn_mfma_f32_16x16x32_bf16(a, b[ks][n], acc[n], 0, 0, 0);
        }
        // store h
#pragma unroll
        for (int n = 0; n < 8; ++n) {
#pragma unroll
            for (int i = 0; i < 4; ++i) {
                int r = rowbase + lk * 4 + i;
                if (r < N) out[(size_t)r * 128 + n * 16 + l16] = f2bu(acc[n][i]);
            }
        }
        // attention-coef row sums
#pragma unroll
        for (int i = 0; i < 4; ++i) {
            int r = rowbase + lk * 4 + i;
            if (H == 2) {
                float s0 = 0.f, s1 = 0.f, d0 = 0.f, d1 = 0.f;
#pragma unroll
                for (int n = 0; n < 4; ++n) { s0 += acc[n][i] * atts[n]; d0 += acc[n][i] * attd[n]; }
#pragma unroll
                for (int n = 4; n < 8; ++n) { s1 += acc[n][i] * atts[n]; d1 += acc[n][i] * attd[n]; }
#pragma unroll
                for (int o = 1; o < 16; o <<= 1) {
                    s0 += __shfl_xor(s0, o); d0 += __shfl_xor(d0, o);
                    s1 += __shfl_xor(s1, o); d1 += __shfl_xor(d1, o);
                }
                if (l16 == 0 && r < N) {
                    a_src[(size_t)r * 2 + 0] = s0; a_src[(size_t)r * 2 + 1] = s1;
                    a_dst[(size_t)r * 2 + 0] = d0; a_dst[(size_t)r * 2 + 1] = d1;
                }
            } else {
                float s0 = 0.f, d0 = 0.f;
#pragma unroll
                for (int n = 0; n < 8; ++n) { s0 += acc[n][i] * atts[n]; d0 += acc[n][i] * attd[n]; }
#pragma unroll
                for (int o = 1; o < 16; o <<= 1) {
                    s0 += __shfl_xor(s0, o); d0 += __shfl_xor(d0, o);
                }
                if (l16 == 0 && r < N) { a_src[r] = s0; a_dst[r] = d0; }
            }
        }
    }
}

// ---------------- per-node segment softmax + aggregation ----------------
// Phase A: wave-parallel online softmax (wave per head).
// Phase B: 8 edge-groups x 16 lanes, bf16x8 (16B) gathers -> 1KB per wave inst;
//          8 edges in flight per block; partials combined via LDS.

template <int H, typename TOUT>
__global__ __launch_bounds__(128) void k_agg(
    const int* __restrict__ rowst, const int* __restrict__ adj,
    const float* __restrict__ a_src, const float* __restrict__ a_dst,
    const u16* __restrict__ h_in, const float* __restrict__ bias,
    TOUT* __restrict__ out, int N) {
    int n = blockIdx.x;
    if (n >= N) return;
    const int Ch = 128 / H;
    int c = threadIdx.x;
    int w = c >> 6;
    int l = c & 63;
    int h = c / Ch;             // head of channel c (final combine)
    int hh = (H == 2) ? w : 0;  // head this wave softmaxes for
    int g = c >> 4;             // edge-group 0..7
    int li = c & 15;            // lane in group
    int ch0 = li * 8;           // channels ch0..ch0+7
    int h8 = (H == 2) ? (li >> 3) : 0;  // head of this thread's 8 channels
    __shared__ float sm_m[H], sm_s[H], sscale[H], asd[H];
    __shared__ int srcs[64];
    __shared__ float pv[H][64];
    __shared__ float accbuf[8][128];   // 4 KB
    if (c < H) {
        sm_m[c] = -1e30f; sm_s[c] = 0.f;
        asd[c] = a_dst[(size_t)n * H + c];
    }
    if (c < 64) srcs[c] = 0;
    float a0 = 0.f, a1 = 0.f, a2 = 0.f, a3 = 0.f;
    float a4 = 0.f, a5 = 0.f, a6 = 0.f, a7 = 0.f;
    int rs = rowst[n], re = rowst[n + 1];
    __syncthreads();
    for (int base = rs; base < re; base += 64) {
        int cnt = min(64, re - base);
        if (c < cnt) srcs[c] = adj[base + c];
        __syncthreads();
        // ---- phase A: online softmax ----
        bool active = (H == 2) || (w == 0);
        bool ok = active && (l < cnt);
        float xv = -1e30f;
        if (ok) {
            float v = a_src[(size_t)srcs[l] * H + hh] + asd[hh];
            xv = (v > 0.f) ? v : LEAKY * v;
        }
        float lm = xv;
#pragma unroll
        for (int o = 32; o > 0; o >>= 1) lm = fmaxf(lm, __shfl_xor(lm, o));
        float mx = fmaxf(sm_m[hh], lm);
        float pe = ok ? __expf(xv - mx) : 0.f;
        float sum = pe;
#pragma unroll
        for (int o = 32; o > 0; o >>= 1) sum += __shfl_xor(sum, o);
        if (active) {
            pv[hh][l] = pe;
            if (l == 0) {
                float sc = __expf(sm_m[hh] - mx);
                sscale[hh] = sc;
                sm_s[hh] = sm_s[hh] * sc + sum;
                sm_m[hh] = mx;
            }
        }
        __syncthreads();
        // ---- phase B: 16B gathers, 8 edges in flight ----
        float sc8 = sscale[h8];
        a0 *= sc8; a1 *= sc8; a2 *= sc8; a3 *= sc8;
        a4 *= sc8; a5 *= sc8; a6 *= sc8; a7 *= sc8;
        for (int e8 = 0; e8 < cnt; e8 += 8) {
            int e = e8 + g;                 // <= 63 always
            float pe_ = pv[h8][e];          // 0 for e >= cnt
            int s = srcs[e];                // valid node id even when stale
            bf16x8 v = *(const bf16x8*)(h_in + (size_t)s * 128 + ch0);
            a0 += pe_ * bu2f((u16)v[0]);
            a1 += pe_ * bu2f((u16)v[1]);
            a2 += pe_ * bu2f((u16)v[2]);
            a3 += pe_ * bu2f((u16)v[3]);
            a4 += pe_ * bu2f((u16)v[4]);
            a5 += pe_ * bu2f((u16)v[5]);
            a6 += pe_ * bu2f((u16)v[6]);
            a7 += pe_ * bu2f((u16)v[7]);
        }
        __syncthreads();
    }
    accbuf[g][ch0 + 0] = a0; accbuf[g][ch0 + 1] = a1;
    accbuf[g][ch0 + 2] = a2; accbuf[g][ch0 + 3] = a3;
    accbuf[g][ch0 + 4] = a4; accbuf[g][ch0 + 5] = a5;
    accbuf[g][ch0 + 6] = a6; accbuf[g][ch0 + 7] = a7;
    __syncthreads();
    float val = 0.f;
#pragma unroll
    for (int k = 0; k < 8; ++k) val += accbuf[k][c];
    val = val / (sm_s[h] + 1e-16f) + bias[c];
    if constexpr (sizeof(TOUT) == 2) {
        out[(size_t)n * 128 + c] = (TOUT)f2bu(val);
    } else {
        out[(size_t)n * 128 + c] = (TOUT)val;
    }
}

// ---------------- score head ----------------

__global__ void k_cvec(const float* __restrict__ q, const float* __restrict__ Wq1,
                       const float* __restrict__ bq1, float* __restrict__ cvec) {
    int j = threadIdx.x;  // 128 threads
    float acc = bq1[j];
    for (int k = 0; k < 384; ++k) acc += q[k] * Wq1[(size_t)(128 + k) * 128 + j];
    cvec[j] = acc;
}

__global__ __launch_bounds__(256, 2) void k_score_mfma(
    const float* __restrict__ h2, const float* __restrict__ Wq1, const float* __restrict__ Wq2,
    const float* __restrict__ bq2, const float* __restrict__ cvec,
    float* __restrict__ scores, unsigned* __restrict__ gmaxb, int N, int ngrp) {
    int t = threadIdx.x;
    int l = t & 63;
    int wv = t >> 6;
    int l16 = l & 15;
    int lk = l >> 4;

    bf16x8 b[4][8];
#pragma unroll
    for (int ks = 0; ks < 4; ++ks) {
#pragma unroll
        for (int n = 0; n < 8; ++n) {
            int kbase = ks * 32 + lk * 8;
            int col = n * 16 + l16;
            bf16x8 bb;
#pragma unroll
            for (int j = 0; j < 8; ++j) bb[j] = (short)f2bu(Wq1[(size_t)(kbase + j) * 128 + col]);
            b[ks][n] = bb;
        }
    }
    float cva[8], w2a[8];
#pragma unroll
    for (int n = 0; n < 8; ++n) {
        cva[n] = cvec[n * 16 + l16];
        w2a[n] = Wq2[n * 16 + l16];
    }
    float bq2v = bq2[0];
    float lmax = -1e30f;

    for (int g = blockIdx.x; g < ngrp; g += gridDim.x) {
        int rowbase = g * 64 + wv * 16;
        f32x4 acc[8];
#pragma unroll
        for (int n = 0; n < 8; ++n) acc[n] = (f32x4){0.f, 0.f, 0.f, 0.f};
        int ra = rowbase + l16;
#pragma unroll
        for (int ks = 0; ks < 4; ++ks) {
            bf16x8 a;
            if (ra < N) {
                const float4* pf = (const float4*)(h2 + (size_t)ra * 128 + ks * 32 + lk * 8);
                float4 p0 = pf[0], p1 = pf[1];
                a[0] = (short)f2bu(p0.x); a[1] = (short)f2bu(p0.y);
                a[2] = (short)f2bu(p0.z); a[3] = (short)f2bu(p0.w);
                a[4] = (short)f2bu(p1.x); a[5] = (short)f2bu(p1.y);
                a[6] = (short)f2bu(p1.z); a[7] = (short)f2bu(p1.w);
            } else {
                a = (bf16x8){0, 0, 0, 0, 0, 0, 0, 0};
            }
#pragma unroll
            for (int n = 0; n < 8; ++n)
                acc[n] = __builtin_amdgcn_mfma_f32_16x16x32_bf16(a, b[ks][n], acc[n], 0, 0, 0);
        }
#pragma unroll
        for (int i = 0; i < 4; ++i) {
            int r = rowbase + lk * 4 + i;
            float s = 0.f;
#pragma unroll
            for (int n = 0; n < 8; ++n) s += fmaxf(acc[n][i] + cva[n], 0.f) * w2a[n];
#pragma unroll
            for (int o = 1; o < 16; o <<= 1) s += __shfl_xor(s, o);
            if (l16 == 0 && r < N) {
                float sc = s + bq2v;
                scores[r] = sc;
                lmax = fmaxf(lmax, sc);
            }
        }
    }
#pragma unroll
    for (int o = 1; o < 64; o <<= 1) lmax = fmaxf(lmax, __shfl_xor(lmax, o));
    __shared__ float bmax[4];
    if (l == 0) bmax[wv] = lmax;
    __syncthreads();
    if (t == 0)
        atomicMax(gmaxb, fmapu(fmaxf(fmaxf(bmax[0], bmax[1]), fmaxf(bmax[2], bmax[3]))));
}

__global__ void k_sumexp(float* __restrict__ scores, const unsigned* __restrict__ gmaxb,
                         float* __restrict__ sumexp, int N) {
    int i = blockIdx.x * blockDim.x + threadIdx.x;
    float gmax = funmapu(*gmaxb);
    float p = 0.f;
    if (i < N) {
        p = __expf(scores[i] - gmax);
        scores[i] = p;
    }
#pragma unroll
    for (int o = 32; o > 0; o >>= 1) p += __shfl_down(p, o);
    __shared__ float ws_[4];
    if ((threadIdx.x & 63) == 0) ws_[threadIdx.x >> 6] = p;
    __syncthreads();
    if (threadIdx.x == 0) atomicAdd(sumexp, ws_[0] + ws_[1] + ws_[2] + ws_[3]);
}

__global__ void k_final(const float* __restrict__ scores, const float* __restrict__ sumexp,
                        float* __restrict__ out_s, int N) {
    int i = blockIdx.x * blockDim.x + threadIdx.x;
    if (i < N) out_s[i] = scores[i] / *sumexp;
}

// ---------------- launch ----------------

extern "C" void kernel_launch(void* const* d_in, const int* in_sizes, int n_in,
                              void* d_out, int out_size, void* d_ws, size_t ws_size,
                              hipStream_t stream) {
    const float* x   = (const float*)d_in[0];
    const int*   ei  = (const int*)d_in[1];
    const float* q   = (const float*)d_in[3];
    const float* W1  = (const float*)d_in[4];
    const float* as1 = (const float*)d_in[5];
    const float* ad1 = (const float*)d_in[6];
    const float* b1  = (const float*)d_in[7];
    const float* W2  = (const float*)d_in[8];
    const float* as2 = (const float*)d_in[9];
    const float* ad2 = (const float*)d_in[10];
    const float* b2  = (const float*)d_in[11];
    const float* Wq1 = (const float*)d_in[12];
    const float* bq1 = (const float*)d_in[13];
    const float* Wq2 = (const float*)d_in[14];
    const float* bq2 = (const float*)d_in[15];

    const int N = in_sizes[0] / 128;
    const int E = in_sizes[1] / 2;
    const int ET = E + N;
    const int* esrc = ei;
    const int* edst = ei + E;

    char* p = (char*)d_ws;
    auto alloc = [&](size_t bytes) -> char* {
        char* r = p;
        p += (bytes + 255) & ~(size_t)255;
        return r;
    };
    u16*   hbufA  = (u16*)alloc((size_t)N * 128 * sizeof(u16));  // gemm outputs (bf16)
    u16*   hbufB  = (u16*)alloc((size_t)N * 128 * sizeof(u16));  // layer-1 result (bf16)
    float* asrc1  = (float*)alloc((size_t)N * 2 * sizeof(float));
    float* adst1  = (float*)alloc((size_t)N * 2 * sizeof(float));
    float* asrc2  = (float*)alloc((size_t)N * sizeof(float));
    float* adst2  = (float*)alloc((size_t)N * sizeof(float));
    int*   deg    = (int*)alloc((size_t)N * sizeof(int));
    int*   rowst  = (int*)alloc((size_t)(N + 1) * sizeof(int));
    int*   cursor = (int*)alloc((size_t)N * sizeof(int));
    int*   adjl   = (int*)alloc((size_t)ET * sizeof(int));
    float* scores = (float*)alloc((size_t)N * sizeof(float));
    float* cvec   = (float*)alloc(128 * sizeof(float));
    int*   bsum   = (int*)alloc(((size_t)(N + 1023) / 1024 + 64) * sizeof(int));
    unsigned* gmaxb = (unsigned*)alloc(256);
    float* sumexp   = (float*)alloc(256);

    float* out_h = (float*)d_out;             // [N*128]
    float* out_s = out_h + (size_t)N * 128;   // [N]

    const int tb = 256;
    const int nb = (N + 1023) / 1024;
    k_init<<<(N + tb - 1) / tb, tb, 0, stream>>>(deg, gmaxb, sumexp, N);
    k_count<<<(E + tb - 1) / tb, tb, 0, stream>>>(edst, deg, E);
    k_scan1<<<nb, 256, 0, stream>>>(deg, bsum, N);
    k_scan2<<<1, 64, 0, stream>>>(bsum, nb);
    k_scan3<<<nb, 256, 0, stream>>>(deg, bsum, rowst, N);
    k_selfloop<<<(N + tb - 1) / tb, tb, 0, stream>>>(rowst, cursor, adjl, N);
    k_scatter<<<(E + tb - 1) / tb, tb, 0, stream>>>(esrc, edst, cursor, adjl, E);

    const int ngrp = (N + 63) / 64;
    const int gb = (ngrp < 512) ? ngrp : 512;

    // layer 1: heads=2  (x f32 -> h1 bf16)
    k_gemm_mfma<2, float><<<gb, 256, 0, stream>>>(x, W1, as1, ad1, hbufA, asrc1, adst1, N, ngrp);
    k_agg<2, u16><<<N, 128, 0, stream>>>(rowst, adjl, asrc1, adst1, hbufA, b1, hbufB, N);

    // layer 2: heads=1  (h1 bf16 -> h2 f32 into d_out)
    k_gemm_mfma<1, u16><<<gb, 256, 0, stream>>>(hbufB, W2, as2, ad2, hbufA, asrc2, adst2, N, ngrp);
    k_agg<1, float><<<N, 128, 0, stream>>>(rowst, adjl, asrc2, adst2, hbufA, b2, out_h, N);

    // score head
    k_cvec<<<1, 128, 0, stream>>>(q, Wq1, bq1, cvec);
    k_score_mfma<<<gb, 256, 0, stream>>>(out_h, Wq1, Wq2, bq2, cvec, scores, gmaxb, N, ngrp);
    k_sumexp<<<(N + tb - 1) / tb, tb, 0, stream>>>(scores, gmaxb, sumexp, N);
    k_final<<<(N + tb - 1) / tb, tb, 0, stream>>>(scores, sumexp, out_s, N);
}

// Round 11
// 252.022 us; speedup vs baseline: 5.5664x; 1.0819x over previous
//
#include <hip/hip_runtime.h>
#include <hip/hip_bf16.h>

typedef unsigned short u16;
typedef __attribute__((ext_vector_type(8))) short bf16x8;
typedef __attribute__((ext_vector_type(4))) float f32x4;

#define LEAKY 0.2f

__device__ __forceinline__ float bu2f(u16 v) {
    return __uint_as_float(((unsigned)v) << 16);
}
__device__ __forceinline__ u16 f2bu(float f) {
    unsigned u = __float_as_uint(f);
    unsigned r = (u + 0x7FFFu + ((u >> 16) & 1u)) >> 16;
    return (u16)r;
}
__device__ __forceinline__ unsigned fmapu(float f) {
    unsigned u = __float_as_uint(f);
    return (u & 0x80000000u) ? ~u : (u | 0x80000000u);
}
__device__ __forceinline__ float funmapu(unsigned u) {
    return __uint_as_float((u & 0x80000000u) ? (u & 0x7FFFFFFFu) : ~u);
}

// ---------------- CSR build ----------------

__global__ void k_init(int* deg, unsigned* gmaxb, float* sumexp, int N) {
    int i = blockIdx.x * blockDim.x + threadIdx.x;
    if (i < N) deg[i] = 1;  // self loop
    if (i == 0) { *gmaxb = 0u; *sumexp = 0.f; }
}

__global__ void k_count(const int* __restrict__ dst, int* __restrict__ deg, int E) {
    int i = blockIdx.x * blockDim.x + threadIdx.x;
    if (i < E) {
        int d = __builtin_nontemporal_load(dst + i);  // streaming read: keep deg L2-resident
        atomicAdd(&deg[d], 1);
    }
}

// ---- hierarchical exclusive scan of deg -> rowst (rowst[N] = total) ----

__global__ __launch_bounds__(256) void k_scan1(const int* __restrict__ deg,
                                               int* __restrict__ bsum, int N) {
    int b = blockIdx.x;
    int t = threadIdx.x;
    int base = b * 1024;
    int s = 0;
    for (int i = t; i < 1024; i += 256) {
        int idx = base + i;
        if (idx < N) s += deg[idx];
    }
#pragma unroll
    for (int o = 32; o > 0; o >>= 1) s += __shfl_down(s, o);
    __shared__ int ws[4];
    if ((t & 63) == 0) ws[t >> 6] = s;
    __syncthreads();
    if (t == 0) bsum[b] = ws[0] + ws[1] + ws[2] + ws[3];
}

__global__ void k_scan2(int* __restrict__ bsum, int nb) {
    int t = threadIdx.x;   // 64 threads
    if (nb <= 64) {
        int orig = (t < nb) ? bsum[t] : 0;
        int v = orig;
#pragma unroll
        for (int o = 1; o < 64; o <<= 1) {
            int u = __shfl_up(v, o);
            if (t >= o) v += u;
        }
        if (t < nb) bsum[t] = v - orig;  // exclusive
    } else {
        if (t == 0) {
            int run = 0;
            for (int i = 0; i < nb; ++i) { int v = bsum[i]; bsum[i] = run; run += v; }
        }
    }
}

__global__ __launch_bounds__(256) void k_scan3(const int* __restrict__ deg,
                                               const int* __restrict__ bsum,
                                               int* __restrict__ rowst, int N) {
    int b = blockIdx.x;
    int t = threadIdx.x;
    int l = t & 63;
    int wv = t >> 6;
    int idx0 = b * 1024 + t * 4;
    int d[4];
#pragma unroll
    for (int j = 0; j < 4; ++j) d[j] = (idx0 + j < N) ? deg[idx0 + j] : 0;
    int s = d[0] + d[1] + d[2] + d[3];
    int orig = s;
    int v = s;
#pragma unroll
    for (int o = 1; o < 64; o <<= 1) {
        int u = __shfl_up(v, o);
        if (l >= o) v += u;
    }
    __shared__ int wsum[4];
    if (l == 63) wsum[wv] = v;
    __syncthreads();
    int woff = 0;
    for (int w = 0; w < wv; ++w) woff += wsum[w];
    int run = v - orig + woff + bsum[b];
#pragma unroll
    for (int j = 0; j < 4; ++j) {
        if (idx0 + j < N) rowst[idx0 + j] = run;
        run += d[j];
    }
    if (idx0 <= N - 1 && N - 1 < idx0 + 4) rowst[N] = run;
}

__global__ void k_selfloop(const int* __restrict__ rowst, int* __restrict__ cursor,
                           int* __restrict__ adj, int N) {
    int i = blockIdx.x * blockDim.x + threadIdx.x;
    if (i < N) {
        int p = rowst[i];
        adj[p] = i;          // self loop first
        cursor[i] = p + 1;
    }
}

__global__ void k_scatter(const int* __restrict__ src, const int* __restrict__ dst,
                          int* __restrict__ cursor, int* __restrict__ adj, int E) {
    int i = blockIdx.x * blockDim.x + threadIdx.x;
    if (i < E) {
        int d = __builtin_nontemporal_load(dst + i);   // streaming: don't evict adj/cursor
        int s = __builtin_nontemporal_load(src + i);
        int pos = atomicAdd(&cursor[d], 1);
        adj[pos] = s;
    }
}

// ---------------- MFMA GEMM (N x 128) @ (128 x 128) + attention-coef epilogue ----------------

template <int H, typename TIN>
__global__ __launch_bounds__(256, 2) void k_gemm_mfma(
    const TIN* __restrict__ in, const float* __restrict__ W,
    const float* __restrict__ att_s, const float* __restrict__ att_d,
    u16* __restrict__ out, float* __restrict__ a_src, float* __restrict__ a_dst,
    int N, int ngrp) {
    int t = threadIdx.x;
    int l = t & 63;
    int wv = t >> 6;        // wave 0..3
    int l16 = l & 15;
    int lk = l >> 4;        // 0..3

    bf16x8 b[4][8];
#pragma unroll
    for (int ks = 0; ks < 4; ++ks) {
#pragma unroll
        for (int n = 0; n < 8; ++n) {
            int kbase = ks * 32 + lk * 8;
            int col = n * 16 + l16;
            bf16x8 bb;
#pragma unroll
            for (int j = 0; j < 8; ++j) bb[j] = (short)f2bu(W[(size_t)(kbase + j) * 128 + col]);
            b[ks][n] = bb;
        }
    }
    float atts[8], attd[8];
#pragma unroll
    for (int n = 0; n < 8; ++n) {
        atts[n] = att_s[n * 16 + l16];
        attd[n] = att_d[n * 16 + l16];
    }

    for (int g = blockIdx.x; g < ngrp; g += gridDim.x) {
        int rowbase = g * 64 + wv * 16;
        f32x4 acc[8];
#pragma unroll
        for (int n = 0; n < 8; ++n) acc[n] = (f32x4){0.f, 0.f, 0.f, 0.f};
        int ra = rowbase + l16;   // A-row this lane feeds
#pragma unroll
        for (int ks = 0; ks < 4; ++ks) {
            bf16x8 a;
            if (ra < N) {
                if constexpr (sizeof(TIN) == 4) {
                    const float4* pf = (const float4*)((const float*)in + (size_t)ra * 128 + ks * 32 + lk * 8);
                    float4 p0 = pf[0], p1 = pf[1];
                    a[0] = (short)f2bu(p0.x); a[1] = (short)f2bu(p0.y);
                    a[2] = (short)f2bu(p0.z); a[3] = (short)f2bu(p0.w);
                    a[4] = (short)f2bu(p1.x); a[5] = (short)f2bu(p1.y);
                    a[6] = (short)f2bu(p1.z); a[7] = (short)f2bu(p1.w);
                } else {
                    a = *(const bf16x8*)((const u16*)in + (size_t)ra * 128 + ks * 32 + lk * 8);
                }
            } else {
                a = (bf16x8){0, 0, 0, 0, 0, 0, 0, 0};
            }
#pragma unroll
            for (int n = 0; n < 8; ++n)
                acc[n] = __builtin_amdgcn_mfma_f32_16x16x32_bf16(a, b[ks][n], acc[n], 0, 0, 0);
        }
        // store h
#pragma unroll
        for (int n = 0; n < 8; ++n) {
#pragma unroll
            for (int i = 0; i < 4; ++i) {
                int r = rowbase + lk * 4 + i;
                if (r < N) out[(size_t)r * 128 + n * 16 + l16] = f2bu(acc[n][i]);
            }
        }
        // attention-coef row sums
#pragma unroll
        for (int i = 0; i < 4; ++i) {
            int r = rowbase + lk * 4 + i;
            if (H == 2) {
                float s0 = 0.f, s1 = 0.f, d0 = 0.f, d1 = 0.f;
#pragma unroll
                for (int n = 0; n < 4; ++n) { s0 += acc[n][i] * atts[n]; d0 += acc[n][i] * attd[n]; }
#pragma unroll
                for (int n = 4; n < 8; ++n) { s1 += acc[n][i] * atts[n]; d1 += acc[n][i] * attd[n]; }
#pragma unroll
                for (int o = 1; o < 16; o <<= 1) {
                    s0 += __shfl_xor(s0, o); d0 += __shfl_xor(d0, o);
                    s1 += __shfl_xor(s1, o); d1 += __shfl_xor(d1, o);
                }
                if (l16 == 0 && r < N) {
                    a_src[(size_t)r * 2 + 0] = s0; a_src[(size_t)r * 2 + 1] = s1;
                    a_dst[(size_t)r * 2 + 0] = d0; a_dst[(size_t)r * 2 + 1] = d1;
                }
            } else {
                float s0 = 0.f, d0 = 0.f;
#pragma unroll
                for (int n = 0; n < 8; ++n) { s0 += acc[n][i] * atts[n]; d0 += acc[n][i] * attd[n]; }
#pragma unroll
                for (int o = 1; o < 16; o <<= 1) {
                    s0 += __shfl_xor(s0, o); d0 += __shfl_xor(d0, o);
                }
                if (l16 == 0 && r < N) { a_src[r] = s0; a_dst[r] = d0; }
            }
        }
    }
}

// ---------------- per-node segment softmax + aggregation ----------------
// ONE WAVE PER NODE (4 nodes / 256-thread block). No LDS, no __syncthreads.
// Phase A: edge-per-lane softmax via shfl_xor, per-head online state in regs.
// Phase B: 4 edge-groups x 16 lanes, bf16x8 (16B) gathers; srcs/pe broadcast
// via __shfl; cross-group combine via 2 shfl_xor rounds.

template <int H, typename TOUT>
__global__ __launch_bounds__(256) void k_agg(
    const int* __restrict__ rowst, const int* __restrict__ adj,
    const float* __restrict__ a_src, const float* __restrict__ a_dst,
    const u16* __restrict__ h_in, const float* __restrict__ bias,
    TOUT* __restrict__ out, int N) {
    int wid = threadIdx.x >> 6;
    int n = blockIdx.x * 4 + wid;
    if (n >= N) return;                 // wave-uniform
    int l = threadIdx.x & 63;
    int g = l >> 4;                     // edge-group 0..3
    int li = l & 15;
    int ch0 = li * 8;                   // channels ch0..ch0+7
    int h8 = (H == 2) ? (li >> 3) : 0;  // head of this lane's channels
    int rs = rowst[n], re = rowst[n + 1];
    float asd0 = a_dst[(size_t)n * H];
    float asd1 = (H == 2) ? a_dst[(size_t)n * H + 1] : 0.f;
    float m0 = -1e30f, m1 = -1e30f, s0 = 0.f, s1 = 0.f;
    float acc[8];
#pragma unroll
    for (int j = 0; j < 8; ++j) acc[j] = 0.f;

    for (int base = rs; base < re; base += 64) {
        int cnt = min(64, re - base);
        int sidx = (l < cnt) ? __builtin_nontemporal_load(adj + base + l) : 0;
        // phase A: leaky-relu scores, edge l on lane l
        float p0 = -1e30f, p1 = -1e30f;
        if (l < cnt) {
            if (H == 2) {
                float2 vv = *(const float2*)(a_src + (size_t)sidx * 2);
                float v0 = vv.x + asd0, v1 = vv.y + asd1;
                p0 = (v0 > 0.f) ? v0 : LEAKY * v0;
                p1 = (v1 > 0.f) ? v1 : LEAKY * v1;
            } else {
                float v0 = a_src[sidx] + asd0;
                p0 = (v0 > 0.f) ? v0 : LEAKY * v0;
            }
        }
        float lm0 = p0, lm1 = p1;
#pragma unroll
        for (int o = 32; o > 0; o >>= 1) {
            lm0 = fmaxf(lm0, __shfl_xor(lm0, o));
            if (H == 2) lm1 = fmaxf(lm1, __shfl_xor(lm1, o));
        }
        float nm0 = fmaxf(m0, lm0);
        float nm1 = (H == 2) ? fmaxf(m1, lm1) : 0.f;
        p0 = (l < cnt) ? __expf(p0 - nm0) : 0.f;
        if (H == 2) p1 = (l < cnt) ? __expf(p1 - nm1) : 0.f;
        float sum0 = p0, sum1 = p1;
#pragma unroll
        for (int o = 32; o > 0; o >>= 1) {
            sum0 += __shfl_xor(sum0, o);
            if (H == 2) sum1 += __shfl_xor(sum1, o);
        }
        float r0 = __expf(m0 - nm0);
        float r1 = (H == 2) ? __expf(m1 - nm1) : 0.f;
        s0 = s0 * r0 + sum0; m0 = nm0;
        if (H == 2) { s1 = s1 * r1 + sum1; m1 = nm1; }
        float racc = (H == 2) ? (h8 ? r1 : r0) : r0;
#pragma unroll
        for (int j = 0; j < 8; ++j) acc[j] *= racc;
        // phase B: gather, 4 edges in flight per wave
        for (int e4 = 0; e4 < cnt; e4 += 4) {
            int e = e4 + g;                     // <= 63
            int s = __shfl(sidx, e);            // pe==0 if e>=cnt
            float pe0 = __shfl(p0, e);
            float pe = pe0;
            if (H == 2) { float pe1 = __shfl(p1, e); pe = h8 ? pe1 : pe0; }
            bf16x8 v = *(const bf16x8*)(h_in + (size_t)s * 128 + ch0);
#pragma unroll
            for (int j = 0; j < 8; ++j) acc[j] += pe * bu2f((u16)v[j]);
        }
    }
    // combine the 4 edge-groups
#pragma unroll
    for (int j = 0; j < 8; ++j) acc[j] += __shfl_xor(acc[j], 16);
#pragma unroll
    for (int j = 0; j < 8; ++j) acc[j] += __shfl_xor(acc[j], 32);
    if (l < 16) {
        float sden = (H == 2) ? (h8 ? s1 : s0) : s0;
        float inv = 1.f / (sden + 1e-16f);
#pragma unroll
        for (int j = 0; j < 8; ++j) {
            float val = acc[j] * inv + bias[ch0 + j];
            if constexpr (sizeof(TOUT) == 2) {
                out[(size_t)n * 128 + ch0 + j] = (TOUT)f2bu(val);
            } else {
                out[(size_t)n * 128 + ch0 + j] = (TOUT)val;
            }
        }
    }
}

// ---------------- score head ----------------

__global__ void k_cvec(const float* __restrict__ q, const float* __restrict__ Wq1,
                       const float* __restrict__ bq1, float* __restrict__ cvec) {
    int j = threadIdx.x;  // 128 threads
    float acc = bq1[j];
    for (int k = 0; k < 384; ++k) acc += q[k] * Wq1[(size_t)(128 + k) * 128 + j];
    cvec[j] = acc;
}

__global__ __launch_bounds__(256, 2) void k_score_mfma(
    const float* __restrict__ h2, const float* __restrict__ Wq1, const float* __restrict__ Wq2,
    const float* __restrict__ bq2, const float* __restrict__ cvec,
    float* __restrict__ scores, unsigned* __restrict__ gmaxb, int N, int ngrp) {
    int t = threadIdx.x;
    int l = t & 63;
    int wv = t >> 6;
    int l16 = l & 15;
    int lk = l >> 4;

    bf16x8 b[4][8];
#pragma unroll
    for (int ks = 0; ks < 4; ++ks) {
#pragma unroll
        for (int n = 0; n < 8; ++n) {
            int kbase = ks * 32 + lk * 8;
            int col = n * 16 + l16;
            bf16x8 bb;
#pragma unroll
            for (int j = 0; j < 8; ++j) bb[j] = (short)f2bu(Wq1[(size_t)(kbase + j) * 128 + col]);
            b[ks][n] = bb;
        }
    }
    float cva[8], w2a[8];
#pragma unroll
    for (int n = 0; n < 8; ++n) {
        cva[n] = cvec[n * 16 + l16];
        w2a[n] = Wq2[n * 16 + l16];
    }
    float bq2v = bq2[0];
    float lmax = -1e30f;

    for (int g = blockIdx.x; g < ngrp; g += gridDim.x) {
        int rowbase = g * 64 + wv * 16;
        f32x4 acc[8];
#pragma unroll
        for (int n = 0; n < 8; ++n) acc[n] = (f32x4){0.f, 0.f, 0.f, 0.f};
        int ra = rowbase + l16;
#pragma unroll
        for (int ks = 0; ks < 4; ++ks) {
            bf16x8 a;
            if (ra < N) {
                const float4* pf = (const float4*)(h2 + (size_t)ra * 128 + ks * 32 + lk * 8);
                float4 p0 = pf[0], p1 = pf[1];
                a[0] = (short)f2bu(p0.x); a[1] = (short)f2bu(p0.y);
                a[2] = (short)f2bu(p0.z); a[3] = (short)f2bu(p0.w);
                a[4] = (short)f2bu(p1.x); a[5] = (short)f2bu(p1.y);
                a[6] = (short)f2bu(p1.z); a[7] = (short)f2bu(p1.w);
            } else {
                a = (bf16x8){0, 0, 0, 0, 0, 0, 0, 0};
            }
#pragma unroll
            for (int n = 0; n < 8; ++n)
                acc[n] = __builtin_amdgcn_mfma_f32_16x16x32_bf16(a, b[ks][n], acc[n], 0, 0, 0);
        }
#pragma unroll
        for (int i = 0; i < 4; ++i) {
            int r = rowbase + lk * 4 + i;
            float s = 0.f;
#pragma unroll
            for (int n = 0; n < 8; ++n) s += fmaxf(acc[n][i] + cva[n], 0.f) * w2a[n];
#pragma unroll
            for (int o = 1; o < 16; o <<= 1) s += __shfl_xor(s, o);
            if (l16 == 0 && r < N) {
                float sc = s + bq2v;
                scores[r] = sc;
                lmax = fmaxf(lmax, sc);
            }
        }
    }
#pragma unroll
    for (int o = 1; o < 64; o <<= 1) lmax = fmaxf(lmax, __shfl_xor(lmax, o));
    __shared__ float bmax[4];
    if (l == 0) bmax[wv] = lmax;
    __syncthreads();
    if (t == 0)
        atomicMax(gmaxb, fmapu(fmaxf(fmaxf(bmax[0], bmax[1]), fmaxf(bmax[2], bmax[3]))));
}

__global__ void k_sumexp(float* __restrict__ scores, const unsigned* __restrict__ gmaxb,
                         float* __restrict__ sumexp, int N) {
    int i = blockIdx.x * blockDim.x + threadIdx.x;
    float gmax = funmapu(*gmaxb);
    float p = 0.f;
    if (i < N) {
        p = __expf(scores[i] - gmax);
        scores[i] = p;
    }
#pragma unroll
    for (int o = 32; o > 0; o >>= 1) p += __shfl_down(p, o);
    __shared__ float ws_[4];
    if ((threadIdx.x & 63) == 0) ws_[threadIdx.x >> 6] = p;
    __syncthreads();
    if (threadIdx.x == 0) atomicAdd(sumexp, ws_[0] + ws_[1] + ws_[2] + ws_[3]);
}

__global__ void k_final(const float* __restrict__ scores, const float* __restrict__ sumexp,
                        float* __restrict__ out_s, int N) {
    int i = blockIdx.x * blockDim.x + threadIdx.x;
    if (i < N) out_s[i] = scores[i] / *sumexp;
}

// ---------------- launch ----------------

extern "C" void kernel_launch(void* const* d_in, const int* in_sizes, int n_in,
                              void* d_out, int out_size, void* d_ws, size_t ws_size,
                              hipStream_t stream) {
    const float* x   = (const float*)d_in[0];
    const int*   ei  = (const int*)d_in[1];
    const float* q   = (const float*)d_in[3];
    const float* W1  = (const float*)d_in[4];
    const float* as1 = (const float*)d_in[5];
    const float* ad1 = (const float*)d_in[6];
    const float* b1  = (const float*)d_in[7];
    const float* W2  = (const float*)d_in[8];
    const float* as2 = (const float*)d_in[9];
    const float* ad2 = (const float*)d_in[10];
    const float* b2  = (const float*)d_in[11];
    const float* Wq1 = (const float*)d_in[12];
    const float* bq1 = (const float*)d_in[13];
    const float* Wq2 = (const float*)d_in[14];
    const float* bq2 = (const float*)d_in[15];

    const int N = in_sizes[0] / 128;
    const int E = in_sizes[1] / 2;
    const int ET = E + N;
    const int* esrc = ei;
    const int* edst = ei + E;

    char* p = (char*)d_ws;
    auto alloc = [&](size_t bytes) -> char* {
        char* r = p;
        p += (bytes + 255) & ~(size_t)255;
        return r;
    };
    u16*   hbufA  = (u16*)alloc((size_t)N * 128 * sizeof(u16));  // gemm outputs (bf16)
    u16*   hbufB  = (u16*)alloc((size_t)N * 128 * sizeof(u16));  // layer-1 result (bf16)
    float* asrc1  = (float*)alloc((size_t)N * 2 * sizeof(float));
    float* adst1  = (float*)alloc((size_t)N * 2 * sizeof(float));
    float* asrc2  = (float*)alloc((size_t)N * sizeof(float));
    float* adst2  = (float*)alloc((size_t)N * sizeof(float));
    int*   deg    = (int*)alloc((size_t)N * sizeof(int));
    int*   rowst  = (int*)alloc((size_t)(N + 1) * sizeof(int));
    int*   cursor = (int*)alloc((size_t)N * sizeof(int));
    int*   adjl   = (int*)alloc((size_t)ET * sizeof(int));
    float* scores = (float*)alloc((size_t)N * sizeof(float));
    float* cvec   = (float*)alloc(128 * sizeof(float));
    int*   bsum   = (int*)alloc(((size_t)(N + 1023) / 1024 + 64) * sizeof(int));
    unsigned* gmaxb = (unsigned*)alloc(256);
    float* sumexp   = (float*)alloc(256);

    float* out_h = (float*)d_out;             // [N*128]
    float* out_s = out_h + (size_t)N * 128;   // [N]

    const int tb = 256;
    const int nb = (N + 1023) / 1024;
    k_init<<<(N + tb - 1) / tb, tb, 0, stream>>>(deg, gmaxb, sumexp, N);
    k_count<<<(E + tb - 1) / tb, tb, 0, stream>>>(edst, deg, E);
    k_scan1<<<nb, 256, 0, stream>>>(deg, bsum, N);
    k_scan2<<<1, 64, 0, stream>>>(bsum, nb);
    k_scan3<<<nb, 256, 0, stream>>>(deg, bsum, rowst, N);
    k_selfloop<<<(N + tb - 1) / tb, tb, 0, stream>>>(rowst, cursor, adjl, N);
    k_scatter<<<(E + tb - 1) / tb, tb, 0, stream>>>(esrc, edst, cursor, adjl, E);

    const int ngrp = (N + 63) / 64;
    const int gb = (ngrp < 512) ? ngrp : 512;

    // layer 1: heads=2  (x f32 -> h1 bf16)
    k_gemm_mfma<2, float><<<gb, 256, 0, stream>>>(x, W1, as1, ad1, hbufA, asrc1, adst1, N, ngrp);
    k_agg<2, u16><<<(N + 3) / 4, 256, 0, stream>>>(rowst, adjl, asrc1, adst1, hbufA, b1, hbufB, N);

    // layer 2: heads=1  (h1 bf16 -> h2 f32 into d_out)
    k_gemm_mfma<1, u16><<<gb, 256, 0, stream>>>(hbufB, W2, as2, ad2, hbufA, asrc2, adst2, N, ngrp);
    k_agg<1, float><<<(N + 3) / 4, 256, 0, stream>>>(rowst, adjl, asrc2, adst2, hbufA, b2, out_h, N);

    // score head
    k_cvec<<<1, 128, 0, stream>>>(q, Wq1, bq1, cvec);
    k_score_mfma<<<gb, 256, 0, stream>>>(out_h, Wq1, Wq2, bq2, cvec, scores, gmaxb, N, ngrp);
    k_sumexp<<<(N + tb - 1) / tb, tb, 0, stream>>>(scores, gmaxb, sumexp, N);
    k_final<<<(N + tb - 1) / tb, tb, 0, stream>>>(scores, sumexp, out_s, N);
}

// Round 12
// 246.087 us; speedup vs baseline: 5.7006x; 1.0241x over previous
//
#include <hip/hip_runtime.h>
#include <hip/hip_bf16.h>

typedef unsigned short u16;
typedef __attribute__((ext_vector_type(8))) short bf16x8;
typedef __attribute__((ext_vector_type(4))) float f32x4;

#define LEAKY 0.2f

__device__ __forceinline__ float bu2f(u16 v) {
    return __uint_as_float(((unsigned)v) << 16);
}
__device__ __forceinline__ u16 f2bu(float f) {
    unsigned u = __float_as_uint(f);
    unsigned r = (u + 0x7FFFu + ((u >> 16) & 1u)) >> 16;
    return (u16)r;
}
__device__ __forceinline__ unsigned fmapu(float f) {
    unsigned u = __float_as_uint(f);
    return (u & 0x80000000u) ? ~u : (u | 0x80000000u);
}
__device__ __forceinline__ float funmapu(unsigned u) {
    return __uint_as_float((u & 0x80000000u) ? (u & 0x7FFFFFFFu) : ~u);
}

// ---------------- CSR build ----------------

__global__ void k_init(int* deg, unsigned* gmaxb, float* sumexp, int N) {
    int i = blockIdx.x * blockDim.x + threadIdx.x;
    if (i < N) deg[i] = 1;  // self loop
    if (i == 0) { *gmaxb = 0u; *sumexp = 0.f; }
}

// XCD-partitioned count: block bid handles edge chunk (bid>>3), but only edges
// whose dst falls in node-range (bid&7). With round-robin block->XCD dispatch,
// each deg line is touched by exactly one XCD -> no cross-L2 line ping-pong.
__global__ __launch_bounds__(256) void k_count(const int* __restrict__ dst,
                                               int* __restrict__ deg,
                                               int E, int rng, int M) {
    int myx = blockIdx.x & 7;
    int m = blockIdx.x >> 3;
    int C = (E + M - 1) / M;
    int lo = m * C;
    int hi = min(lo + C, E);
    for (int i = lo + threadIdx.x; i < hi; i += 256) {
        int d = __builtin_nontemporal_load(dst + i);
        if (d / rng == myx) atomicAdd(&deg[d], 1);
    }
}

// ---- hierarchical exclusive scan of deg -> rowst (rowst[N] = total) ----

__global__ __launch_bounds__(256) void k_scan1(const int* __restrict__ deg,
                                               int* __restrict__ bsum, int N) {
    int b = blockIdx.x;
    int t = threadIdx.x;
    int base = b * 1024;
    int s = 0;
    for (int i = t; i < 1024; i += 256) {
        int idx = base + i;
        if (idx < N) s += deg[idx];
    }
#pragma unroll
    for (int o = 32; o > 0; o >>= 1) s += __shfl_down(s, o);
    __shared__ int ws[4];
    if ((t & 63) == 0) ws[t >> 6] = s;
    __syncthreads();
    if (t == 0) bsum[b] = ws[0] + ws[1] + ws[2] + ws[3];
}

__global__ void k_scan2(int* __restrict__ bsum, int nb) {
    int t = threadIdx.x;   // 64 threads
    if (nb <= 64) {
        int orig = (t < nb) ? bsum[t] : 0;
        int v = orig;
#pragma unroll
        for (int o = 1; o < 64; o <<= 1) {
            int u = __shfl_up(v, o);
            if (t >= o) v += u;
        }
        if (t < nb) bsum[t] = v - orig;  // exclusive
    } else {
        if (t == 0) {
            int run = 0;
            for (int i = 0; i < nb; ++i) { int v = bsum[i]; bsum[i] = run; run += v; }
        }
    }
}

__global__ __launch_bounds__(256) void k_scan3(const int* __restrict__ deg,
                                               const int* __restrict__ bsum,
                                               int* __restrict__ rowst, int N) {
    int b = blockIdx.x;
    int t = threadIdx.x;
    int l = t & 63;
    int wv = t >> 6;
    int idx0 = b * 1024 + t * 4;
    int d[4];
#pragma unroll
    for (int j = 0; j < 4; ++j) d[j] = (idx0 + j < N) ? deg[idx0 + j] : 0;
    int s = d[0] + d[1] + d[2] + d[3];
    int orig = s;
    int v = s;
#pragma unroll
    for (int o = 1; o < 64; o <<= 1) {
        int u = __shfl_up(v, o);
        if (l >= o) v += u;
    }
    __shared__ int wsum[4];
    if (l == 63) wsum[wv] = v;
    __syncthreads();
    int woff = 0;
    for (int w = 0; w < wv; ++w) woff += wsum[w];
    int run = v - orig + woff + bsum[b];
#pragma unroll
    for (int j = 0; j < 4; ++j) {
        if (idx0 + j < N) rowst[idx0 + j] = run;
        run += d[j];
    }
    if (idx0 <= N - 1 && N - 1 < idx0 + 4) rowst[N] = run;
}

__global__ void k_selfloop(const int* __restrict__ rowst, int* __restrict__ cursor,
                           int* __restrict__ adj, int N) {
    int i = blockIdx.x * blockDim.x + threadIdx.x;
    if (i < N) {
        int p = rowst[i];
        adj[p] = i;          // self loop first
        cursor[i] = p + 1;
    }
}

// XCD-partitioned scatter (see k_count). adj/cursor lines stay in ONE XCD's L2
// until final writeback -> write traffic ~= adj size instead of 64B/edge.
__global__ __launch_bounds__(256) void k_scatter(const int* __restrict__ src,
                                                 const int* __restrict__ dst,
                                                 int* __restrict__ cursor,
                                                 int* __restrict__ adj,
                                                 int E, int rng, int M) {
    int myx = blockIdx.x & 7;
    int m = blockIdx.x >> 3;
    int C = (E + M - 1) / M;
    int lo = m * C;
    int hi = min(lo + C, E);
    for (int i = lo + threadIdx.x; i < hi; i += 256) {
        int d = __builtin_nontemporal_load(dst + i);
        if (d / rng == myx) {
            int s = __builtin_nontemporal_load(src + i);
            int pos = atomicAdd(&cursor[d], 1);
            adj[pos] = s;
        }
    }
}

// ---------------- MFMA GEMM (N x 128) @ (128 x 128) + attention-coef epilogue ----------------

template <int H, typename TIN>
__global__ __launch_bounds__(256, 2) void k_gemm_mfma(
    const TIN* __restrict__ in, const float* __restrict__ W,
    const float* __restrict__ att_s, const float* __restrict__ att_d,
    u16* __restrict__ out, float* __restrict__ a_src, float* __restrict__ a_dst,
    int N, int ngrp) {
    int t = threadIdx.x;
    int l = t & 63;
    int wv = t >> 6;        // wave 0..3
    int l16 = l & 15;
    int lk = l >> 4;        // 0..3

    bf16x8 b[4][8];
#pragma unroll
    for (int ks = 0; ks < 4; ++ks) {
#pragma unroll
        for (int n = 0; n < 8; ++n) {
            int kbase = ks * 32 + lk * 8;
            int col = n * 16 + l16;
            bf16x8 bb;
#pragma unroll
            for (int j = 0; j < 8; ++j) bb[j] = (short)f2bu(W[(size_t)(kbase + j) * 128 + col]);
            b[ks][n] = bb;
        }
    }
    float atts[8], attd[8];
#pragma unroll
    for (int n = 0; n < 8; ++n) {
        atts[n] = att_s[n * 16 + l16];
        attd[n] = att_d[n * 16 + l16];
    }

    for (int g = blockIdx.x; g < ngrp; g += gridDim.x) {
        int rowbase = g * 64 + wv * 16;
        f32x4 acc[8];
#pragma unroll
        for (int n = 0; n < 8; ++n) acc[n] = (f32x4){0.f, 0.f, 0.f, 0.f};
        int ra = rowbase + l16;   // A-row this lane feeds
#pragma unroll
        for (int ks = 0; ks < 4; ++ks) {
            bf16x8 a;
            if (ra < N) {
                if constexpr (sizeof(TIN) == 4) {
                    const float4* pf = (const float4*)((const float*)in + (size_t)ra * 128 + ks * 32 + lk * 8);
                    float4 p0 = pf[0], p1 = pf[1];
                    a[0] = (short)f2bu(p0.x); a[1] = (short)f2bu(p0.y);
                    a[2] = (short)f2bu(p0.z); a[3] = (short)f2bu(p0.w);
                    a[4] = (short)f2bu(p1.x); a[5] = (short)f2bu(p1.y);
                    a[6] = (short)f2bu(p1.z); a[7] = (short)f2bu(p1.w);
                } else {
                    a = *(const bf16x8*)((const u16*)in + (size_t)ra * 128 + ks * 32 + lk * 8);
                }
            } else {
                a = (bf16x8){0, 0, 0, 0, 0, 0, 0, 0};
            }
#pragma unroll
            for (int n = 0; n < 8; ++n)
                acc[n] = __builtin_amdgcn_mfma_f32_16x16x32_bf16(a, b[ks][n], acc[n], 0, 0, 0);
        }
        // store h
#pragma unroll
        for (int n = 0; n < 8; ++n) {
#pragma unroll
            for (int i = 0; i < 4; ++i) {
                int r = rowbase + lk * 4 + i;
                if (r < N) out[(size_t)r * 128 + n * 16 + l16] = f2bu(acc[n][i]);
            }
        }
        // attention-coef row sums
#pragma unroll
        for (int i = 0; i < 4; ++i) {
            int r = rowbase + lk * 4 + i;
            if (H == 2) {
                float s0 = 0.f, s1 = 0.f, d0 = 0.f, d1 = 0.f;
#pragma unroll
                for (int n = 0; n < 4; ++n) { s0 += acc[n][i] * atts[n]; d0 += acc[n][i] * attd[n]; }
#pragma unroll
                for (int n = 4; n < 8; ++n) { s1 += acc[n][i] * atts[n]; d1 += acc[n][i] * attd[n]; }
#pragma unroll
                for (int o = 1; o < 16; o <<= 1) {
                    s0 += __shfl_xor(s0, o); d0 += __shfl_xor(d0, o);
                    s1 += __shfl_xor(s1, o); d1 += __shfl_xor(d1, o);
                }
                if (l16 == 0 && r < N) {
                    a_src[(size_t)r * 2 + 0] = s0; a_src[(size_t)r * 2 + 1] = s1;
                    a_dst[(size_t)r * 2 + 0] = d0; a_dst[(size_t)r * 2 + 1] = d1;
                }
            } else {
                float s0 = 0.f, d0 = 0.f;
#pragma unroll
                for (int n = 0; n < 8; ++n) { s0 += acc[n][i] * atts[n]; d0 += acc[n][i] * attd[n]; }
#pragma unroll
                for (int o = 1; o < 16; o <<= 1) {
                    s0 += __shfl_xor(s0, o); d0 += __shfl_xor(d0, o);
                }
                if (l16 == 0 && r < N) { a_src[r] = s0; a_dst[r] = d0; }
            }
        }
    }
}

// ---------------- per-node segment softmax + aggregation ----------------
// ONE WAVE PER NODE (4 nodes / 256-thread block). No LDS, no __syncthreads.

template <int H, typename TOUT>
__global__ __launch_bounds__(256) void k_agg(
    const int* __restrict__ rowst, const int* __restrict__ adj,
    const float* __restrict__ a_src, const float* __restrict__ a_dst,
    const u16* __restrict__ h_in, const float* __restrict__ bias,
    TOUT* __restrict__ out, int N) {
    int wid = threadIdx.x >> 6;
    int n = blockIdx.x * 4 + wid;
    if (n >= N) return;                 // wave-uniform
    int l = threadIdx.x & 63;
    int g = l >> 4;                     // edge-group 0..3
    int li = l & 15;
    int ch0 = li * 8;                   // channels ch0..ch0+7
    int h8 = (H == 2) ? (li >> 3) : 0;  // head of this lane's channels
    int rs = rowst[n], re = rowst[n + 1];
    float asd0 = a_dst[(size_t)n * H];
    float asd1 = (H == 2) ? a_dst[(size_t)n * H + 1] : 0.f;
    float m0 = -1e30f, m1 = -1e30f, s0 = 0.f, s1 = 0.f;
    float acc[8];
#pragma unroll
    for (int j = 0; j < 8; ++j) acc[j] = 0.f;

    for (int base = rs; base < re; base += 64) {
        int cnt = min(64, re - base);
        int sidx = (l < cnt) ? __builtin_nontemporal_load(adj + base + l) : 0;
        // phase A: leaky-relu scores, edge l on lane l
        float p0 = -1e30f, p1 = -1e30f;
        if (l < cnt) {
            if (H == 2) {
                float2 vv = *(const float2*)(a_src + (size_t)sidx * 2);
                float v0 = vv.x + asd0, v1 = vv.y + asd1;
                p0 = (v0 > 0.f) ? v0 : LEAKY * v0;
                p1 = (v1 > 0.f) ? v1 : LEAKY * v1;
            } else {
                float v0 = a_src[sidx] + asd0;
                p0 = (v0 > 0.f) ? v0 : LEAKY * v0;
            }
        }
        float lm0 = p0, lm1 = p1;
#pragma unroll
        for (int o = 32; o > 0; o >>= 1) {
            lm0 = fmaxf(lm0, __shfl_xor(lm0, o));
            if (H == 2) lm1 = fmaxf(lm1, __shfl_xor(lm1, o));
        }
        float nm0 = fmaxf(m0, lm0);
        float nm1 = (H == 2) ? fmaxf(m1, lm1) : 0.f;
        p0 = (l < cnt) ? __expf(p0 - nm0) : 0.f;
        if (H == 2) p1 = (l < cnt) ? __expf(p1 - nm1) : 0.f;
        float sum0 = p0, sum1 = p1;
#pragma unroll
        for (int o = 32; o > 0; o >>= 1) {
            sum0 += __shfl_xor(sum0, o);
            if (H == 2) sum1 += __shfl_xor(sum1, o);
        }
        float r0 = __expf(m0 - nm0);
        float r1 = (H == 2) ? __expf(m1 - nm1) : 0.f;
        s0 = s0 * r0 + sum0; m0 = nm0;
        if (H == 2) { s1 = s1 * r1 + sum1; m1 = nm1; }
        float racc = (H == 2) ? (h8 ? r1 : r0) : r0;
#pragma unroll
        for (int j = 0; j < 8; ++j) acc[j] *= racc;
        // phase B: gather, 4 edges in flight per wave
        for (int e4 = 0; e4 < cnt; e4 += 4) {
            int e = e4 + g;                     // <= 63
            int s = __shfl(sidx, e);            // pe==0 if e>=cnt
            float pe0 = __shfl(p0, e);
            float pe = pe0;
            if (H == 2) { float pe1 = __shfl(p1, e); pe = h8 ? pe1 : pe0; }
            bf16x8 v = *(const bf16x8*)(h_in + (size_t)s * 128 + ch0);
#pragma unroll
            for (int j = 0; j < 8; ++j) acc[j] += pe * bu2f((u16)v[j]);
        }
    }
    // combine the 4 edge-groups
#pragma unroll
    for (int j = 0; j < 8; ++j) acc[j] += __shfl_xor(acc[j], 16);
#pragma unroll
    for (int j = 0; j < 8; ++j) acc[j] += __shfl_xor(acc[j], 32);
    if (l < 16) {
        float sden = (H == 2) ? (h8 ? s1 : s0) : s0;
        float inv = 1.f / (sden + 1e-16f);
#pragma unroll
        for (int j = 0; j < 8; ++j) {
            float val = acc[j] * inv + bias[ch0 + j];
            if constexpr (sizeof(TOUT) == 2) {
                out[(size_t)n * 128 + ch0 + j] = (TOUT)f2bu(val);
            } else {
                out[(size_t)n * 128 + ch0 + j] = (TOUT)val;
            }
        }
    }
}

// ---------------- score head ----------------

__global__ void k_cvec(const float* __restrict__ q, const float* __restrict__ Wq1,
                       const float* __restrict__ bq1, float* __restrict__ cvec) {
    int j = threadIdx.x;  // 128 threads
    float acc = bq1[j];
    for (int k = 0; k < 384; ++k) acc += q[k] * Wq1[(size_t)(128 + k) * 128 + j];
    cvec[j] = acc;
}

__global__ __launch_bounds__(256, 2) void k_score_mfma(
    const float* __restrict__ h2, const float* __restrict__ Wq1, const float* __restrict__ Wq2,
    const float* __restrict__ bq2, const float* __restrict__ cvec,
    float* __restrict__ scores, unsigned* __restrict__ gmaxb, int N, int ngrp) {
    int t = threadIdx.x;
    int l = t & 63;
    int wv = t >> 6;
    int l16 = l & 15;
    int lk = l >> 4;

    bf16x8 b[4][8];
#pragma unroll
    for (int ks = 0; ks < 4; ++ks) {
#pragma unroll
        for (int n = 0; n < 8; ++n) {
            int kbase = ks * 32 + lk * 8;
            int col = n * 16 + l16;
            bf16x8 bb;
#pragma unroll
            for (int j = 0; j < 8; ++j) bb[j] = (short)f2bu(Wq1[(size_t)(kbase + j) * 128 + col]);
            b[ks][n] = bb;
        }
    }
    float cva[8], w2a[8];
#pragma unroll
    for (int n = 0; n < 8; ++n) {
        cva[n] = cvec[n * 16 + l16];
        w2a[n] = Wq2[n * 16 + l16];
    }
    float bq2v = bq2[0];
    float lmax = -1e30f;

    for (int g = blockIdx.x; g < ngrp; g += gridDim.x) {
        int rowbase = g * 64 + wv * 16;
        f32x4 acc[8];
#pragma unroll
        for (int n = 0; n < 8; ++n) acc[n] = (f32x4){0.f, 0.f, 0.f, 0.f};
        int ra = rowbase + l16;
#pragma unroll
        for (int ks = 0; ks < 4; ++ks) {
            bf16x8 a;
            if (ra < N) {
                const float4* pf = (const float4*)(h2 + (size_t)ra * 128 + ks * 32 + lk * 8);
                float4 p0 = pf[0], p1 = pf[1];
                a[0] = (short)f2bu(p0.x); a[1] = (short)f2bu(p0.y);
                a[2] = (short)f2bu(p0.z); a[3] = (short)f2bu(p0.w);
                a[4] = (short)f2bu(p1.x); a[5] = (short)f2bu(p1.y);
                a[6] = (short)f2bu(p1.z); a[7] = (short)f2bu(p1.w);
            } else {
                a = (bf16x8){0, 0, 0, 0, 0, 0, 0, 0};
            }
#pragma unroll
            for (int n = 0; n < 8; ++n)
                acc[n] = __builtin_amdgcn_mfma_f32_16x16x32_bf16(a, b[ks][n], acc[n], 0, 0, 0);
        }
#pragma unroll
        for (int i = 0; i < 4; ++i) {
            int r = rowbase + lk * 4 + i;
            float s = 0.f;
#pragma unroll
            for (int n = 0; n < 8; ++n) s += fmaxf(acc[n][i] + cva[n], 0.f) * w2a[n];
#pragma unroll
            for (int o = 1; o < 16; o <<= 1) s += __shfl_xor(s, o);
            if (l16 == 0 && r < N) {
                float sc = s + bq2v;
                scores[r] = sc;
                lmax = fmaxf(lmax, sc);
            }
        }
    }
#pragma unroll
    for (int o = 1; o < 64; o <<= 1) lmax = fmaxf(lmax, __shfl_xor(lmax, o));
    __shared__ float bmax[4];
    if (l == 0) bmax[wv] = lmax;
    __syncthreads();
    if (t == 0)
        atomicMax(gmaxb, fmapu(fmaxf(fmaxf(bmax[0], bmax[1]), fmaxf(bmax[2], bmax[3]))));
}

__global__ void k_sumexp(float* __restrict__ scores, const unsigned* __restrict__ gmaxb,
                         float* __restrict__ sumexp, int N) {
    int i = blockIdx.x * blockDim.x + threadIdx.x;
    float gmax = funmapu(*gmaxb);
    float p = 0.f;
    if (i < N) {
        p = __expf(scores[i] - gmax);
        scores[i] = p;
    }
#pragma unroll
    for (int o = 32; o > 0; o >>= 1) p += __shfl_down(p, o);
    __shared__ float ws_[4];
    if ((threadIdx.x & 63) == 0) ws_[threadIdx.x >> 6] = p;
    __syncthreads();
    if (threadIdx.x == 0) atomicAdd(sumexp, ws_[0] + ws_[1] + ws_[2] + ws_[3]);
}

__global__ void k_final(const float* __restrict__ scores, const float* __restrict__ sumexp,
                        float* __restrict__ out_s, int N) {
    int i = blockIdx.x * blockDim.x + threadIdx.x;
    if (i < N) out_s[i] = scores[i] / *sumexp;
}

// ---------------- launch ----------------

extern "C" void kernel_launch(void* const* d_in, const int* in_sizes, int n_in,
                              void* d_out, int out_size, void* d_ws, size_t ws_size,
                              hipStream_t stream) {
    const float* x   = (const float*)d_in[0];
    const int*   ei  = (const int*)d_in[1];
    const float* q   = (const float*)d_in[3];
    const float* W1  = (const float*)d_in[4];
    const float* as1 = (const float*)d_in[5];
    const float* ad1 = (const float*)d_in[6];
    const float* b1  = (const float*)d_in[7];
    const float* W2  = (const float*)d_in[8];
    const float* as2 = (const float*)d_in[9];
    const float* ad2 = (const float*)d_in[10];
    const float* b2  = (const float*)d_in[11];
    const float* Wq1 = (const float*)d_in[12];
    const float* bq1 = (const float*)d_in[13];
    const float* Wq2 = (const float*)d_in[14];
    const float* bq2 = (const float*)d_in[15];

    const int N = in_sizes[0] / 128;
    const int E = in_sizes[1] / 2;
    const int ET = E + N;
    const int* esrc = ei;
    const int* edst = ei + E;

    char* p = (char*)d_ws;
    auto alloc = [&](size_t bytes) -> char* {
        char* r = p;
        p += (bytes + 255) & ~(size_t)255;
        return r;
    };
    u16*   hbufA  = (u16*)alloc((size_t)N * 128 * sizeof(u16));  // gemm outputs (bf16)
    u16*   hbufB  = (u16*)alloc((size_t)N * 128 * sizeof(u16));  // layer-1 result (bf16)
    float* asrc1  = (float*)alloc((size_t)N * 2 * sizeof(float));
    float* adst1  = (float*)alloc((size_t)N * 2 * sizeof(float));
    float* asrc2  = (float*)alloc((size_t)N * sizeof(float));
    float* adst2  = (float*)alloc((size_t)N * sizeof(float));
    int*   deg    = (int*)alloc((size_t)N * sizeof(int));
    int*   rowst  = (int*)alloc((size_t)(N + 1) * sizeof(int));
    int*   cursor = (int*)alloc((size_t)N * sizeof(int));
    int*   adjl   = (int*)alloc((size_t)ET * sizeof(int));
    float* scores = (float*)alloc((size_t)N * sizeof(float));
    float* cvec   = (float*)alloc(128 * sizeof(float));
    int*   bsum   = (int*)alloc(((size_t)(N + 1023) / 1024 + 64) * sizeof(int));
    unsigned* gmaxb = (unsigned*)alloc(256);
    float* sumexp   = (float*)alloc(256);

    float* out_h = (float*)d_out;             // [N*128]
    float* out_s = out_h + (size_t)N * 128;   // [N]

    const int tb = 256;
    const int nb = (N + 1023) / 1024;
    const int rng = (N + 7) >> 3;     // nodes per XCD partition
    const int M = 256;                // edge chunks (grid = 8*M)
    k_init<<<(N + tb - 1) / tb, tb, 0, stream>>>(deg, gmaxb, sumexp, N);
    k_count<<<8 * M, 256, 0, stream>>>(edst, deg, E, rng, M);
    k_scan1<<<nb, 256, 0, stream>>>(deg, bsum, N);
    k_scan2<<<1, 64, 0, stream>>>(bsum, nb);
    k_scan3<<<nb, 256, 0, stream>>>(deg, bsum, rowst, N);
    k_selfloop<<<(N + tb - 1) / tb, tb, 0, stream>>>(rowst, cursor, adjl, N);
    k_scatter<<<8 * M, 256, 0, stream>>>(esrc, edst, cursor, adjl, E, rng, M);

    const int ngrp = (N + 63) / 64;
    const int gb = (ngrp < 512) ? ngrp : 512;

    // layer 1: heads=2  (x f32 -> h1 bf16)
    k_gemm_mfma<2, float><<<gb, 256, 0, stream>>>(x, W1, as1, ad1, hbufA, asrc1, adst1, N, ngrp);
    k_agg<2, u16><<<(N + 3) / 4, 256, 0, stream>>>(rowst, adjl, asrc1, adst1, hbufA, b1, hbufB, N);

    // layer 2: heads=1  (h1 bf16 -> h2 f32 into d_out)
    k_gemm_mfma<1, u16><<<gb, 256, 0, stream>>>(hbufB, W2, as2, ad2, hbufA, asrc2, adst2, N, ngrp);
    k_agg<1, float><<<(N + 3) / 4, 256, 0, stream>>>(rowst, adjl, asrc2, adst2, hbufA, b2, out_h, N);

    // score head
    k_cvec<<<1, 128, 0, stream>>>(q, Wq1, bq1, cvec);
    k_score_mfma<<<gb, 256, 0, stream>>>(out_h, Wq1, Wq2, bq2, cvec, scores, gmaxb, N, ngrp);
    k_sumexp<<<(N + tb - 1) / tb, tb, 0, stream>>>(scores, gmaxb, sumexp, N);
    k_final<<<(N + tb - 1) / tb, tb, 0, stream>>>(scores, sumexp, out_s, N);
}